// Round 3
// baseline (1027.228 us; speedup 1.0000x reference)
//
#include <hip/hip_runtime.h>
#include <float.h>

typedef __bf16 bf16;
typedef __attribute__((ext_vector_type(8))) __bf16 bf16x8;
typedef __attribute__((ext_vector_type(4))) __bf16 bf16x4;
typedef __attribute__((ext_vector_type(4))) float f32x4;

__device__ __forceinline__ int imin(int a, int b) { return a < b ? a : b; }

// async global->LDS, 16B per lane; LDS dest = wave-uniform base + lane*16
__device__ __forceinline__ void gl2lds(const bf16* g, bf16* l) {
  __builtin_amdgcn_global_load_lds(
      (const __attribute__((address_space(1))) void*)g,
      (__attribute__((address_space(3))) void*)l, 16, 0, 0);
}

// ---------------- zero-page + padded lin weights (fused tiny prep) ----------------
__global__ void k_prep_misc(bf16* zp, const float* __restrict__ l1w,
                            const float* __restrict__ l2w,
                            bf16* __restrict__ L1p, bf16* __restrict__ L2p) {
  zp[threadIdx.x] = (bf16)0.0f;
  for (int i = threadIdx.x; i < 3456; i += 256) {
    int r = i / 72, c = i - r * 72;
    L1p[i] = (c < 48) ? (bf16)l1w[r * 48 + c] : (bf16)0.0f;
    L2p[i] = (c < 48) ? (bf16)l2w[r * 48 + c] : (bf16)0.0f;
  }
}

// ---------------- fused f32->bf16 casts (13 segments) ----------------
struct CastSegs { const float* s[13]; bf16* d[13]; int n[13]; };
__global__ void k_cast_all(CastSegs sg, int total) {
  int i = blockIdx.x * 256 + threadIdx.x;
  if (i >= total) return;
  for (int k = 0; k < 13; ++k) {
    if (i < sg.n[k]) { sg.d[k][i] = (bf16)sg.s[k][i]; return; }
    i -= sg.n[k];
  }
}

// ---------------- rel transpose via LDS: (sh, k*48+j) fp32 -> (sh, j*32+k) bf16 ----------------
__global__ __launch_bounds__(256) void k_prep_rel(const float* __restrict__ rel,
                                                  bf16* __restrict__ RelT) {
  __shared__ float tile[32 * 49];
  const int t = threadIdx.x;
  for (int u = 0; u < 8; ++u) {
    const size_t sh = (size_t)blockIdx.x * 8 + u;
    const float* src = rel + sh * 1536;
    bf16* dst = RelT + sh * 1536;
    __syncthreads();
    for (int i = t; i < 1536; i += 256) {
      int k = i / 48, j = i - k * 48;
      tile[k * 49 + j] = src[i];
    }
    __syncthreads();
    for (int i = t; i < 1536; i += 256) {
      int j = i >> 5, k = i & 31;
      dst[i] = (bf16)tile[k * 49 + j];
    }
  }
}

// ---------------- X_en|X_de (b,32,32,32) -> XR rows (96*1024, 32ch) bf16 ----------------
__global__ void k_prep_x(const float* __restrict__ XE, const float* __restrict__ XD,
                         bf16* __restrict__ XR) {
  int idx = blockIdx.x * 256 + threadIdx.x;
  if (idx >= 96 * 1024 * 32) return;
  int b = idx >> 15, r = idx & 32767, pos = r >> 5, ic = r & 31;
  const float* X = (b < 48) ? XE : XD;
  int bl = (b < 48) ? b : b - 48;
  XR[idx] = (bf16)X[((size_t)(bl * 32 + ic) << 10) + pos];
}

// ---------------- conv weight pack: (OC,IC,3,3) -> 9 x (OC,IC) bf16 ----------------
__global__ void k_pack_conv(const float* __restrict__ w, bf16* __restrict__ dst,
                            int OC, int IC, int total) {
  int idx = blockIdx.x * 256 + threadIdx.x;
  if (idx >= total) return;
  int t = idx / (OC * IC);
  int rem = idx - t * OC * IC;
  int oc = rem / IC, ic = rem - oc * IC;
  dst[idx] = (bf16)w[(size_t)(oc * IC + ic) * 9 + t];
}

// ---------------- 128x128 GEMM, BK=64, single-buffered, conflict-free LDS ----------
// LDS: A [128][64] at 0, B [128][64] at +8192 (128-B row pitch).
// Swizzle involution: seg' = seg ^ (row&7) (16-B segs, 8/row); gl2lds dest linear,
// SOURCE pre-swizzled, reads swizzled with the same XOR.
// If n0 >= nsplit: use A2/B2 with local n (merged dual-GEMM launch). K%64==0, N%128==0.
__global__ __launch_bounds__(256, 2) void k_gemm128(
    const bf16* __restrict__ A, const bf16* __restrict__ A2,
    const bf16* __restrict__ B, const bf16* __restrict__ B2, int nsplit,
    const float* __restrict__ bias, bf16* __restrict__ C,
    int M, int N, int K, int relu, int ldc, int coff) {
  __shared__ alignas(16) bf16 SM[16384];
  const int t = threadIdx.x, wave = t >> 6;
  const int lane = t & 63, fr = lane & 15, kq = lane >> 4;
  const int wm = wave & 1, wn = wave >> 1;
  const int m0 = blockIdx.x * 128, n0 = blockIdx.y * 128;
  const bf16* Ause = A; const bf16* Buse = B; int nloc = n0;
  if (n0 >= nsplit) { Ause = A2; Buse = B2; nloc = n0 - nsplit; }
  // staging map: thread t covers (row = r*32 + (t>>3), seg = t&7), r = 0..3 for A and B
  const int srow = t >> 3;
  const int sg8 = (((t & 7) ^ (srow & 7)) << 3);  // pre-swizzled source k-seg (elements)
  const bf16* gA[4]; const bf16* gB[4];
#pragma unroll
  for (int r = 0; r < 4; ++r) {
    gA[r] = Ause + (size_t)imin(m0 + r * 32 + srow, M - 1) * K + sg8;
    gB[r] = Buse + (size_t)(nloc + r * 32 + srow) * K + sg8;
  }
  // fragment-read offsets (elements); ^32 switches k-halves
  const int swz = (kq ^ (fr & 7)) << 3;
  const int aoff = (wm * 64 + fr) * 64 + swz;
  const int boff = 8192 + (wn * 64 + fr) * 64 + swz;
  f32x4 acc[4][4] = {};
  for (int k0 = 0; k0 < K; k0 += 64) {
    bf16* db = SM + wave * 512;
#pragma unroll
    for (int r = 0; r < 4; ++r) gl2lds(gA[r] + k0, db + r * 2048);
#pragma unroll
    for (int r = 0; r < 4; ++r) gl2lds(gB[r] + k0, db + 8192 + r * 2048);
    __syncthreads();
#pragma unroll
    for (int kk = 0; kk < 2; ++kk) {
      const int xo = kk << 5;
      bf16x8 af[4], bw[4];
#pragma unroll
      for (int mt = 0; mt < 4; ++mt)
        af[mt] = *(const bf16x8*)(SM + ((aoff + mt * 1024) ^ xo));
#pragma unroll
      for (int nt = 0; nt < 4; ++nt)
        bw[nt] = *(const bf16x8*)(SM + ((boff + nt * 1024) ^ xo));
#pragma unroll
      for (int mt = 0; mt < 4; ++mt)
#pragma unroll
        for (int nt = 0; nt < 4; ++nt)
          acc[mt][nt] = __builtin_amdgcn_mfma_f32_16x16x32_bf16(af[mt], bw[nt], acc[mt][nt], 0, 0, 0);
    }
    __syncthreads();
  }
  bf16* Cst = SM;  // 64 x 136 (padded pitch: conflict-free epilogue)
  for (int half = 0; half < 2; ++half) {
    if (wm == half) {
      for (int mt = 0; mt < 4; ++mt)
        for (int nt = 0; nt < 4; ++nt) {
          int n = n0 + wn * 64 + nt * 16 + fr;
          float bv = bias ? bias[n] : 0.0f;
          for (int r = 0; r < 4; ++r) {
            float v = acc[mt][nt][r] + bv;
            if (relu) v = fmaxf(v, 0.0f);
            Cst[(mt * 16 + kq * 4 + r) * 136 + wn * 64 + nt * 16 + fr] = (bf16)v;
          }
        }
    }
    __syncthreads();
    for (int i = t; i < 1024; i += 256) {
      int r = i >> 4, cs = i & 15;
      int gm = m0 + half * 64 + r;
      if (gm < M)
        *(bf16x8*)(C + (size_t)gm * ldc + coff + n0 + cs * 8) = *(const bf16x8*)(Cst + r * 136 + cs * 8);
    }
    __syncthreads();
  }
}

// ---------------- FFN2 (M x 256 = A[Mx1024] x B[256x1024]^T) with fused add+LN ------
// Block 128x256 (full rows), 4 waves of 64x128 (acc 4x8, 1.33x LDS reuse of 64x64).
// Same staging map / swizzle / 2-barrier loop as k_gemm128 (parameter variant).
// Epilogue per 64-row half: stage to LDS, add residual, LayerNorm via 4-lane shfl.
// FUSEY=0: write LN result to C. FUSEY=1: write only Y[gm] = dot(LN-row, ow) + ob.
template <int FUSEY>
__global__ __launch_bounds__(256, 2) void k_ffn2ln(
    const bf16* __restrict__ A, const bf16* __restrict__ B,
    const float* __restrict__ bias, const bf16* __restrict__ RES,
    bf16* __restrict__ C, const float* __restrict__ ow,
    const float* __restrict__ ob, float* __restrict__ Y, int M) {
  __shared__ alignas(16) bf16 SM[24576];  // staging: A 128x64 | B 256x64 ; epi: 64x264
  const int t = threadIdx.x, wave = t >> 6;
  const int lane = t & 63, fr = lane & 15, kq = lane >> 4;
  const int wm = wave & 1, wn = wave >> 1;
  const int m0 = blockIdx.x * 128;
  const int srow = t >> 3;
  const int sg8 = (((t & 7) ^ (srow & 7)) << 3);
  const bf16* gA[4]; const bf16* gB[8];
#pragma unroll
  for (int r = 0; r < 4; ++r)
    gA[r] = A + (size_t)imin(m0 + r * 32 + srow, M - 1) * 1024 + sg8;
#pragma unroll
  for (int r = 0; r < 8; ++r)
    gB[r] = B + (size_t)(r * 32 + srow) * 1024 + sg8;
  const int swz = (kq ^ (fr & 7)) << 3;
  const int aoff = (wm * 64 + fr) * 64 + swz;
  const int boff = 8192 + (wn * 128 + fr) * 64 + swz;
  f32x4 acc[4][8] = {};
  for (int k0 = 0; k0 < 1024; k0 += 64) {
    bf16* db = SM + wave * 512;
#pragma unroll
    for (int r = 0; r < 4; ++r) gl2lds(gA[r] + k0, db + r * 2048);
#pragma unroll
    for (int r = 0; r < 8; ++r) gl2lds(gB[r] + k0, db + 8192 + r * 2048);
    __syncthreads();
#pragma unroll
    for (int kk = 0; kk < 2; ++kk) {
      const int xo = kk << 5;
      bf16x8 af[4], bw[8];
#pragma unroll
      for (int mt = 0; mt < 4; ++mt)
        af[mt] = *(const bf16x8*)(SM + ((aoff + mt * 1024) ^ xo));
#pragma unroll
      for (int nt = 0; nt < 8; ++nt)
        bw[nt] = *(const bf16x8*)(SM + ((boff + nt * 1024) ^ xo));
#pragma unroll
      for (int mt = 0; mt < 4; ++mt)
#pragma unroll
        for (int nt = 0; nt < 8; ++nt)
          acc[mt][nt] = __builtin_amdgcn_mfma_f32_16x16x32_bf16(af[mt], bw[nt], acc[mt][nt], 0, 0, 0);
    }
    __syncthreads();
  }
  // epilogue: per half, 64 full rows of 256 in LDS (pitch 264), then add+LN
  bf16* Cst = SM;
  const int erow = t >> 2, eq = t & 3;
  for (int half = 0; half < 2; ++half) {
    if (wm == half) {
      for (int mt = 0; mt < 4; ++mt)
        for (int nt = 0; nt < 8; ++nt) {
          int n = wn * 128 + nt * 16 + fr;
          float bv = bias[n];
          for (int r = 0; r < 4; ++r)
            Cst[(mt * 16 + kq * 4 + r) * 264 + n] = (bf16)(acc[mt][nt][r] + bv);
        }
    }
    __syncthreads();
    const int gm = m0 + half * 64 + erow;
    if (gm < M) {
      const bf16* crow = Cst + erow * 264 + eq * 64;
      bf16x8 rv[8];
#pragma unroll
      for (int j = 0; j < 8; ++j)
        rv[j] = *(const bf16x8*)(RES + (size_t)gm * 256 + eq * 64 + j * 8);
      float sum = 0.0f;
#pragma unroll
      for (int j = 0; j < 8; ++j) {
        bf16x8 cv = *(const bf16x8*)(crow + j * 8);
        for (int e = 0; e < 8; ++e) sum += (float)cv[e] + (float)rv[j][e];
      }
      sum += __shfl_xor(sum, 1); sum += __shfl_xor(sum, 2);
      const float mean = sum * (1.0f / 256.0f);
      float q2 = 0.0f;
#pragma unroll
      for (int j = 0; j < 8; ++j) {
        bf16x8 cv = *(const bf16x8*)(crow + j * 8);
        for (int e = 0; e < 8; ++e) {
          float d = (float)cv[e] + (float)rv[j][e] - mean;
          q2 += d * d;
        }
      }
      q2 += __shfl_xor(q2, 1); q2 += __shfl_xor(q2, 2);
      const float rstd = rsqrtf(q2 * (1.0f / 256.0f) + 1e-5f);
      if constexpr (FUSEY) {
        float yv = 0.0f;
#pragma unroll
        for (int j = 0; j < 8; ++j) {
          bf16x8 cv = *(const bf16x8*)(crow + j * 8);
          for (int e = 0; e < 8; ++e) {
            float x = (float)cv[e] + (float)rv[j][e];
            yv += (x - mean) * rstd * ow[eq * 64 + j * 8 + e];
          }
        }
        yv += __shfl_xor(yv, 1); yv += __shfl_xor(yv, 2);
        if (eq == 0) Y[gm] = yv + ob[0];
      } else {
#pragma unroll
        for (int j = 0; j < 8; ++j) {
          bf16x8 cv = *(const bf16x8*)(crow + j * 8);
          bf16x8 yv8;
          for (int e = 0; e < 8; ++e) {
            float x = (float)cv[e] + (float)rv[j][e];
            yv8[e] = (bf16)((x - mean) * rstd);
          }
          *(bf16x8*)(C + (size_t)gm * 256 + eq * 64 + j * 8) = yv8;
        }
      }
    }
    __syncthreads();
  }
}

// ---------------- conv1 (BK=32): shifted 128x128 GEMM, merged 96 batches ----------------
template <int CIN, int PAD, int SRCW, int SRCROWS, int CHECK, int TRANS, int MTOT>
__global__ __launch_bounds__(256, 2) void k_conv128(
    const bf16* __restrict__ A, const bf16* __restrict__ Bp,
    const float* __restrict__ bias, bf16* __restrict__ C,
    const bf16* __restrict__ zpage) {
  __shared__ alignas(16) bf16 SM[8192];
  bf16* As = SM;
  bf16* Bs = SM + 4096;
  const int t = threadIdx.x, wave = t >> 6;
  const int lane = t & 63, fr = lane & 15, kq = lane >> 4;
  const int wm = wave & 1, wn = wave >> 1;
  const int m0 = blockIdx.x * 128, n0 = blockIdx.y * 128;
  const int srow = t >> 2, kseg = (t & 3) * 8;
  f32x4 acc[4][4] = {};
  int bb[2], yy[2], xx[2];
  for (int hf = 0; hf < 2; ++hf) {
    int m = imin(m0 + hf * 64 + srow, MTOT - 1);
    int b = m / 900, p = m - b * 900;
    bb[hf] = b; yy[hf] = p / 30; xx[hf] = p - (p / 30) * 30;
  }
  bf16* sA0 = As + wave * 512;
  bf16* sA1 = As + 2048 + wave * 512;
  bf16* sB0 = Bs + wave * 512;
  bf16* sB1 = Bs + 2048 + wave * 512;
  for (int k0 = 0; k0 < CIN; k0 += 32) {
    for (int t9 = 0; t9 < 9; ++t9) {
      const int ky = t9 / 3, kx = t9 - ky * 3;
      const bf16* ga[2];
      for (int hf = 0; hf < 2; ++hf) {
        int sy = yy[hf] + ky - PAD, sx = xx[hf] + kx - PAD;
        bool valid = !CHECK || (sy >= 0 && sy < SRCW && sx >= 0 && sx < SRCW);
        ga[hf] = (valid ? A + (size_t)(bb[hf] * SRCROWS + sy * SRCW + sx) * CIN : zpage) + kseg;
      }
      const bf16* gb = Bp + (size_t)(t9 * 256 + n0 + srow) * CIN + kseg;
      gl2lds(ga[0] + k0, sA0);
      gl2lds(ga[1] + k0, sA1);
      gl2lds(gb + k0, sB0);
      gl2lds(gb + (size_t)64 * CIN + k0, sB1);
      __syncthreads();
      bf16x8 af[4], bw[4];
      for (int mt = 0; mt < 4; ++mt)
        af[mt] = *(const bf16x8*)(As + (wm * 64 + mt * 16 + fr) * 32 + kq * 8);
      for (int nt = 0; nt < 4; ++nt)
        bw[nt] = *(const bf16x8*)(Bs + (wn * 64 + nt * 16 + fr) * 32 + kq * 8);
      for (int mt = 0; mt < 4; ++mt)
        for (int nt = 0; nt < 4; ++nt)
          acc[mt][nt] = __builtin_amdgcn_mfma_f32_16x16x32_bf16(af[mt], bw[nt], acc[mt][nt], 0, 0, 0);
      __syncthreads();
    }
  }
  bf16* Cst = SM;
  for (int half = 0; half < 2; ++half) {
    if (wm == half) {
      for (int mt = 0; mt < 4; ++mt)
        for (int nt = 0; nt < 4; ++nt) {
          int n = n0 + wn * 64 + nt * 16 + fr;
          float bv = bias[n];
          for (int r = 0; r < 4; ++r) {
            float v = acc[mt][nt][r] + bv;
            if (TRANS)
              Cst[(wn * 64 + nt * 16 + fr) * 64 + mt * 16 + kq * 4 + r] = (bf16)v;
            else
              Cst[(mt * 16 + kq * 4 + r) * 128 + wn * 64 + nt * 16 + fr] = (bf16)v;
          }
        }
    }
    __syncthreads();
    if (TRANS) {
      for (int i = t; i < 2048; i += 256) {
        int oc = i >> 4, pc = i & 15;
        int gm = m0 + half * 64 + pc * 4;
        if (gm < MTOT) {
          int b = gm / 900, p = gm - b * 900;
          *(bf16x4*)(C + (size_t)(b * 256 + n0 + oc) * 900 + p) = *(const bf16x4*)(Cst + oc * 64 + pc * 4);
        }
      }
    } else {
      for (int i = t; i < 1024; i += 256) {
        int r = i >> 4, cs = i & 15;
        int gm = m0 + half * 64 + r;
        if (gm < MTOT)
          *(bf16x8*)(C + (size_t)gm * 256 + n0 + cs * 8) = *(const bf16x8*)(Cst + r * 128 + cs * 8);
      }
    }
    __syncthreads();
  }
}

// ---------------- conv2 (CIN=256, pad=1): k0-outer/tap-inner (L2-tight), BK=64,
// single-buffered 32 KiB, conflict-free [128][64] swizzled LDS, merged 96 batches ----
__global__ __launch_bounds__(256, 2) void k_conv2x(
    const bf16* __restrict__ A, const bf16* __restrict__ Bp,
    const float* __restrict__ bias, bf16* __restrict__ C,
    const bf16* __restrict__ zpage) {
  __shared__ alignas(16) bf16 SM[16384];
  const int t = threadIdx.x, wave = t >> 6;
  const int lane = t & 63, fr = lane & 15, kq = lane >> 4;
  const int wm = wave & 1, wn = wave >> 1;
  const int m0 = blockIdx.x * 128, n0 = blockIdx.y * 128;
  const int srow = t >> 3;                            // staged row slot (0..31)
  const int sg8 = (((t & 7) ^ (srow & 7)) << 3);      // pre-swizzled source k-seg
  // decode the 4 A-rows this thread stages (positions, clamped)
  int pb[4], py[4], px[4];
#pragma unroll
  for (int r = 0; r < 4; ++r) {
    int m = imin(m0 + r * 32 + srow, 86399);
    int b = m / 900, p = m - b * 900;
    pb[r] = b * 900; py[r] = p / 30; px[r] = p - (p / 30) * 30;
  }
  const int swz = (kq ^ (fr & 7)) << 3;
  const int aoff = (wm * 64 + fr) * 64 + swz;
  const int boff = 8192 + (wn * 64 + fr) * 64 + swz;
  f32x4 acc[4][4] = {};
  for (int k0 = 0; k0 < 256; k0 += 64) {
    for (int t9 = 0; t9 < 9; ++t9) {
      const int ky = t9 / 3, kx = t9 - ky * 3;
      bf16* db = SM + wave * 512;
#pragma unroll
      for (int r = 0; r < 4; ++r) {
        int sy = py[r] + ky - 1, sx = px[r] + kx - 1;
        bool valid = (sy >= 0 && sy < 30 && sx >= 0 && sx < 30);
        const bf16* g = valid ? (A + (size_t)(pb[r] + sy * 30 + sx) * 256 + k0 + sg8)
                              : (zpage + sg8);
        gl2lds(g, db + r * 2048);
      }
#pragma unroll
      for (int r = 0; r < 4; ++r)
        gl2lds(Bp + (size_t)(t9 * 256 + n0 + r * 32 + srow) * 256 + k0 + sg8,
               db + 8192 + r * 2048);
      __syncthreads();
#pragma unroll
      for (int kk = 0; kk < 2; ++kk) {
        const int xo = kk << 5;
        bf16x8 af[4], bw[4];
#pragma unroll
        for (int mt = 0; mt < 4; ++mt)
          af[mt] = *(const bf16x8*)(SM + ((aoff + mt * 1024) ^ xo));
#pragma unroll
        for (int nt = 0; nt < 4; ++nt)
          bw[nt] = *(const bf16x8*)(SM + ((boff + nt * 1024) ^ xo));
#pragma unroll
        for (int mt = 0; mt < 4; ++mt)
#pragma unroll
          for (int nt = 0; nt < 4; ++nt)
            acc[mt][nt] = __builtin_amdgcn_mfma_f32_16x16x32_bf16(af[mt], bw[nt], acc[mt][nt], 0, 0, 0);
      }
      __syncthreads();
    }
  }
  bf16* Cst = SM;  // 128 oc x 68 (padded pitch: conflict-free epilogue)
  for (int half = 0; half < 2; ++half) {
    if (wm == half) {
      for (int mt = 0; mt < 4; ++mt)
        for (int nt = 0; nt < 4; ++nt) {
          int n = n0 + wn * 64 + nt * 16 + fr;
          float bv = bias[n];
          for (int r = 0; r < 4; ++r) {
            float v = acc[mt][nt][r] + bv;
            Cst[(wn * 64 + nt * 16 + fr) * 68 + mt * 16 + kq * 4 + r] = (bf16)v;
          }
        }
    }
    __syncthreads();
    for (int i = t; i < 2048; i += 256) {
      int oc = i >> 4, pc = i & 15;
      int gm = m0 + half * 64 + pc * 4;
      int b = gm / 900, p = gm - b * 900;
      *(bf16x4*)(C + (size_t)(b * 256 + n0 + oc) * 900 + p) = *(const bf16x4*)(Cst + oc * 68 + pc * 4);
    }
    __syncthreads();
  }
}

// ---------------- attention logits z for one (s,h) ----------------
template <int MASKED>
__global__ __launch_bounds__(256, MASKED ? 4 : 5) void k_attn_z(
    const bf16* __restrict__ QKV, const bf16* __restrict__ RelT, bf16* __restrict__ Z,
    const bf16* __restrict__ L1p, const bf16* __restrict__ L2p,
    const float* __restrict__ l1b, const float* __restrict__ l2b) {
  __shared__ alignas(16) bf16 QKs[2][48 * 40];
  __shared__ float EMD[48 * 49];
  __shared__ alignas(16) bf16 zst[48 * 48];
  __shared__ alignas(16) bf16 Sc[MASKED ? 48 * 72 : 8];
  __shared__ alignas(16) bf16 T2b[MASKED ? 48 * 72 : 8];
  const int sh = blockIdx.x, s = sh >> 3, h = sh & 7;
  const int t = threadIdx.x, wave = t >> 6, lane = t & 63, fr = lane & 15, kq = lane >> 4;
  const float scale = 0.17677669529663687f;  // 1/sqrt(32)
  for (int c = t; c < 384; c += 256) {
    int half = c >= 192 ? 1 : 0, cc = c - half * 192;
    int row = cc >> 2, seg = cc & 3;
    *(bf16x8*)(&QKs[half][row * 40 + seg * 8]) =
        *(const bf16x8*)(QKV + (size_t)(s * 48 + row) * 768 + half * 256 + h * 32 + seg * 8);
  }
  if constexpr (MASKED) {
    for (int i = t; i < 768; i += 256) {
      int r = i >> 4, c = 48 + (i & 15);
      Sc[r * 72 + c] = (bf16)0.0f;
      T2b[r * 72 + c] = (bf16)0.0f;
    }
  }
  __syncthreads();
  const bf16* relb = RelT + (size_t)sh * 1536;
  f32x4 sreg[3];
  int u = 0;
  for (int t9 = wave; t9 < 9; t9 += 4, ++u) {
    int ti = t9 / 3, tj = t9 - ti * 3;
    bf16x8 af = *(const bf16x8*)(&QKs[0][(ti * 16 + fr) * 40 + kq * 8]);
    bf16x8 bk = *(const bf16x8*)(&QKs[1][(tj * 16 + fr) * 40 + kq * 8]);
    bf16x8 rf = *(const bf16x8*)(relb + (tj * 16 + fr) * 32 + kq * 8);
    f32x4 sacc = {}, eacc = {};
    sacc = __builtin_amdgcn_mfma_f32_16x16x32_bf16(af, bk, sacc, 0, 0, 0);
    eacc = __builtin_amdgcn_mfma_f32_16x16x32_bf16(af, rf, eacc, 0, 0, 0);
    for (int r = 0; r < 4; ++r)
      EMD[(ti * 16 + kq * 4 + r) * 49 + tj * 16 + fr] = eacc[r];
    if constexpr (MASKED) {
      for (int r = 0; r < 4; ++r)
        Sc[(ti * 16 + kq * 4 + r) * 72 + tj * 16 + fr] = (bf16)(sacc[r] * scale);
    } else {
      for (int r = 0; r < 4; ++r) sreg[u][r] = sacc[r] * scale;
    }
  }
  __syncthreads();
  if constexpr (!MASKED) {
    u = 0;
    for (int t9 = wave; t9 < 9; t9 += 4, ++u) {
      int ti = t9 / 3, tj = t9 - ti * 3;
      for (int r = 0; r < 4; ++r) {
        int i = ti * 16 + kq * 4 + r, j = tj * 16 + fr;
        float v = sreg[u][r];
        if (j <= i) v += EMD[i * 49 + 47 + j - i];
        zst[i * 48 + j] = (bf16)v;
      }
    }
  } else {
    for (int t9 = wave; t9 < 9; t9 += 4) {
      int ti = t9 / 3, tj = t9 - ti * 3;
      f32x4 a2 = {};
      for (int k0 = 0; k0 < 64; k0 += 32) {
        bf16x8 af = *(const bf16x8*)(Sc + (ti * 16 + fr) * 72 + k0 + kq * 8);
        bf16x8 bw = *(const bf16x8*)(L1p + (tj * 16 + fr) * 72 + k0 + kq * 8);
        a2 = __builtin_amdgcn_mfma_f32_16x16x32_bf16(af, bw, a2, 0, 0, 0);
      }
      for (int r = 0; r < 4; ++r) {
        int i = ti * 16 + kq * 4 + r, a = tj * 16 + fr;
        T2b[a * 72 + i] = (bf16)(a2[r] + l1b[a]);
      }
    }
    __syncthreads();
    for (int t9 = wave; t9 < 9; t9 += 4) {
      int ti = t9 / 3, tj = t9 - ti * 3;
      f32x4 a2 = {};
      for (int k0 = 0; k0 < 64; k0 += 32) {
        bf16x8 af = *(const bf16x8*)(T2b + (ti * 16 + fr) * 72 + k0 + kq * 8);
        bf16x8 bw = *(const bf16x8*)(L2p + (tj * 16 + fr) * 72 + k0 + kq * 8);
        a2 = __builtin_amdgcn_mfma_f32_16x16x32_bf16(af, bw, a2, 0, 0, 0);
      }
      for (int r = 0; r < 4; ++r) {
        int aa = ti * 16 + kq * 4 + r, cc = tj * 16 + fr;
        float v;
        if (cc > aa) v = -10000.0f;  // masked column -> exactly uniform after softmax
        else v = a2[r] + l2b[cc] + EMD[aa * 49 + 47 + cc - aa];
        zst[aa * 48 + cc] = (bf16)v;
      }
    }
  }
  __syncthreads();
  bf16* zb = Z + (size_t)sh * 2304;
  for (int c = t; c < 288; c += 256)
    *(bf16x8*)(zb + c * 8) = *(const bf16x8*)(zst + c * 8);
}

// ---------------- per-column (over s=900) online max & inverse-sum ----------------
// grid 288: 64 cols/block (8 thr x 8 cols, bf16x8) x 32 s-groups of 29
__global__ __launch_bounds__(256) void k_colstats(const bf16* __restrict__ Z,
                                                  float* __restrict__ Mc, float* __restrict__ Ic) {
  __shared__ float rm[32][72], rs[32][72];
  const int t = threadIdx.x, cg = t & 7, sg = t >> 3;
  const bf16* p = Z + blockIdx.x * 64 + cg * 8;
  const int s0 = sg * 29, s1 = imin(900, s0 + 29);
  float m[8], ss[8];
  for (int e = 0; e < 8; ++e) { m[e] = -FLT_MAX; ss[e] = 0.0f; }
  for (int s = s0; s < s1; ++s) {
    bf16x8 zv = *(const bf16x8*)(p + (size_t)s * 18432);
    for (int e = 0; e < 8; ++e) {
      float v = (float)zv[e];
      if (v > m[e]) { ss[e] *= __expf(m[e] - v); m[e] = v; }
      ss[e] += __expf(v - m[e]);
    }
  }
  for (int e = 0; e < 8; ++e) { rm[sg][cg * 8 + e] = m[e]; rs[sg][cg * 8 + e] = ss[e]; }
  __syncthreads();
  if (t < 64) {
    float M2 = -FLT_MAX;
    for (int g = 0; g < 32; ++g) M2 = fmaxf(M2, rm[g][t]);
    float S2 = 0.0f;
    for (int g = 0; g < 32; ++g) S2 += rs[g][t] * __expf(rm[g][t] - M2);
    Mc[blockIdx.x * 64 + t] = M2;
    Ic[blockIdx.x * 64 + t] = 1.0f / S2;
  }
}

// ---------------- O[s,h,i,d] = sum_j softmax(Z)[s,h,i,j] V[s,h,j,d] ----------------
__global__ __launch_bounds__(256, 6) void k_attn_av(
    const bf16* __restrict__ Z, const bf16* __restrict__ QKV,
    const float* __restrict__ Mc, const float* __restrict__ Ic, bf16* __restrict__ O) {
  __shared__ alignas(16) bf16 Ps[48 * 72];
  __shared__ alignas(16) bf16 Vt[32 * 72];
  __shared__ alignas(16) bf16 Ost[48 * 32];
  const int sh = blockIdx.x, s = sh >> 3, h = sh & 7;
  const int t = threadIdx.x, wave = t >> 6, lane = t & 63, fr = lane & 15, kq = lane >> 4;
  for (int i = t; i < 768; i += 256) Ps[(i >> 4) * 72 + 48 + (i & 15)] = (bf16)0.0f;
  for (int i = t; i < 512; i += 256) Vt[(i >> 4) * 72 + 48 + (i & 15)] = (bf16)0.0f;
  const bf16* zb = Z + (size_t)sh * 2304;
  const float* mc = Mc + h * 2304;
  const float* ic = Ic + h * 2304;
  for (int c = t; c < 288; c += 256) {
    int r = c / 6, seg = c - r * 6;
    int idx = r * 48 + seg * 8;
    bf16x8 zv = *(const bf16x8*)(zb + idx);
    f32x4 m0v = *(const f32x4*)(mc + idx), m1v = *(const f32x4*)(mc + idx + 4);
    f32x4 i0v = *(const f32x4*)(ic + idx), i1v = *(const f32x4*)(ic + idx + 4);
    bf16x8 pv;
    for (int e = 0; e < 4; ++e) pv[e] = (bf16)(__expf((float)zv[e] - m0v[e]) * i0v[e]);
    for (int e = 0; e < 4; ++e) pv[4 + e] = (bf16)(__expf((float)zv[4 + e] - m1v[e]) * i1v[e]);
    *(bf16x8*)(Ps + r * 72 + seg * 8) = pv;
  }
  for (int c = t; c < 192; c += 256) {
    int j = c >> 2, seg = c & 3;
    bf16x8 v = *(const bf16x8*)(QKV + (size_t)(s * 48 + j) * 768 + 512 + h * 32 + seg * 8);
    for (int e = 0; e < 8; ++e) Vt[(seg * 8 + e) * 72 + j] = v[e];
  }
  __syncthreads();
  for (int t6 = wave; t6 < 6; t6 += 4) {
    int ti = t6 >> 1, td = t6 & 1;
    f32x4 a2 = {};
    for (int k0 = 0; k0 < 64; k0 += 32) {
      bf16x8 af = *(const bf16x8*)(Ps + (ti * 16 + fr) * 72 + k0 + kq * 8);
      bf16x8 bv = *(const bf16x8*)(Vt + (td * 16 + fr) * 72 + k0 + kq * 8);
      a2 = __builtin_amdgcn_mfma_f32_16x16x32_bf16(af, bv, a2, 0, 0, 0);
    }
    for (int r = 0; r < 4; ++r)
      Ost[(ti * 16 + kq * 4 + r) * 32 + td * 16 + fr] = (bf16)a2[r];
  }
  __syncthreads();
  bf16* ob = O + (size_t)sh * 1536;
  for (int c = t; c < 192; c += 256)
    *(bf16x8*)(ob + c * 8) = *(const bf16x8*)(Ost + c * 8);
}

// ---------------- out = LN(Xa + Xb), rows of 256, bf16 ----------------
__global__ __launch_bounds__(256) void k_add_ln(
    const bf16* __restrict__ Xa, const bf16* __restrict__ Xb, bf16* __restrict__ out) {
  const int t = threadIdx.x, lane = t & 63, w = t >> 6;
  const size_t off = ((size_t)blockIdx.x * 4 + w) * 256 + lane * 4;
  bf16x4 av = *(const bf16x4*)(Xa + off);
  bf16x4 bv = *(const bf16x4*)(Xb + off);
  f32x4 x;
  for (int c = 0; c < 4; ++c) x[c] = (float)av[c] + (float)bv[c];
  float sum = x[0] + x[1] + x[2] + x[3];
  for (int o = 1; o < 64; o <<= 1) sum += __shfl_xor(sum, o);
  float mean = sum * (1.0f / 256.0f);
  float q = 0.0f;
  for (int c = 0; c < 4; ++c) { float d = x[c] - mean; q += d * d; }
  for (int o = 1; o < 64; o <<= 1) q += __shfl_xor(q, o);
  float rstd = rsqrtf(q * (1.0f / 256.0f) + 1e-5f);
  bf16x4 y;
  for (int c = 0; c < 4; ++c) y[c] = (bf16)((x[c] - mean) * rstd);
  *(bf16x4*)(out + off) = y;
}

// ---------------- softmax over b (48) per column ----------------
__global__ void k_softmax48(const float* __restrict__ Y, float* __restrict__ O) {
  int ss = blockIdx.x * 256 + threadIdx.x;
  if (ss >= 900) return;
  float m = -FLT_MAX;
  for (int b = 0; b < 48; ++b) m = fmaxf(m, Y[b * 900 + ss]);
  float sum = 0.0f;
  for (int b = 0; b < 48; ++b) sum += __expf(Y[b * 900 + ss] - m);
  float inv = 1.0f / sum;
  for (int b = 0; b < 48; ++b) O[b * 900 + ss] = __expf(Y[b * 900 + ss] - m) * inv;
}

extern "C" void kernel_launch(void* const* d_in, const int* in_sizes, int n_in,
                              void* d_out, int out_size, void* d_ws, size_t ws_size,
                              hipStream_t stream) {
  (void)in_sizes; (void)n_in; (void)out_size;
  const float* X_en = (const float*)d_in[0];
  const float* X_de = (const float*)d_in[1];
  const float* conv1_w = (const float*)d_in[2];
  const float* conv1_b = (const float*)d_in[3];
  const float* conv2_w = (const float*)d_in[4];
  const float* conv2_b = (const float*)d_in[5];
  const float* enc_wq = (const float*)d_in[6];
  const float* enc_wk = (const float*)d_in[7];
  const float* enc_wv = (const float*)d_in[8];
  const float* enc_rel = (const float*)d_in[9];
  const float* enc_f1w = (const float*)d_in[10];
  const float* enc_f1b = (const float*)d_in[11];
  const float* enc_f2w = (const float*)d_in[12];
  const float* enc_f2b = (const float*)d_in[13];
  const float* dm_wq = (const float*)d_in[14];
  const float* dm_wk = (const float*)d_in[15];
  const float* dm_wv = (const float*)d_in[16];
  const float* dm_rel = (const float*)d_in[17];
  const float* dm_l1w = (const float*)d_in[18];
  const float* dm_l1b = (const float*)d_in[19];
  const float* dm_l2w = (const float*)d_in[20];
  const float* dm_l2b = (const float*)d_in[21];
  const float* dc_wq = (const float*)d_in[22];
  const float* dc_wk = (const float*)d_in[23];
  const float* dc_wv = (const float*)d_in[24];
  const float* dc_rel = (const float*)d_in[25];
  const float* d_f1w = (const float*)d_in[26];
  const float* d_f1b = (const float*)d_in[27];
  const float* d_f2w = (const float*)d_in[28];
  const float* d_f2b = (const float*)d_in[29];
  const float* out_w = (const float*)d_in[30];
  const float* out_b = (const float*)d_in[31];
  float* OUT = (float*)d_out;

  // ---- workspace layout ----
  const size_t SLOT = 22118400;  // 43200*256 bf16
  char* ws = (char*)d_ws;
  size_t o = 0;
  bf16* S1 = (bf16*)(ws + o); o += SLOT;  // XEb -> ENCb
  bf16* S2 = (bf16*)(ws + o); o += SLOT;  // XDb -> (cross stats)
  bf16* S3 = (bf16*)(ws + o); o += SLOT;  // (enc RelT) -> o1 -> (dm stats) -> (cross RelT) -> h2
  bf16* S4 = (bf16*)(ws + o); o += SLOT;  // (enc stats) -> h1
  bf16* S5 = (bf16*)(ws + o); o += SLOT;  // attn-out / (dm RelT)
  char* U = ws + o; o += 33177600 + 3 * SLOT;  // Z + QKV, union { HID, XR+C1R }
  bf16* Zb = (bf16*)U;
  bf16* QKV = (bf16*)(U + 33177600);
  bf16* XR = (bf16*)U;                    // conv phase: 96*1024*32 bf16 = 12.6 MB
  bf16* C1R = (bf16*)(U + 12582912);      // conv phase: 96*900*256 bf16 = 44.2 MB
  bf16* HID = (bf16*)U;                   // FFN phase only
  bf16* wa = (bf16*)(ws + o); o += 4603904 + 16384;
  float* Y = (float*)(ws + o); o += 172800;
  if (ws_size < o) return;

  bf16* zpage = (bf16*)Y;  // 512 B zero page; Y dead until dec FFN2 writes it
  float* encM = (float*)S4; float* encI = encM + 18432;
  float* dmM  = (float*)S3; float* dmI  = dmM + 18432;
  float* crM  = (float*)S2; float* crI  = crM + 18432;
  bf16* encRel = S3;   // free until o1 written
  bf16* dmRel  = S5;   // free until dm attn_av writes S5
  bf16* crRel  = S3;   // o1 dead after enc_out

  // weight arena (element offsets)
  bf16* c1p = wa;
  bf16* c2p = wa + 73728;
  bf16* EQKVw = wa + 663552;
  bf16* MQKVw = wa + 860160;
  bf16* cqw = wa + 1056768;
  bf16* CKVw = wa + 1122304;
  bf16* ef1 = wa + 1253376;
  bf16* ef2 = wa + 1515520;
  bf16* df1 = wa + 1777664;
  bf16* df2 = wa + 2039808;
  bf16* L1p = wa + 2301952;
  bf16* L2p = wa + 2305408;

  auto gemm = [&](const bf16* A, const bf16* B, const float* bias, bf16* C,
                  int M, int N, int K, int relu, int ldc, int coff) {
    k_gemm128<<<dim3((M + 127) / 128, N / 128), dim3(256), 0, stream>>>(
        A, A, B, B, N, bias, C, M, N, K, relu, ldc, coff);
  };

  // ---- weight prep ----
  k_prep_misc<<<dim3(1), dim3(256), 0, stream>>>(zpage, dm_l1w, dm_l2w, L1p, L2p);
  k_pack_conv<<<dim3(288), dim3(256), 0, stream>>>(conv1_w, c1p, 256, 32, 73728);
  k_pack_conv<<<dim3(2304), dim3(256), 0, stream>>>(conv2_w, c2p, 256, 256, 589824);
  {
    CastSegs sg;
    const float* srcs[13] = {enc_wq, enc_wk, enc_wv, dm_wq, dm_wk, dm_wv, dc_wq,
                             dc_wk, dc_wv, enc_f1w, enc_f2w, d_f1w, d_f2w};
    bf16* dsts[13] = {EQKVw, EQKVw + 65536, EQKVw + 131072, MQKVw, MQKVw + 65536,
                      MQKVw + 131072, cqw, CKVw, CKVw + 65536, ef1, ef2, df1, df2};
    int ns[13] = {65536, 65536, 65536, 65536, 65536, 65536, 65536, 65536, 65536,
                  262144, 262144, 262144, 262144};
    int total = 0;
    for (int k = 0; k < 13; ++k) { sg.s[k] = srcs[k]; sg.d[k] = dsts[k]; sg.n[k] = ns[k]; total += ns[k]; }
    k_cast_all<<<dim3((total + 255) / 256), dim3(256), 0, stream>>>(sg, total);
  }

  // ---- merged conv chain (96 batches: en then de; conv2 writes S1||S2 contiguously) ----
  k_prep_x<<<dim3(12288), dim3(256), 0, stream>>>(X_en, X_de, XR);
  k_conv128<32, 0, 32, 1024, 0, 0, 86400><<<dim3(675, 2), dim3(256), 0, stream>>>(
      XR, c1p, conv1_b, C1R, zpage);
  k_conv2x<<<dim3(675, 2), dim3(256), 0, stream>>>(C1R, c2p, conv2_b, S1, zpage);

  // ---- encoder ----
  gemm(S1, EQKVw, nullptr, QKV, 43200, 768, 256, 0, 768, 0);
  k_prep_rel<<<dim3(900), dim3(256), 0, stream>>>(enc_rel, encRel);
  k_attn_z<0><<<dim3(7200), dim3(256), 0, stream>>>(QKV, encRel, Zb, nullptr, nullptr, nullptr, nullptr);
  k_colstats<<<dim3(288), dim3(256), 0, stream>>>(Zb, encM, encI);
  k_attn_av<<<dim3(7200), dim3(256), 0, stream>>>(Zb, QKV, encM, encI, S5);
  k_add_ln<<<dim3(10800), dim3(256), 0, stream>>>(S1, S5, S3);  // o1
  gemm(S3, ef1, enc_f1b, HID, 43200, 1024, 256, 1, 1024, 0);
  // enc_out = LN(o1 + FFN2(HID)) fused
  k_ffn2ln<0><<<dim3(338), dim3(256), 0, stream>>>(
      HID, ef2, enc_f2b, S3, S1, nullptr, nullptr, nullptr, 43200);

  // ---- decoder masked self-attention ----
  gemm(S2, MQKVw, nullptr, QKV, 43200, 768, 256, 0, 768, 0);
  k_prep_rel<<<dim3(900), dim3(256), 0, stream>>>(dm_rel, dmRel);
  k_attn_z<1><<<dim3(7200), dim3(256), 0, stream>>>(QKV, dmRel, Zb, L1p, L2p, dm_l1b, dm_l2b);
  k_colstats<<<dim3(288), dim3(256), 0, stream>>>(Zb, dmM, dmI);
  k_attn_av<<<dim3(7200), dim3(256), 0, stream>>>(Zb, QKV, dmM, dmI, S5);
  k_add_ln<<<dim3(10800), dim3(256), 0, stream>>>(S2, S5, S4);  // h1

  // ---- cross attention (q + kv merged into one dual-GEMM launch) ----
  k_gemm128<<<dim3(338, 6), dim3(256), 0, stream>>>(
      S4, S1, cqw, CKVw, 256, nullptr, QKV, 43200, 768, 256, 0, 768, 0);
  k_prep_rel<<<dim3(900), dim3(256), 0, stream>>>(dc_rel, crRel);
  k_attn_z<0><<<dim3(7200), dim3(256), 0, stream>>>(QKV, crRel, Zb, nullptr, nullptr, nullptr, nullptr);
  k_colstats<<<dim3(288), dim3(256), 0, stream>>>(Zb, crM, crI);
  k_attn_av<<<dim3(7200), dim3(256), 0, stream>>>(Zb, QKV, crM, crI, S5);
  k_add_ln<<<dim3(10800), dim3(256), 0, stream>>>(S5, S4, S3);  // h2 = ln(c + h1)

  // ---- decoder FFN + head ----
  gemm(S3, df1, d_f1b, HID, 43200, 1024, 256, 1, 1024, 0);
  // Y[m] = dot(LN(h2 + FFN2(HID)), out_w) + out_b, fused (h3 never materialized)
  k_ffn2ln<1><<<dim3(338), dim3(256), 0, stream>>>(
      HID, df2, d_f2b, S3, nullptr, out_w, out_b, Y, 43200);
  k_softmax48<<<dim3(4), dim3(256), 0, stream>>>(Y, OUT);
}

// Round 6
// 1009.263 us; speedup vs baseline: 1.0178x; 1.0178x over previous
//
#include <hip/hip_runtime.h>
#include <float.h>

typedef __bf16 bf16;
typedef __attribute__((ext_vector_type(8))) __bf16 bf16x8;
typedef __attribute__((ext_vector_type(4))) __bf16 bf16x4;
typedef __attribute__((ext_vector_type(4))) float f32x4;

__device__ __forceinline__ int imin(int a, int b) { return a < b ? a : b; }

// async global->LDS, 16B per lane; LDS dest = wave-uniform base + lane*16
__device__ __forceinline__ void gl2lds(const bf16* g, bf16* l) {
  __builtin_amdgcn_global_load_lds(
      (const __attribute__((address_space(1))) void*)g,
      (__attribute__((address_space(3))) void*)l, 16, 0, 0);
}

// ---------------- zero-page + padded lin weights (fused tiny prep) ----------------
__global__ void k_prep_misc(bf16* zp, const float* __restrict__ l1w,
                            const float* __restrict__ l2w,
                            bf16* __restrict__ L1p, bf16* __restrict__ L2p) {
  zp[threadIdx.x] = (bf16)0.0f;
  for (int i = threadIdx.x; i < 3456; i += 256) {
    int r = i / 72, c = i - r * 72;
    L1p[i] = (c < 48) ? (bf16)l1w[r * 48 + c] : (bf16)0.0f;
    L2p[i] = (c < 48) ? (bf16)l2w[r * 48 + c] : (bf16)0.0f;
  }
}

// ---------------- fused f32->bf16 casts (13 segments) ----------------
struct CastSegs { const float* s[13]; bf16* d[13]; int n[13]; };
__global__ void k_cast_all(CastSegs sg, int total) {
  int i = blockIdx.x * 256 + threadIdx.x;
  if (i >= total) return;
  for (int k = 0; k < 13; ++k) {
    if (i < sg.n[k]) { sg.d[k][i] = (bf16)sg.s[k][i]; return; }
    i -= sg.n[k];
  }
}

// ---------------- rel transpose via LDS: (sh, k*48+j) fp32 -> (sh, j*32+k) bf16 ----------------
__global__ __launch_bounds__(256) void k_prep_rel(const float* __restrict__ rel,
                                                  bf16* __restrict__ RelT) {
  __shared__ float tile[32 * 49];
  const int t = threadIdx.x;
  for (int u = 0; u < 8; ++u) {
    const size_t sh = (size_t)blockIdx.x * 8 + u;
    const float* src = rel + sh * 1536;
    bf16* dst = RelT + sh * 1536;
    __syncthreads();
    for (int i = t; i < 1536; i += 256) {
      int k = i / 48, j = i - k * 48;
      tile[k * 49 + j] = src[i];
    }
    __syncthreads();
    for (int i = t; i < 1536; i += 256) {
      int j = i >> 5, k = i & 31;
      dst[i] = (bf16)tile[k * 49 + j];
    }
  }
}

// ---------------- X_en|X_de (b,32,32,32) -> XR rows (96*1024, 32ch) bf16 ----------------
__global__ void k_prep_x(const float* __restrict__ XE, const float* __restrict__ XD,
                         bf16* __restrict__ XR) {
  int idx = blockIdx.x * 256 + threadIdx.x;
  if (idx >= 96 * 1024 * 32) return;
  int b = idx >> 15, r = idx & 32767, pos = r >> 5, ic = r & 31;
  const float* X = (b < 48) ? XE : XD;
  int bl = (b < 48) ? b : b - 48;
  XR[idx] = (bf16)X[((size_t)(bl * 32 + ic) << 10) + pos];
}

// ---------------- conv weight pack: (OC,IC,3,3) -> 9 x (OC,IC) bf16 ----------------
__global__ void k_pack_conv(const float* __restrict__ w, bf16* __restrict__ dst,
                            int OC, int IC, int total) {
  int idx = blockIdx.x * 256 + threadIdx.x;
  if (idx >= total) return;
  int t = idx / (OC * IC);
  int rem = idx - t * OC * IC;
  int oc = rem / IC, ic = rem - oc * IC;
  dst[idx] = (bf16)w[(size_t)(oc * IC + ic) * 9 + t];
}

// ---------------- 128x128 GEMM, BK=64, single-buffered, conflict-free LDS ----------
// LDS: A [128][64] at 0, B [128][64] at +8192 (128-B row pitch).
// Swizzle involution: seg' = seg ^ (row&7) (16-B segs, 8/row); gl2lds dest linear,
// SOURCE pre-swizzled, reads swizzled with the same XOR.
// If n0 >= nsplit: use A2/B2 with local n (merged dual-GEMM launch). K%64==0, N%128==0.
__global__ __launch_bounds__(256, 2) void k_gemm128(
    const bf16* __restrict__ A, const bf16* __restrict__ A2,
    const bf16* __restrict__ B, const bf16* __restrict__ B2, int nsplit,
    const float* __restrict__ bias, bf16* __restrict__ C,
    int M, int N, int K, int relu, int ldc, int coff) {
  __shared__ alignas(16) bf16 SM[16384];
  const int t = threadIdx.x, wave = t >> 6;
  const int lane = t & 63, fr = lane & 15, kq = lane >> 4;
  const int wm = wave & 1, wn = wave >> 1;
  const int m0 = blockIdx.x * 128, n0 = blockIdx.y * 128;
  const bf16* Ause = A; const bf16* Buse = B; int nloc = n0;
  if (n0 >= nsplit) { Ause = A2; Buse = B2; nloc = n0 - nsplit; }
  // staging map: thread t covers (row = r*32 + (t>>3), seg = t&7), r = 0..3 for A and B
  const int srow = t >> 3;
  const int sg8 = (((t & 7) ^ (srow & 7)) << 3);  // pre-swizzled source k-seg (elements)
  const bf16* gA[4]; const bf16* gB[4];
#pragma unroll
  for (int r = 0; r < 4; ++r) {
    gA[r] = Ause + (size_t)imin(m0 + r * 32 + srow, M - 1) * K + sg8;
    gB[r] = Buse + (size_t)(nloc + r * 32 + srow) * K + sg8;
  }
  // fragment-read offsets (elements); ^32 switches k-halves
  const int swz = (kq ^ (fr & 7)) << 3;
  const int aoff = (wm * 64 + fr) * 64 + swz;
  const int boff = 8192 + (wn * 64 + fr) * 64 + swz;
  f32x4 acc[4][4] = {};
  for (int k0 = 0; k0 < K; k0 += 64) {
    bf16* db = SM + wave * 512;
#pragma unroll
    for (int r = 0; r < 4; ++r) gl2lds(gA[r] + k0, db + r * 2048);
#pragma unroll
    for (int r = 0; r < 4; ++r) gl2lds(gB[r] + k0, db + 8192 + r * 2048);
    __syncthreads();
#pragma unroll
    for (int kk = 0; kk < 2; ++kk) {
      const int xo = kk << 5;
      bf16x8 af[4], bw[4];
#pragma unroll
      for (int mt = 0; mt < 4; ++mt)
        af[mt] = *(const bf16x8*)(SM + ((aoff + mt * 1024) ^ xo));
#pragma unroll
      for (int nt = 0; nt < 4; ++nt)
        bw[nt] = *(const bf16x8*)(SM + ((boff + nt * 1024) ^ xo));
#pragma unroll
      for (int mt = 0; mt < 4; ++mt)
#pragma unroll
        for (int nt = 0; nt < 4; ++nt)
          acc[mt][nt] = __builtin_amdgcn_mfma_f32_16x16x32_bf16(af[mt], bw[nt], acc[mt][nt], 0, 0, 0);
    }
    __syncthreads();
  }
  bf16* Cst = SM;  // 64 x 136 (padded pitch: conflict-free epilogue)
  for (int half = 0; half < 2; ++half) {
    if (wm == half) {
      for (int mt = 0; mt < 4; ++mt)
        for (int nt = 0; nt < 4; ++nt) {
          int n = n0 + wn * 64 + nt * 16 + fr;
          float bv = bias ? bias[n] : 0.0f;
          for (int r = 0; r < 4; ++r) {
            float v = acc[mt][nt][r] + bv;
            if (relu) v = fmaxf(v, 0.0f);
            Cst[(mt * 16 + kq * 4 + r) * 136 + wn * 64 + nt * 16 + fr] = (bf16)v;
          }
        }
    }
    __syncthreads();
    for (int i = t; i < 1024; i += 256) {
      int r = i >> 4, cs = i & 15;
      int gm = m0 + half * 64 + r;
      if (gm < M)
        *(bf16x8*)(C + (size_t)gm * ldc + coff + n0 + cs * 8) = *(const bf16x8*)(Cst + r * 136 + cs * 8);
    }
    __syncthreads();
  }
}

// ---------------- conv1 (BK=32): shifted 128x128 GEMM, merged 96 batches ----------------
template <int CIN, int PAD, int SRCW, int SRCROWS, int CHECK, int TRANS, int MTOT>
__global__ __launch_bounds__(256, 2) void k_conv128(
    const bf16* __restrict__ A, const bf16* __restrict__ Bp,
    const float* __restrict__ bias, bf16* __restrict__ C,
    const bf16* __restrict__ zpage) {
  __shared__ alignas(16) bf16 SM[8192];
  bf16* As = SM;
  bf16* Bs = SM + 4096;
  const int t = threadIdx.x, wave = t >> 6;
  const int lane = t & 63, fr = lane & 15, kq = lane >> 4;
  const int wm = wave & 1, wn = wave >> 1;
  const int m0 = blockIdx.x * 128, n0 = blockIdx.y * 128;
  const int srow = t >> 2, kseg = (t & 3) * 8;
  f32x4 acc[4][4] = {};
  int bb[2], yy[2], xx[2];
  for (int hf = 0; hf < 2; ++hf) {
    int m = imin(m0 + hf * 64 + srow, MTOT - 1);
    int b = m / 900, p = m - b * 900;
    bb[hf] = b; yy[hf] = p / 30; xx[hf] = p - (p / 30) * 30;
  }
  bf16* sA0 = As + wave * 512;
  bf16* sA1 = As + 2048 + wave * 512;
  bf16* sB0 = Bs + wave * 512;
  bf16* sB1 = Bs + 2048 + wave * 512;
  for (int k0 = 0; k0 < CIN; k0 += 32) {
    for (int t9 = 0; t9 < 9; ++t9) {
      const int ky = t9 / 3, kx = t9 - ky * 3;
      const bf16* ga[2];
      for (int hf = 0; hf < 2; ++hf) {
        int sy = yy[hf] + ky - PAD, sx = xx[hf] + kx - PAD;
        bool valid = !CHECK || (sy >= 0 && sy < SRCW && sx >= 0 && sx < SRCW);
        ga[hf] = (valid ? A + (size_t)(bb[hf] * SRCROWS + sy * SRCW + sx) * CIN : zpage) + kseg;
      }
      const bf16* gb = Bp + (size_t)(t9 * 256 + n0 + srow) * CIN + kseg;
      gl2lds(ga[0] + k0, sA0);
      gl2lds(ga[1] + k0, sA1);
      gl2lds(gb + k0, sB0);
      gl2lds(gb + (size_t)64 * CIN + k0, sB1);
      __syncthreads();
      bf16x8 af[4], bw[4];
      for (int mt = 0; mt < 4; ++mt)
        af[mt] = *(const bf16x8*)(As + (wm * 64 + mt * 16 + fr) * 32 + kq * 8);
      for (int nt = 0; nt < 4; ++nt)
        bw[nt] = *(const bf16x8*)(Bs + (wn * 64 + nt * 16 + fr) * 32 + kq * 8);
      for (int mt = 0; mt < 4; ++mt)
        for (int nt = 0; nt < 4; ++nt)
          acc[mt][nt] = __builtin_amdgcn_mfma_f32_16x16x32_bf16(af[mt], bw[nt], acc[mt][nt], 0, 0, 0);
      __syncthreads();
    }
  }
  bf16* Cst = SM;
  for (int half = 0; half < 2; ++half) {
    if (wm == half) {
      for (int mt = 0; mt < 4; ++mt)
        for (int nt = 0; nt < 4; ++nt) {
          int n = n0 + wn * 64 + nt * 16 + fr;
          float bv = bias[n];
          for (int r = 0; r < 4; ++r) {
            float v = acc[mt][nt][r] + bv;
            if (TRANS)
              Cst[(wn * 64 + nt * 16 + fr) * 64 + mt * 16 + kq * 4 + r] = (bf16)v;
            else
              Cst[(mt * 16 + kq * 4 + r) * 128 + wn * 64 + nt * 16 + fr] = (bf16)v;
          }
        }
    }
    __syncthreads();
    if (TRANS) {
      for (int i = t; i < 2048; i += 256) {
        int oc = i >> 4, pc = i & 15;
        int gm = m0 + half * 64 + pc * 4;
        if (gm < MTOT) {
          int b = gm / 900, p = gm - b * 900;
          *(bf16x4*)(C + (size_t)(b * 256 + n0 + oc) * 900 + p) = *(const bf16x4*)(Cst + oc * 64 + pc * 4);
        }
      }
    } else {
      for (int i = t; i < 1024; i += 256) {
        int r = i >> 4, cs = i & 15;
        int gm = m0 + half * 64 + r;
        if (gm < MTOT)
          *(bf16x8*)(C + (size_t)gm * 256 + n0 + cs * 8) = *(const bf16x8*)(Cst + r * 128 + cs * 8);
      }
    }
    __syncthreads();
  }
}

// ---------------- conv2 (CIN=256, pad=1): k0-outer/tap-inner (L2-tight), BK=64,
// single-buffered 32 KiB, conflict-free [128][64] swizzled LDS, merged 96 batches ----
__global__ __launch_bounds__(256, 2) void k_conv2x(
    const bf16* __restrict__ A, const bf16* __restrict__ Bp,
    const float* __restrict__ bias, bf16* __restrict__ C,
    const bf16* __restrict__ zpage) {
  __shared__ alignas(16) bf16 SM[16384];
  const int t = threadIdx.x, wave = t >> 6;
  const int lane = t & 63, fr = lane & 15, kq = lane >> 4;
  const int wm = wave & 1, wn = wave >> 1;
  const int m0 = blockIdx.x * 128, n0 = blockIdx.y * 128;
  const int srow = t >> 3;                            // staged row slot (0..31)
  const int sg8 = (((t & 7) ^ (srow & 7)) << 3);      // pre-swizzled source k-seg
  // decode the 4 A-rows this thread stages (positions, clamped)
  int pb[4], py[4], px[4];
#pragma unroll
  for (int r = 0; r < 4; ++r) {
    int m = imin(m0 + r * 32 + srow, 86399);
    int b = m / 900, p = m - b * 900;
    pb[r] = b * 900; py[r] = p / 30; px[r] = p - (p / 30) * 30;
  }
  const int swz = (kq ^ (fr & 7)) << 3;
  const int aoff = (wm * 64 + fr) * 64 + swz;
  const int boff = 8192 + (wn * 64 + fr) * 64 + swz;
  f32x4 acc[4][4] = {};
  for (int k0 = 0; k0 < 256; k0 += 64) {
    for (int t9 = 0; t9 < 9; ++t9) {
      const int ky = t9 / 3, kx = t9 - ky * 3;
      bf16* db = SM + wave * 512;
#pragma unroll
      for (int r = 0; r < 4; ++r) {
        int sy = py[r] + ky - 1, sx = px[r] + kx - 1;
        bool valid = (sy >= 0 && sy < 30 && sx >= 0 && sx < 30);
        const bf16* g = valid ? (A + (size_t)(pb[r] + sy * 30 + sx) * 256 + k0 + sg8)
                              : (zpage + sg8);
        gl2lds(g, db + r * 2048);
      }
#pragma unroll
      for (int r = 0; r < 4; ++r)
        gl2lds(Bp + (size_t)(t9 * 256 + n0 + r * 32 + srow) * 256 + k0 + sg8,
               db + 8192 + r * 2048);
      __syncthreads();
#pragma unroll
      for (int kk = 0; kk < 2; ++kk) {
        const int xo = kk << 5;
        bf16x8 af[4], bw[4];
#pragma unroll
        for (int mt = 0; mt < 4; ++mt)
          af[mt] = *(const bf16x8*)(SM + ((aoff + mt * 1024) ^ xo));
#pragma unroll
        for (int nt = 0; nt < 4; ++nt)
          bw[nt] = *(const bf16x8*)(SM + ((boff + nt * 1024) ^ xo));
#pragma unroll
        for (int mt = 0; mt < 4; ++mt)
#pragma unroll
          for (int nt = 0; nt < 4; ++nt)
            acc[mt][nt] = __builtin_amdgcn_mfma_f32_16x16x32_bf16(af[mt], bw[nt], acc[mt][nt], 0, 0, 0);
      }
      __syncthreads();
    }
  }
  bf16* Cst = SM;  // 128 oc x 68 (padded pitch: conflict-free epilogue)
  for (int half = 0; half < 2; ++half) {
    if (wm == half) {
      for (int mt = 0; mt < 4; ++mt)
        for (int nt = 0; nt < 4; ++nt) {
          int n = n0 + wn * 64 + nt * 16 + fr;
          float bv = bias[n];
          for (int r = 0; r < 4; ++r) {
            float v = acc[mt][nt][r] + bv;
            Cst[(wn * 64 + nt * 16 + fr) * 68 + mt * 16 + kq * 4 + r] = (bf16)v;
          }
        }
    }
    __syncthreads();
    for (int i = t; i < 2048; i += 256) {
      int oc = i >> 4, pc = i & 15;
      int gm = m0 + half * 64 + pc * 4;
      int b = gm / 900, p = gm - b * 900;
      *(bf16x4*)(C + (size_t)(b * 256 + n0 + oc) * 900 + p) = *(const bf16x4*)(Cst + oc * 68 + pc * 4);
    }
    __syncthreads();
  }
}

// ---------------- attention logits z for one (s,h) ----------------
template <int MASKED>
__global__ __launch_bounds__(256, MASKED ? 4 : 5) void k_attn_z(
    const bf16* __restrict__ QKV, const bf16* __restrict__ RelT, bf16* __restrict__ Z,
    const bf16* __restrict__ L1p, const bf16* __restrict__ L2p,
    const float* __restrict__ l1b, const float* __restrict__ l2b) {
  __shared__ alignas(16) bf16 QKs[2][48 * 40];
  __shared__ float EMD[48 * 49];
  __shared__ alignas(16) bf16 zst[48 * 48];
  __shared__ alignas(16) bf16 Sc[MASKED ? 48 * 72 : 8];
  __shared__ alignas(16) bf16 T2b[MASKED ? 48 * 72 : 8];
  const int sh = blockIdx.x, s = sh >> 3, h = sh & 7;
  const int t = threadIdx.x, wave = t >> 6, lane = t & 63, fr = lane & 15, kq = lane >> 4;
  const float scale = 0.17677669529663687f;  // 1/sqrt(32)
  for (int c = t; c < 384; c += 256) {
    int half = c >= 192 ? 1 : 0, cc = c - half * 192;
    int row = cc >> 2, seg = cc & 3;
    *(bf16x8*)(&QKs[half][row * 40 + seg * 8]) =
        *(const bf16x8*)(QKV + (size_t)(s * 48 + row) * 768 + half * 256 + h * 32 + seg * 8);
  }
  if constexpr (MASKED) {
    for (int i = t; i < 768; i += 256) {
      int r = i >> 4, c = 48 + (i & 15);
      Sc[r * 72 + c] = (bf16)0.0f;
      T2b[r * 72 + c] = (bf16)0.0f;
    }
  }
  __syncthreads();
  const bf16* relb = RelT + (size_t)sh * 1536;
  f32x4 sreg[3];
  int u = 0;
  for (int t9 = wave; t9 < 9; t9 += 4, ++u) {
    int ti = t9 / 3, tj = t9 - ti * 3;
    bf16x8 af = *(const bf16x8*)(&QKs[0][(ti * 16 + fr) * 40 + kq * 8]);
    bf16x8 bk = *(const bf16x8*)(&QKs[1][(tj * 16 + fr) * 40 + kq * 8]);
    bf16x8 rf = *(const bf16x8*)(relb + (tj * 16 + fr) * 32 + kq * 8);
    f32x4 sacc = {}, eacc = {};
    sacc = __builtin_amdgcn_mfma_f32_16x16x32_bf16(af, bk, sacc, 0, 0, 0);
    eacc = __builtin_amdgcn_mfma_f32_16x16x32_bf16(af, rf, eacc, 0, 0, 0);
    for (int r = 0; r < 4; ++r)
      EMD[(ti * 16 + kq * 4 + r) * 49 + tj * 16 + fr] = eacc[r];
    if constexpr (MASKED) {
      for (int r = 0; r < 4; ++r)
        Sc[(ti * 16 + kq * 4 + r) * 72 + tj * 16 + fr] = (bf16)(sacc[r] * scale);
    } else {
      for (int r = 0; r < 4; ++r) sreg[u][r] = sacc[r] * scale;
    }
  }
  __syncthreads();
  if constexpr (!MASKED) {
    u = 0;
    for (int t9 = wave; t9 < 9; t9 += 4, ++u) {
      int ti = t9 / 3, tj = t9 - ti * 3;
      for (int r = 0; r < 4; ++r) {
        int i = ti * 16 + kq * 4 + r, j = tj * 16 + fr;
        float v = sreg[u][r];
        if (j <= i) v += EMD[i * 49 + 47 + j - i];
        zst[i * 48 + j] = (bf16)v;
      }
    }
  } else {
    for (int t9 = wave; t9 < 9; t9 += 4) {
      int ti = t9 / 3, tj = t9 - ti * 3;
      f32x4 a2 = {};
      for (int k0 = 0; k0 < 64; k0 += 32) {
        bf16x8 af = *(const bf16x8*)(Sc + (ti * 16 + fr) * 72 + k0 + kq * 8);
        bf16x8 bw = *(const bf16x8*)(L1p + (tj * 16 + fr) * 72 + k0 + kq * 8);
        a2 = __builtin_amdgcn_mfma_f32_16x16x32_bf16(af, bw, a2, 0, 0, 0);
      }
      for (int r = 0; r < 4; ++r) {
        int i = ti * 16 + kq * 4 + r, a = tj * 16 + fr;
        T2b[a * 72 + i] = (bf16)(a2[r] + l1b[a]);
      }
    }
    __syncthreads();
    for (int t9 = wave; t9 < 9; t9 += 4) {
      int ti = t9 / 3, tj = t9 - ti * 3;
      f32x4 a2 = {};
      for (int k0 = 0; k0 < 64; k0 += 32) {
        bf16x8 af = *(const bf16x8*)(T2b + (ti * 16 + fr) * 72 + k0 + kq * 8);
        bf16x8 bw = *(const bf16x8*)(L2p + (tj * 16 + fr) * 72 + k0 + kq * 8);
        a2 = __builtin_amdgcn_mfma_f32_16x16x32_bf16(af, bw, a2, 0, 0, 0);
      }
      for (int r = 0; r < 4; ++r) {
        int aa = ti * 16 + kq * 4 + r, cc = tj * 16 + fr;
        float v;
        if (cc > aa) v = -10000.0f;  // masked column -> exactly uniform after softmax
        else v = a2[r] + l2b[cc] + EMD[aa * 49 + 47 + cc - aa];
        zst[aa * 48 + cc] = (bf16)v;
      }
    }
  }
  __syncthreads();
  bf16* zb = Z + (size_t)sh * 2304;
  for (int c = t; c < 288; c += 256)
    *(bf16x8*)(zb + c * 8) = *(const bf16x8*)(zst + c * 8);
}

// ---------------- per-column (over s=900) online max & inverse-sum ----------------
// grid 288: 64 cols/block (8 thr x 8 cols, bf16x8) x 32 s-groups of 29
__global__ __launch_bounds__(256) void k_colstats(const bf16* __restrict__ Z,
                                                  float* __restrict__ Mc, float* __restrict__ Ic) {
  __shared__ float rm[32][72], rs[32][72];
  const int t = threadIdx.x, cg = t & 7, sg = t >> 3;
  const bf16* p = Z + blockIdx.x * 64 + cg * 8;
  const int s0 = sg * 29, s1 = imin(900, s0 + 29);
  float m[8], ss[8];
  for (int e = 0; e < 8; ++e) { m[e] = -FLT_MAX; ss[e] = 0.0f; }
  for (int s = s0; s < s1; ++s) {
    bf16x8 zv = *(const bf16x8*)(p + (size_t)s * 18432);
    for (int e = 0; e < 8; ++e) {
      float v = (float)zv[e];
      if (v > m[e]) { ss[e] *= __expf(m[e] - v); m[e] = v; }
      ss[e] += __expf(v - m[e]);
    }
  }
  for (int e = 0; e < 8; ++e) { rm[sg][cg * 8 + e] = m[e]; rs[sg][cg * 8 + e] = ss[e]; }
  __syncthreads();
  if (t < 64) {
    float M2 = -FLT_MAX;
    for (int g = 0; g < 32; ++g) M2 = fmaxf(M2, rm[g][t]);
    float S2 = 0.0f;
    for (int g = 0; g < 32; ++g) S2 += rs[g][t] * __expf(rm[g][t] - M2);
    Mc[blockIdx.x * 64 + t] = M2;
    Ic[blockIdx.x * 64 + t] = 1.0f / S2;
  }
}

// ---------------- O[s,h,i,d] = sum_j softmax(Z)[s,h,i,j] V[s,h,j,d] ----------------
__global__ __launch_bounds__(256, 6) void k_attn_av(
    const bf16* __restrict__ Z, const bf16* __restrict__ QKV,
    const float* __restrict__ Mc, const float* __restrict__ Ic, bf16* __restrict__ O) {
  __shared__ alignas(16) bf16 Ps[48 * 72];
  __shared__ alignas(16) bf16 Vt[32 * 72];
  __shared__ alignas(16) bf16 Ost[48 * 32];
  const int sh = blockIdx.x, s = sh >> 3, h = sh & 7;
  const int t = threadIdx.x, wave = t >> 6, lane = t & 63, fr = lane & 15, kq = lane >> 4;
  for (int i = t; i < 768; i += 256) Ps[(i >> 4) * 72 + 48 + (i & 15)] = (bf16)0.0f;
  for (int i = t; i < 512; i += 256) Vt[(i >> 4) * 72 + 48 + (i & 15)] = (bf16)0.0f;
  const bf16* zb = Z + (size_t)sh * 2304;
  const float* mc = Mc + h * 2304;
  const float* ic = Ic + h * 2304;
  for (int c = t; c < 288; c += 256) {
    int r = c / 6, seg = c - r * 6;
    int idx = r * 48 + seg * 8;
    bf16x8 zv = *(const bf16x8*)(zb + idx);
    f32x4 m0v = *(const f32x4*)(mc + idx), m1v = *(const f32x4*)(mc + idx + 4);
    f32x4 i0v = *(const f32x4*)(ic + idx), i1v = *(const f32x4*)(ic + idx + 4);
    bf16x8 pv;
    for (int e = 0; e < 4; ++e) pv[e] = (bf16)(__expf((float)zv[e] - m0v[e]) * i0v[e]);
    for (int e = 0; e < 4; ++e) pv[4 + e] = (bf16)(__expf((float)zv[4 + e] - m1v[e]) * i1v[e]);
    *(bf16x8*)(Ps + r * 72 + seg * 8) = pv;
  }
  for (int c = t; c < 192; c += 256) {
    int j = c >> 2, seg = c & 3;
    bf16x8 v = *(const bf16x8*)(QKV + (size_t)(s * 48 + j) * 768 + 512 + h * 32 + seg * 8);
    for (int e = 0; e < 8; ++e) Vt[(seg * 8 + e) * 72 + j] = v[e];
  }
  __syncthreads();
  for (int t6 = wave; t6 < 6; t6 += 4) {
    int ti = t6 >> 1, td = t6 & 1;
    f32x4 a2 = {};
    for (int k0 = 0; k0 < 64; k0 += 32) {
      bf16x8 af = *(const bf16x8*)(Ps + (ti * 16 + fr) * 72 + k0 + kq * 8);
      bf16x8 bv = *(const bf16x8*)(Vt + (td * 16 + fr) * 72 + k0 + kq * 8);
      a2 = __builtin_amdgcn_mfma_f32_16x16x32_bf16(af, bv, a2, 0, 0, 0);
    }
    for (int r = 0; r < 4; ++r)
      Ost[(ti * 16 + kq * 4 + r) * 32 + td * 16 + fr] = (bf16)a2[r];
  }
  __syncthreads();
  bf16* ob = O + (size_t)sh * 1536;
  for (int c = t; c < 192; c += 256)
    *(bf16x8*)(ob + c * 8) = *(const bf16x8*)(Ost + c * 8);
}

// ---------------- out = LN(Xa + Xb), rows of 256, bf16 ----------------
__global__ __launch_bounds__(256) void k_add_ln(
    const bf16* __restrict__ Xa, const bf16* __restrict__ Xb, bf16* __restrict__ out) {
  const int t = threadIdx.x, lane = t & 63, w = t >> 6;
  const size_t off = ((size_t)blockIdx.x * 4 + w) * 256 + lane * 4;
  bf16x4 av = *(const bf16x4*)(Xa + off);
  bf16x4 bv = *(const bf16x4*)(Xb + off);
  f32x4 x;
  for (int c = 0; c < 4; ++c) x[c] = (float)av[c] + (float)bv[c];
  float sum = x[0] + x[1] + x[2] + x[3];
  for (int o = 1; o < 64; o <<= 1) sum += __shfl_xor(sum, o);
  float mean = sum * (1.0f / 256.0f);
  float q = 0.0f;
  for (int c = 0; c < 4; ++c) { float d = x[c] - mean; q += d * d; }
  for (int o = 1; o < 64; o <<= 1) q += __shfl_xor(q, o);
  float rstd = rsqrtf(q * (1.0f / 256.0f) + 1e-5f);
  bf16x4 y;
  for (int c = 0; c < 4; ++c) y[c] = (bf16)((x[c] - mean) * rstd);
  *(bf16x4*)(out + off) = y;
}

// ---------------- y[m] = dot(H[m,:256], w) + b ----------------
__global__ __launch_bounds__(256) void k_ydot(
    const bf16* __restrict__ H, const float* __restrict__ w,
    const float* __restrict__ b, float* __restrict__ Y) {
  const int t = threadIdx.x, lane = t & 63, wv = t >> 6;
  const size_t row = (size_t)blockIdx.x * 4 + wv;
  bf16x4 hx = *(const bf16x4*)(H + row * 256 + lane * 4);
  f32x4 ww = *(const f32x4*)(w + lane * 4);
  float s = (float)hx[0] * ww[0] + (float)hx[1] * ww[1] + (float)hx[2] * ww[2] + (float)hx[3] * ww[3];
  for (int o = 1; o < 64; o <<= 1) s += __shfl_xor(s, o);
  if (lane == 0) Y[row] = s + b[0];
}

// ---------------- softmax over b (48) per column ----------------
__global__ void k_softmax48(const float* __restrict__ Y, float* __restrict__ O) {
  int ss = blockIdx.x * 256 + threadIdx.x;
  if (ss >= 900) return;
  float m = -FLT_MAX;
  for (int b = 0; b < 48; ++b) m = fmaxf(m, Y[b * 900 + ss]);
  float sum = 0.0f;
  for (int b = 0; b < 48; ++b) sum += __expf(Y[b * 900 + ss] - m);
  float inv = 1.0f / sum;
  for (int b = 0; b < 48; ++b) O[b * 900 + ss] = __expf(Y[b * 900 + ss] - m) * inv;
}

extern "C" void kernel_launch(void* const* d_in, const int* in_sizes, int n_in,
                              void* d_out, int out_size, void* d_ws, size_t ws_size,
                              hipStream_t stream) {
  (void)in_sizes; (void)n_in; (void)out_size;
  const float* X_en = (const float*)d_in[0];
  const float* X_de = (const float*)d_in[1];
  const float* conv1_w = (const float*)d_in[2];
  const float* conv1_b = (const float*)d_in[3];
  const float* conv2_w = (const float*)d_in[4];
  const float* conv2_b = (const float*)d_in[5];
  const float* enc_wq = (const float*)d_in[6];
  const float* enc_wk = (const float*)d_in[7];
  const float* enc_wv = (const float*)d_in[8];
  const float* enc_rel = (const float*)d_in[9];
  const float* enc_f1w = (const float*)d_in[10];
  const float* enc_f1b = (const float*)d_in[11];
  const float* enc_f2w = (const float*)d_in[12];
  const float* enc_f2b = (const float*)d_in[13];
  const float* dm_wq = (const float*)d_in[14];
  const float* dm_wk = (const float*)d_in[15];
  const float* dm_wv = (const float*)d_in[16];
  const float* dm_rel = (const float*)d_in[17];
  const float* dm_l1w = (const float*)d_in[18];
  const float* dm_l1b = (const float*)d_in[19];
  const float* dm_l2w = (const float*)d_in[20];
  const float* dm_l2b = (const float*)d_in[21];
  const float* dc_wq = (const float*)d_in[22];
  const float* dc_wk = (const float*)d_in[23];
  const float* dc_wv = (const float*)d_in[24];
  const float* dc_rel = (const float*)d_in[25];
  const float* d_f1w = (const float*)d_in[26];
  const float* d_f1b = (const float*)d_in[27];
  const float* d_f2w = (const float*)d_in[28];
  const float* d_f2b = (const float*)d_in[29];
  const float* out_w = (const float*)d_in[30];
  const float* out_b = (const float*)d_in[31];
  float* OUT = (float*)d_out;

  // ---- workspace layout ----
  const size_t SLOT = 22118400;  // 43200*256 bf16
  char* ws = (char*)d_ws;
  size_t o = 0;
  bf16* S1 = (bf16*)(ws + o); o += SLOT;  // XEb -> ENCb
  bf16* S2 = (bf16*)(ws + o); o += SLOT;  // XDb -> (cross stats)
  bf16* S3 = (bf16*)(ws + o); o += SLOT;  // (enc RelT) -> o1 -> (dm stats) -> (cross RelT) -> h2
  bf16* S4 = (bf16*)(ws + o); o += SLOT;  // (enc stats) -> h1 -> h3
  bf16* S5 = (bf16*)(ws + o); o += SLOT;  // attn-out / ffn-out / (dm RelT)
  char* U = ws + o; o += 33177600 + 3 * SLOT;  // Z + QKV, union { HID, XR+C1R }
  bf16* Zb = (bf16*)U;
  bf16* QKV = (bf16*)(U + 33177600);
  bf16* XR = (bf16*)U;                    // conv phase: 96*1024*32 bf16 = 12.6 MB
  bf16* C1R = (bf16*)(U + 12582912);      // conv phase: 96*900*256 bf16 = 44.2 MB
  bf16* HID = (bf16*)U;                   // FFN phase only
  bf16* wa = (bf16*)(ws + o); o += 4603904 + 16384;
  float* Y = (float*)(ws + o); o += 172800;
  if (ws_size < o) return;

  bf16* zpage = (bf16*)Y;  // 512 B zero page; Y dead until k_ydot
  float* encM = (float*)S4; float* encI = encM + 18432;
  float* dmM  = (float*)S3; float* dmI  = dmM + 18432;
  float* crM  = (float*)S2; float* crI  = crM + 18432;
  bf16* encRel = S3;   // free until o1 written
  bf16* dmRel  = S5;   // free until dm attn_av writes S5
  bf16* crRel  = S3;   // o1 dead after enc_out

  // weight arena (element offsets)
  bf16* c1p = wa;
  bf16* c2p = wa + 73728;
  bf16* EQKVw = wa + 663552;
  bf16* MQKVw = wa + 860160;
  bf16* cqw = wa + 1056768;
  bf16* CKVw = wa + 1122304;
  bf16* ef1 = wa + 1253376;
  bf16* ef2 = wa + 1515520;
  bf16* df1 = wa + 1777664;
  bf16* df2 = wa + 2039808;
  bf16* L1p = wa + 2301952;
  bf16* L2p = wa + 2305408;

  auto gemm = [&](const bf16* A, const bf16* B, const float* bias, bf16* C,
                  int M, int N, int K, int relu, int ldc, int coff) {
    k_gemm128<<<dim3((M + 127) / 128, N / 128), dim3(256), 0, stream>>>(
        A, A, B, B, N, bias, C, M, N, K, relu, ldc, coff);
  };

  // ---- weight prep ----
  k_prep_misc<<<dim3(1), dim3(256), 0, stream>>>(zpage, dm_l1w, dm_l2w, L1p, L2p);
  k_pack_conv<<<dim3(288), dim3(256), 0, stream>>>(conv1_w, c1p, 256, 32, 73728);
  k_pack_conv<<<dim3(2304), dim3(256), 0, stream>>>(conv2_w, c2p, 256, 256, 589824);
  {
    CastSegs sg;
    const float* srcs[13] = {enc_wq, enc_wk, enc_wv, dm_wq, dm_wk, dm_wv, dc_wq,
                             dc_wk, dc_wv, enc_f1w, enc_f2w, d_f1w, d_f2w};
    bf16* dsts[13] = {EQKVw, EQKVw + 65536, EQKVw + 131072, MQKVw, MQKVw + 65536,
                      MQKVw + 131072, cqw, CKVw, CKVw + 65536, ef1, ef2, df1, df2};
    int ns[13] = {65536, 65536, 65536, 65536, 65536, 65536, 65536, 65536, 65536,
                  262144, 262144, 262144, 262144};
    int total = 0;
    for (int k = 0; k < 13; ++k) { sg.s[k] = srcs[k]; sg.d[k] = dsts[k]; sg.n[k] = ns[k]; total += ns[k]; }
    k_cast_all<<<dim3((total + 255) / 256), dim3(256), 0, stream>>>(sg, total);
  }

  // ---- merged conv chain (96 batches: en then de; conv2 writes S1||S2 contiguously) ----
  k_prep_x<<<dim3(12288), dim3(256), 0, stream>>>(X_en, X_de, XR);
  k_conv128<32, 0, 32, 1024, 0, 0, 86400><<<dim3(675, 2), dim3(256), 0, stream>>>(
      XR, c1p, conv1_b, C1R, zpage);
  k_conv2x<<<dim3(675, 2), dim3(256), 0, stream>>>(C1R, c2p, conv2_b, S1, zpage);

  // ---- encoder ----
  gemm(S1, EQKVw, nullptr, QKV, 43200, 768, 256, 0, 768, 0);
  k_prep_rel<<<dim3(900), dim3(256), 0, stream>>>(enc_rel, encRel);
  k_attn_z<0><<<dim3(7200), dim3(256), 0, stream>>>(QKV, encRel, Zb, nullptr, nullptr, nullptr, nullptr);
  k_colstats<<<dim3(288), dim3(256), 0, stream>>>(Zb, encM, encI);
  k_attn_av<<<dim3(7200), dim3(256), 0, stream>>>(Zb, QKV, encM, encI, S5);
  k_add_ln<<<dim3(10800), dim3(256), 0, stream>>>(S1, S5, S3);  // o1
  gemm(S3, ef1, enc_f1b, HID, 43200, 1024, 256, 1, 1024, 0);
  gemm(HID, ef2, enc_f2b, S5, 43200, 256, 1024, 0, 256, 0);
  k_add_ln<<<dim3(10800), dim3(256), 0, stream>>>(S3, S5, S1);  // enc_out

  // ---- decoder masked self-attention ----
  gemm(S2, MQKVw, nullptr, QKV, 43200, 768, 256, 0, 768, 0);
  k_prep_rel<<<dim3(900), dim3(256), 0, stream>>>(dm_rel, dmRel);
  k_attn_z<1><<<dim3(7200), dim3(256), 0, stream>>>(QKV, dmRel, Zb, L1p, L2p, dm_l1b, dm_l2b);
  k_colstats<<<dim3(288), dim3(256), 0, stream>>>(Zb, dmM, dmI);
  k_attn_av<<<dim3(7200), dim3(256), 0, stream>>>(Zb, QKV, dmM, dmI, S5);
  k_add_ln<<<dim3(10800), dim3(256), 0, stream>>>(S2, S5, S4);  // h1

  // ---- cross attention (q + kv merged into one dual-GEMM launch) ----
  k_gemm128<<<dim3(338, 6), dim3(256), 0, stream>>>(
      S4, S1, cqw, CKVw, 256, nullptr, QKV, 43200, 768, 256, 0, 768, 0);
  k_prep_rel<<<dim3(900), dim3(256), 0, stream>>>(dc_rel, crRel);
  k_attn_z<0><<<dim3(7200), dim3(256), 0, stream>>>(QKV, crRel, Zb, nullptr, nullptr, nullptr, nullptr);
  k_colstats<<<dim3(288), dim3(256), 0, stream>>>(Zb, crM, crI);
  k_attn_av<<<dim3(7200), dim3(256), 0, stream>>>(Zb, QKV, crM, crI, S5);
  k_add_ln<<<dim3(10800), dim3(256), 0, stream>>>(S5, S4, S3);  // h2 = ln(c + h1)

  // ---- decoder FFN + head ----
  gemm(S3, df1, d_f1b, HID, 43200, 1024, 256, 1, 1024, 0);
  gemm(HID, df2, d_f2b, S5, 43200, 256, 1024, 0, 256, 0);
  k_add_ln<<<dim3(10800), dim3(256), 0, stream>>>(S3, S5, S4);  // h3
  k_ydot<<<dim3(10800), dim3(256), 0, stream>>>(S4, out_w, out_b, Y);
  k_softmax48<<<dim3(4), dim3(256), 0, stream>>>(Y, OUT);
}

// Round 7
// 994.037 us; speedup vs baseline: 1.0334x; 1.0153x over previous
//
#include <hip/hip_runtime.h>
#include <float.h>

typedef __bf16 bf16;
typedef __attribute__((ext_vector_type(8))) __bf16 bf16x8;
typedef __attribute__((ext_vector_type(4))) __bf16 bf16x4;
typedef __attribute__((ext_vector_type(4))) float f32x4;

__device__ __forceinline__ int imin(int a, int b) { return a < b ? a : b; }

// async global->LDS, 16B per lane; LDS dest = wave-uniform base + lane*16
__device__ __forceinline__ void gl2lds(const bf16* g, bf16* l) {
  __builtin_amdgcn_global_load_lds(
      (const __attribute__((address_space(1))) void*)g,
      (__attribute__((address_space(3))) void*)l, 16, 0, 0);
}

// ---------------- zero-page + padded lin weights (fused tiny prep) ----------------
__global__ void k_prep_misc(bf16* zp, const float* __restrict__ l1w,
                            const float* __restrict__ l2w,
                            bf16* __restrict__ L1p, bf16* __restrict__ L2p) {
  zp[threadIdx.x] = (bf16)0.0f;
  for (int i = threadIdx.x; i < 3456; i += 256) {
    int r = i / 72, c = i - r * 72;
    L1p[i] = (c < 48) ? (bf16)l1w[r * 48 + c] : (bf16)0.0f;
    L2p[i] = (c < 48) ? (bf16)l2w[r * 48 + c] : (bf16)0.0f;
  }
}

// ---------------- fused f32->bf16 casts (13 segments) ----------------
struct CastSegs { const float* s[13]; bf16* d[13]; int n[13]; };
__global__ void k_cast_all(CastSegs sg, int total) {
  int i = blockIdx.x * 256 + threadIdx.x;
  if (i >= total) return;
  for (int k = 0; k < 13; ++k) {
    if (i < sg.n[k]) { sg.d[k][i] = (bf16)sg.s[k][i]; return; }
    i -= sg.n[k];
  }
}

// ---------------- rel transpose via LDS: (sh, k*48+j) fp32 -> (sh, j*32+k) bf16 ----------------
__global__ __launch_bounds__(256) void k_prep_rel(const float* __restrict__ rel,
                                                  bf16* __restrict__ RelT) {
  __shared__ float tile[32 * 49];
  const int t = threadIdx.x;
  for (int u = 0; u < 8; ++u) {
    const size_t sh = (size_t)blockIdx.x * 8 + u;
    const float* src = rel + sh * 1536;
    bf16* dst = RelT + sh * 1536;
    __syncthreads();
    for (int i = t; i < 1536; i += 256) {
      int k = i / 48, j = i - k * 48;
      tile[k * 49 + j] = src[i];
    }
    __syncthreads();
    for (int i = t; i < 1536; i += 256) {
      int j = i >> 5, k = i & 31;
      dst[i] = (bf16)tile[k * 49 + j];
    }
  }
}

// ---------------- X_en|X_de (b,32,32,32) -> XR rows (96*1024, 32ch) bf16 ----------------
__global__ void k_prep_x(const float* __restrict__ XE, const float* __restrict__ XD,
                         bf16* __restrict__ XR) {
  int idx = blockIdx.x * 256 + threadIdx.x;
  if (idx >= 96 * 1024 * 32) return;
  int b = idx >> 15, r = idx & 32767, pos = r >> 5, ic = r & 31;
  const float* X = (b < 48) ? XE : XD;
  int bl = (b < 48) ? b : b - 48;
  XR[idx] = (bf16)X[((size_t)(bl * 32 + ic) << 10) + pos];
}

// ---------------- conv weight pack: (OC,IC,3,3) -> 9 x (OC,IC) bf16 ----------------
__global__ void k_pack_conv(const float* __restrict__ w, bf16* __restrict__ dst,
                            int OC, int IC, int total) {
  int idx = blockIdx.x * 256 + threadIdx.x;
  if (idx >= total) return;
  int t = idx / (OC * IC);
  int rem = idx - t * OC * IC;
  int oc = rem / IC, ic = rem - oc * IC;
  dst[idx] = (bf16)w[(size_t)(oc * IC + ic) * 9 + t];
}

// ---------------- 128x128 GEMM, BK=64, single-buffered, conflict-free LDS ----------
// LDS: A [128][64] at 0, B [128][64] at +8192 (128-B row pitch).
// Swizzle involution: seg' = seg ^ (row&7) (16-B segs, 8/row); gl2lds dest linear,
// SOURCE pre-swizzled, reads swizzled with the same XOR.
// If n0 >= nsplit: use A2/B2 with local n (merged dual-GEMM launch). K%64==0, N%128==0.
__global__ __launch_bounds__(256, 2) void k_gemm128(
    const bf16* __restrict__ A, const bf16* __restrict__ A2,
    const bf16* __restrict__ B, const bf16* __restrict__ B2, int nsplit,
    const float* __restrict__ bias, bf16* __restrict__ C,
    int M, int N, int K, int relu, int ldc, int coff) {
  __shared__ alignas(16) bf16 SM[16384];
  const int t = threadIdx.x, wave = t >> 6;
  const int lane = t & 63, fr = lane & 15, kq = lane >> 4;
  const int wm = wave & 1, wn = wave >> 1;
  const int m0 = blockIdx.x * 128, n0 = blockIdx.y * 128;
  const bf16* Ause = A; const bf16* Buse = B; int nloc = n0;
  if (n0 >= nsplit) { Ause = A2; Buse = B2; nloc = n0 - nsplit; }
  // staging map: thread t covers (row = r*32 + (t>>3), seg = t&7), r = 0..3 for A and B
  const int srow = t >> 3;
  const int sg8 = (((t & 7) ^ (srow & 7)) << 3);  // pre-swizzled source k-seg (elements)
  const bf16* gA[4]; const bf16* gB[4];
#pragma unroll
  for (int r = 0; r < 4; ++r) {
    gA[r] = Ause + (size_t)imin(m0 + r * 32 + srow, M - 1) * K + sg8;
    gB[r] = Buse + (size_t)(nloc + r * 32 + srow) * K + sg8;
  }
  // fragment-read offsets (elements); ^32 switches k-halves
  const int swz = (kq ^ (fr & 7)) << 3;
  const int aoff = (wm * 64 + fr) * 64 + swz;
  const int boff = 8192 + (wn * 64 + fr) * 64 + swz;
  f32x4 acc[4][4] = {};
  for (int k0 = 0; k0 < K; k0 += 64) {
    bf16* db = SM + wave * 512;
#pragma unroll
    for (int r = 0; r < 4; ++r) gl2lds(gA[r] + k0, db + r * 2048);
#pragma unroll
    for (int r = 0; r < 4; ++r) gl2lds(gB[r] + k0, db + 8192 + r * 2048);
    __syncthreads();
#pragma unroll
    for (int kk = 0; kk < 2; ++kk) {
      const int xo = kk << 5;
      bf16x8 af[4], bw[4];
#pragma unroll
      for (int mt = 0; mt < 4; ++mt)
        af[mt] = *(const bf16x8*)(SM + ((aoff + mt * 1024) ^ xo));
#pragma unroll
      for (int nt = 0; nt < 4; ++nt)
        bw[nt] = *(const bf16x8*)(SM + ((boff + nt * 1024) ^ xo));
#pragma unroll
      for (int mt = 0; mt < 4; ++mt)
#pragma unroll
        for (int nt = 0; nt < 4; ++nt)
          acc[mt][nt] = __builtin_amdgcn_mfma_f32_16x16x32_bf16(af[mt], bw[nt], acc[mt][nt], 0, 0, 0);
    }
    __syncthreads();
  }
  bf16* Cst = SM;  // 64 x 136 (padded pitch: conflict-free epilogue)
  for (int half = 0; half < 2; ++half) {
    if (wm == half) {
      for (int mt = 0; mt < 4; ++mt)
        for (int nt = 0; nt < 4; ++nt) {
          int n = n0 + wn * 64 + nt * 16 + fr;
          float bv = bias ? bias[n] : 0.0f;
          for (int r = 0; r < 4; ++r) {
            float v = acc[mt][nt][r] + bv;
            if (relu) v = fmaxf(v, 0.0f);
            Cst[(mt * 16 + kq * 4 + r) * 136 + wn * 64 + nt * 16 + fr] = (bf16)v;
          }
        }
    }
    __syncthreads();
    for (int i = t; i < 1024; i += 256) {
      int r = i >> 4, cs = i & 15;
      int gm = m0 + half * 64 + r;
      if (gm < M)
        *(bf16x8*)(C + (size_t)gm * ldc + coff + n0 + cs * 8) = *(const bf16x8*)(Cst + r * 136 + cs * 8);
    }
    __syncthreads();
  }
}

// ---------------- conv1 (BK=32): shifted 128x128 GEMM, merged 96 batches ----------------
template <int CIN, int PAD, int SRCW, int SRCROWS, int CHECK, int TRANS, int MTOT>
__global__ __launch_bounds__(256, 2) void k_conv128(
    const bf16* __restrict__ A, const bf16* __restrict__ Bp,
    const float* __restrict__ bias, bf16* __restrict__ C,
    const bf16* __restrict__ zpage) {
  __shared__ alignas(16) bf16 SM[8192];
  bf16* As = SM;
  bf16* Bs = SM + 4096;
  const int t = threadIdx.x, wave = t >> 6;
  const int lane = t & 63, fr = lane & 15, kq = lane >> 4;
  const int wm = wave & 1, wn = wave >> 1;
  const int m0 = blockIdx.x * 128, n0 = blockIdx.y * 128;
  const int srow = t >> 2, kseg = (t & 3) * 8;
  f32x4 acc[4][4] = {};
  int bb[2], yy[2], xx[2];
  for (int hf = 0; hf < 2; ++hf) {
    int m = imin(m0 + hf * 64 + srow, MTOT - 1);
    int b = m / 900, p = m - b * 900;
    bb[hf] = b; yy[hf] = p / 30; xx[hf] = p - (p / 30) * 30;
  }
  bf16* sA0 = As + wave * 512;
  bf16* sA1 = As + 2048 + wave * 512;
  bf16* sB0 = Bs + wave * 512;
  bf16* sB1 = Bs + 2048 + wave * 512;
  for (int k0 = 0; k0 < CIN; k0 += 32) {
    for (int t9 = 0; t9 < 9; ++t9) {
      const int ky = t9 / 3, kx = t9 - ky * 3;
      const bf16* ga[2];
      for (int hf = 0; hf < 2; ++hf) {
        int sy = yy[hf] + ky - PAD, sx = xx[hf] + kx - PAD;
        bool valid = !CHECK || (sy >= 0 && sy < SRCW && sx >= 0 && sx < SRCW);
        ga[hf] = (valid ? A + (size_t)(bb[hf] * SRCROWS + sy * SRCW + sx) * CIN : zpage) + kseg;
      }
      const bf16* gb = Bp + (size_t)(t9 * 256 + n0 + srow) * CIN + kseg;
      gl2lds(ga[0] + k0, sA0);
      gl2lds(ga[1] + k0, sA1);
      gl2lds(gb + k0, sB0);
      gl2lds(gb + (size_t)64 * CIN + k0, sB1);
      __syncthreads();
      bf16x8 af[4], bw[4];
      for (int mt = 0; mt < 4; ++mt)
        af[mt] = *(const bf16x8*)(As + (wm * 64 + mt * 16 + fr) * 32 + kq * 8);
      for (int nt = 0; nt < 4; ++nt)
        bw[nt] = *(const bf16x8*)(Bs + (wn * 64 + nt * 16 + fr) * 32 + kq * 8);
      for (int mt = 0; mt < 4; ++mt)
        for (int nt = 0; nt < 4; ++nt)
          acc[mt][nt] = __builtin_amdgcn_mfma_f32_16x16x32_bf16(af[mt], bw[nt], acc[mt][nt], 0, 0, 0);
      __syncthreads();
    }
  }
  bf16* Cst = SM;
  for (int half = 0; half < 2; ++half) {
    if (wm == half) {
      for (int mt = 0; mt < 4; ++mt)
        for (int nt = 0; nt < 4; ++nt) {
          int n = n0 + wn * 64 + nt * 16 + fr;
          float bv = bias[n];
          for (int r = 0; r < 4; ++r) {
            float v = acc[mt][nt][r] + bv;
            if (TRANS)
              Cst[(wn * 64 + nt * 16 + fr) * 64 + mt * 16 + kq * 4 + r] = (bf16)v;
            else
              Cst[(mt * 16 + kq * 4 + r) * 128 + wn * 64 + nt * 16 + fr] = (bf16)v;
          }
        }
    }
    __syncthreads();
    if (TRANS) {
      for (int i = t; i < 2048; i += 256) {
        int oc = i >> 4, pc = i & 15;
        int gm = m0 + half * 64 + pc * 4;
        if (gm < MTOT) {
          int b = gm / 900, p = gm - b * 900;
          *(bf16x4*)(C + (size_t)(b * 256 + n0 + oc) * 900 + p) = *(const bf16x4*)(Cst + oc * 64 + pc * 4);
        }
      }
    } else {
      for (int i = t; i < 1024; i += 256) {
        int r = i >> 4, cs = i & 15;
        int gm = m0 + half * 64 + r;
        if (gm < MTOT)
          *(bf16x8*)(C + (size_t)gm * 256 + n0 + cs * 8) = *(const bf16x8*)(Cst + r * 128 + cs * 8);
      }
    }
    __syncthreads();
  }
}

// ---------------- conv2 (CIN=256, pad=1): k0-outer/tap-inner (L2-tight), BK=64,
// single-buffered 32 KiB, conflict-free [128][64] swizzled LDS, merged 96 batches ----
__global__ __launch_bounds__(256, 2) void k_conv2x(
    const bf16* __restrict__ A, const bf16* __restrict__ Bp,
    const float* __restrict__ bias, bf16* __restrict__ C,
    const bf16* __restrict__ zpage) {
  __shared__ alignas(16) bf16 SM[16384];
  const int t = threadIdx.x, wave = t >> 6;
  const int lane = t & 63, fr = lane & 15, kq = lane >> 4;
  const int wm = wave & 1, wn = wave >> 1;
  const int m0 = blockIdx.x * 128, n0 = blockIdx.y * 128;
  const int srow = t >> 3;                            // staged row slot (0..31)
  const int sg8 = (((t & 7) ^ (srow & 7)) << 3);      // pre-swizzled source k-seg
  // decode the 4 A-rows this thread stages (positions, clamped)
  int pb[4], py[4], px[4];
#pragma unroll
  for (int r = 0; r < 4; ++r) {
    int m = imin(m0 + r * 32 + srow, 86399);
    int b = m / 900, p = m - b * 900;
    pb[r] = b * 900; py[r] = p / 30; px[r] = p - (p / 30) * 30;
  }
  const int swz = (kq ^ (fr & 7)) << 3;
  const int aoff = (wm * 64 + fr) * 64 + swz;
  const int boff = 8192 + (wn * 64 + fr) * 64 + swz;
  f32x4 acc[4][4] = {};
  for (int k0 = 0; k0 < 256; k0 += 64) {
    for (int t9 = 0; t9 < 9; ++t9) {
      const int ky = t9 / 3, kx = t9 - ky * 3;
      bf16* db = SM + wave * 512;
#pragma unroll
      for (int r = 0; r < 4; ++r) {
        int sy = py[r] + ky - 1, sx = px[r] + kx - 1;
        bool valid = (sy >= 0 && sy < 30 && sx >= 0 && sx < 30);
        const bf16* g = valid ? (A + (size_t)(pb[r] + sy * 30 + sx) * 256 + k0 + sg8)
                              : (zpage + sg8);
        gl2lds(g, db + r * 2048);
      }
#pragma unroll
      for (int r = 0; r < 4; ++r)
        gl2lds(Bp + (size_t)(t9 * 256 + n0 + r * 32 + srow) * 256 + k0 + sg8,
               db + 8192 + r * 2048);
      __syncthreads();
#pragma unroll
      for (int kk = 0; kk < 2; ++kk) {
        const int xo = kk << 5;
        bf16x8 af[4], bw[4];
#pragma unroll
        for (int mt = 0; mt < 4; ++mt)
          af[mt] = *(const bf16x8*)(SM + ((aoff + mt * 1024) ^ xo));
#pragma unroll
        for (int nt = 0; nt < 4; ++nt)
          bw[nt] = *(const bf16x8*)(SM + ((boff + nt * 1024) ^ xo));
#pragma unroll
        for (int mt = 0; mt < 4; ++mt)
#pragma unroll
          for (int nt = 0; nt < 4; ++nt)
            acc[mt][nt] = __builtin_amdgcn_mfma_f32_16x16x32_bf16(af[mt], bw[nt], acc[mt][nt], 0, 0, 0);
      }
      __syncthreads();
    }
  }
  bf16* Cst = SM;  // 128 oc x 68 (padded pitch: conflict-free epilogue)
  for (int half = 0; half < 2; ++half) {
    if (wm == half) {
      for (int mt = 0; mt < 4; ++mt)
        for (int nt = 0; nt < 4; ++nt) {
          int n = n0 + wn * 64 + nt * 16 + fr;
          float bv = bias[n];
          for (int r = 0; r < 4; ++r) {
            float v = acc[mt][nt][r] + bv;
            Cst[(wn * 64 + nt * 16 + fr) * 68 + mt * 16 + kq * 4 + r] = (bf16)v;
          }
        }
    }
    __syncthreads();
    for (int i = t; i < 2048; i += 256) {
      int oc = i >> 4, pc = i & 15;
      int gm = m0 + half * 64 + pc * 4;
      int b = gm / 900, p = gm - b * 900;
      *(bf16x4*)(C + (size_t)(b * 256 + n0 + oc) * 900 + p) = *(const bf16x4*)(Cst + oc * 68 + pc * 4);
    }
    __syncthreads();
  }
}

// ---------------- attention logits z for one (s,h) ----------------
template <int MASKED>
__global__ __launch_bounds__(256, MASKED ? 4 : 5) void k_attn_z(
    const bf16* __restrict__ QKV, const bf16* __restrict__ RelT, bf16* __restrict__ Z,
    const bf16* __restrict__ L1p, const bf16* __restrict__ L2p,
    const float* __restrict__ l1b, const float* __restrict__ l2b) {
  __shared__ alignas(16) bf16 QKs[2][48 * 40];
  __shared__ float EMD[48 * 49];
  __shared__ alignas(16) bf16 zst[48 * 48];
  __shared__ alignas(16) bf16 Sc[MASKED ? 48 * 72 : 8];
  __shared__ alignas(16) bf16 T2b[MASKED ? 48 * 72 : 8];
  const int sh = blockIdx.x, s = sh >> 3, h = sh & 7;
  const int t = threadIdx.x, wave = t >> 6, lane = t & 63, fr = lane & 15, kq = lane >> 4;
  const float scale = 0.17677669529663687f;  // 1/sqrt(32)
  for (int c = t; c < 384; c += 256) {
    int half = c >= 192 ? 1 : 0, cc = c - half * 192;
    int row = cc >> 2, seg = cc & 3;
    *(bf16x8*)(&QKs[half][row * 40 + seg * 8]) =
        *(const bf16x8*)(QKV + (size_t)(s * 48 + row) * 768 + half * 256 + h * 32 + seg * 8);
  }
  if constexpr (MASKED) {
    for (int i = t; i < 768; i += 256) {
      int r = i >> 4, c = 48 + (i & 15);
      Sc[r * 72 + c] = (bf16)0.0f;
      T2b[r * 72 + c] = (bf16)0.0f;
    }
  }
  __syncthreads();
  const bf16* relb = RelT + (size_t)sh * 1536;
  f32x4 sreg[3];
  int u = 0;
  for (int t9 = wave; t9 < 9; t9 += 4, ++u) {
    int ti = t9 / 3, tj = t9 - ti * 3;
    bf16x8 af = *(const bf16x8*)(&QKs[0][(ti * 16 + fr) * 40 + kq * 8]);
    bf16x8 bk = *(const bf16x8*)(&QKs[1][(tj * 16 + fr) * 40 + kq * 8]);
    bf16x8 rf = *(const bf16x8*)(relb + (tj * 16 + fr) * 32 + kq * 8);
    f32x4 sacc = {}, eacc = {};
    sacc = __builtin_amdgcn_mfma_f32_16x16x32_bf16(af, bk, sacc, 0, 0, 0);
    eacc = __builtin_amdgcn_mfma_f32_16x16x32_bf16(af, rf, eacc, 0, 0, 0);
    for (int r = 0; r < 4; ++r)
      EMD[(ti * 16 + kq * 4 + r) * 49 + tj * 16 + fr] = eacc[r];
    if constexpr (MASKED) {
      for (int r = 0; r < 4; ++r)
        Sc[(ti * 16 + kq * 4 + r) * 72 + tj * 16 + fr] = (bf16)(sacc[r] * scale);
    } else {
      for (int r = 0; r < 4; ++r) sreg[u][r] = sacc[r] * scale;
    }
  }
  __syncthreads();
  if constexpr (!MASKED) {
    u = 0;
    for (int t9 = wave; t9 < 9; t9 += 4, ++u) {
      int ti = t9 / 3, tj = t9 - ti * 3;
      for (int r = 0; r < 4; ++r) {
        int i = ti * 16 + kq * 4 + r, j = tj * 16 + fr;
        float v = sreg[u][r];
        if (j <= i) v += EMD[i * 49 + 47 + j - i];
        zst[i * 48 + j] = (bf16)v;
      }
    }
  } else {
    for (int t9 = wave; t9 < 9; t9 += 4) {
      int ti = t9 / 3, tj = t9 - ti * 3;
      f32x4 a2 = {};
      for (int k0 = 0; k0 < 64; k0 += 32) {
        bf16x8 af = *(const bf16x8*)(Sc + (ti * 16 + fr) * 72 + k0 + kq * 8);
        bf16x8 bw = *(const bf16x8*)(L1p + (tj * 16 + fr) * 72 + k0 + kq * 8);
        a2 = __builtin_amdgcn_mfma_f32_16x16x32_bf16(af, bw, a2, 0, 0, 0);
      }
      for (int r = 0; r < 4; ++r) {
        int i = ti * 16 + kq * 4 + r, a = tj * 16 + fr;
        T2b[a * 72 + i] = (bf16)(a2[r] + l1b[a]);
      }
    }
    __syncthreads();
    for (int t9 = wave; t9 < 9; t9 += 4) {
      int ti = t9 / 3, tj = t9 - ti * 3;
      f32x4 a2 = {};
      for (int k0 = 0; k0 < 64; k0 += 32) {
        bf16x8 af = *(const bf16x8*)(T2b + (ti * 16 + fr) * 72 + k0 + kq * 8);
        bf16x8 bw = *(const bf16x8*)(L2p + (tj * 16 + fr) * 72 + k0 + kq * 8);
        a2 = __builtin_amdgcn_mfma_f32_16x16x32_bf16(af, bw, a2, 0, 0, 0);
      }
      for (int r = 0; r < 4; ++r) {
        int aa = ti * 16 + kq * 4 + r, cc = tj * 16 + fr;
        float v;
        if (cc > aa) v = -10000.0f;  // masked column -> exactly uniform after softmax
        else v = a2[r] + l2b[cc] + EMD[aa * 49 + 47 + cc - aa];
        zst[aa * 48 + cc] = (bf16)v;
      }
    }
  }
  __syncthreads();
  bf16* zb = Z + (size_t)sh * 2304;
  for (int c = t; c < 288; c += 256)
    *(bf16x8*)(zb + c * 8) = *(const bf16x8*)(zst + c * 8);
}

// ---------------- per-column (over s=900) online max & inverse-sum ----------------
// grid 288: 64 cols/block (8 thr x 8 cols, bf16x8) x 32 s-groups of 29
__global__ __launch_bounds__(256) void k_colstats(const bf16* __restrict__ Z,
                                                  float* __restrict__ Mc, float* __restrict__ Ic) {
  __shared__ float rm[32][72], rs[32][72];
  const int t = threadIdx.x, cg = t & 7, sg = t >> 3;
  const bf16* p = Z + blockIdx.x * 64 + cg * 8;
  const int s0 = sg * 29, s1 = imin(900, s0 + 29);
  float m[8], ss[8];
  for (int e = 0; e < 8; ++e) { m[e] = -FLT_MAX; ss[e] = 0.0f; }
  for (int s = s0; s < s1; ++s) {
    bf16x8 zv = *(const bf16x8*)(p + (size_t)s * 18432);
    for (int e = 0; e < 8; ++e) {
      float v = (float)zv[e];
      if (v > m[e]) { ss[e] *= __expf(m[e] - v); m[e] = v; }
      ss[e] += __expf(v - m[e]);
    }
  }
  for (int e = 0; e < 8; ++e) { rm[sg][cg * 8 + e] = m[e]; rs[sg][cg * 8 + e] = ss[e]; }
  __syncthreads();
  if (t < 64) {
    float M2 = -FLT_MAX;
    for (int g = 0; g < 32; ++g) M2 = fmaxf(M2, rm[g][t]);
    float S2 = 0.0f;
    for (int g = 0; g < 32; ++g) S2 += rs[g][t] * __expf(rm[g][t] - M2);
    Mc[blockIdx.x * 64 + t] = M2;
    Ic[blockIdx.x * 64 + t] = 1.0f / S2;
  }
}

// ---------------- O = LN(RES + softmax(Z) V) for one (s,h); writes 6 rows of 256 ----
// attn output for block sh is 1536 contiguous elements = flat rows [6*sh, 6*sh+6) of
// the (b, sl, 256) view; each row is fully block-local, so add+LN fuses here.
__global__ __launch_bounds__(256, 6) void k_attn_av(
    const bf16* __restrict__ Z, const bf16* __restrict__ QKV,
    const float* __restrict__ Mc, const float* __restrict__ Ic,
    const bf16* __restrict__ RES, bf16* __restrict__ O) {
  __shared__ alignas(16) bf16 Ps[48 * 72];
  __shared__ alignas(16) bf16 Vt[32 * 72];
  __shared__ alignas(16) bf16 Ost[48 * 32];
  const int sh = blockIdx.x, s = sh >> 3, h = sh & 7;
  const int t = threadIdx.x, wave = t >> 6, lane = t & 63, fr = lane & 15, kq = lane >> 4;
  for (int i = t; i < 768; i += 256) Ps[(i >> 4) * 72 + 48 + (i & 15)] = (bf16)0.0f;
  for (int i = t; i < 512; i += 256) Vt[(i >> 4) * 72 + 48 + (i & 15)] = (bf16)0.0f;
  const bf16* zb = Z + (size_t)sh * 2304;
  const float* mc = Mc + h * 2304;
  const float* ic = Ic + h * 2304;
  for (int c = t; c < 288; c += 256) {
    int r = c / 6, seg = c - r * 6;
    int idx = r * 48 + seg * 8;
    bf16x8 zv = *(const bf16x8*)(zb + idx);
    f32x4 m0v = *(const f32x4*)(mc + idx), m1v = *(const f32x4*)(mc + idx + 4);
    f32x4 i0v = *(const f32x4*)(ic + idx), i1v = *(const f32x4*)(ic + idx + 4);
    bf16x8 pv;
    for (int e = 0; e < 4; ++e) pv[e] = (bf16)(__expf((float)zv[e] - m0v[e]) * i0v[e]);
    for (int e = 0; e < 4; ++e) pv[4 + e] = (bf16)(__expf((float)zv[4 + e] - m1v[e]) * i1v[e]);
    *(bf16x8*)(Ps + r * 72 + seg * 8) = pv;
  }
  for (int c = t; c < 192; c += 256) {
    int j = c >> 2, seg = c & 3;
    bf16x8 v = *(const bf16x8*)(QKV + (size_t)(s * 48 + j) * 768 + 512 + h * 32 + seg * 8);
    for (int e = 0; e < 8; ++e) Vt[(seg * 8 + e) * 72 + j] = v[e];
  }
  __syncthreads();
  for (int t6 = wave; t6 < 6; t6 += 4) {
    int ti = t6 >> 1, td = t6 & 1;
    f32x4 a2 = {};
    for (int k0 = 0; k0 < 64; k0 += 32) {
      bf16x8 af = *(const bf16x8*)(Ps + (ti * 16 + fr) * 72 + k0 + kq * 8);
      bf16x8 bv = *(const bf16x8*)(Vt + (td * 16 + fr) * 72 + k0 + kq * 8);
      a2 = __builtin_amdgcn_mfma_f32_16x16x32_bf16(af, bv, a2, 0, 0, 0);
    }
    for (int r = 0; r < 4; ++r)
      Ost[(ti * 16 + kq * 4 + r) * 32 + td * 16 + fr] = (bf16)a2[r];
  }
  __syncthreads();
  // fused add + LayerNorm: 6 rows of 256, 1 row per wave (2 rounds) — k_add_ln math
  const size_t base = (size_t)sh * 1536;
  for (int r = wave; r < 6; r += 4) {
    const size_t off = base + r * 256 + lane * 4;
    bf16x4 av = *(const bf16x4*)(Ost + r * 256 + lane * 4);
    bf16x4 bv = *(const bf16x4*)(RES + off);
    f32x4 x;
    for (int c = 0; c < 4; ++c) x[c] = (float)av[c] + (float)bv[c];
    float sum = x[0] + x[1] + x[2] + x[3];
    for (int o = 1; o < 64; o <<= 1) sum += __shfl_xor(sum, o);
    float mean = sum * (1.0f / 256.0f);
    float q = 0.0f;
    for (int c = 0; c < 4; ++c) { float d = x[c] - mean; q += d * d; }
    for (int o = 1; o < 64; o <<= 1) q += __shfl_xor(q, o);
    float rstd = rsqrtf(q * (1.0f / 256.0f) + 1e-5f);
    bf16x4 y;
    for (int c = 0; c < 4; ++c) y[c] = (bf16)((x[c] - mean) * rstd);
    *(bf16x4*)(O + off) = y;
  }
}

// ---------------- out = LN(Xa + Xb), rows of 256, bf16 ----------------
__global__ __launch_bounds__(256) void k_add_ln(
    const bf16* __restrict__ Xa, const bf16* __restrict__ Xb, bf16* __restrict__ out) {
  const int t = threadIdx.x, lane = t & 63, w = t >> 6;
  const size_t off = ((size_t)blockIdx.x * 4 + w) * 256 + lane * 4;
  bf16x4 av = *(const bf16x4*)(Xa + off);
  bf16x4 bv = *(const bf16x4*)(Xb + off);
  f32x4 x;
  for (int c = 0; c < 4; ++c) x[c] = (float)av[c] + (float)bv[c];
  float sum = x[0] + x[1] + x[2] + x[3];
  for (int o = 1; o < 64; o <<= 1) sum += __shfl_xor(sum, o);
  float mean = sum * (1.0f / 256.0f);
  float q = 0.0f;
  for (int c = 0; c < 4; ++c) { float d = x[c] - mean; q += d * d; }
  for (int o = 1; o < 64; o <<= 1) q += __shfl_xor(q, o);
  float rstd = rsqrtf(q * (1.0f / 256.0f) + 1e-5f);
  bf16x4 y;
  for (int c = 0; c < 4; ++c) y[c] = (bf16)((x[c] - mean) * rstd);
  *(bf16x4*)(out + off) = y;
}

// ---------------- y[m] = dot(H[m,:256], w) + b ----------------
__global__ __launch_bounds__(256) void k_ydot(
    const bf16* __restrict__ H, const float* __restrict__ w,
    const float* __restrict__ b, float* __restrict__ Y) {
  const int t = threadIdx.x, lane = t & 63, wv = t >> 6;
  const size_t row = (size_t)blockIdx.x * 4 + wv;
  bf16x4 hx = *(const bf16x4*)(H + row * 256 + lane * 4);
  f32x4 ww = *(const f32x4*)(w + lane * 4);
  float s = (float)hx[0] * ww[0] + (float)hx[1] * ww[1] + (float)hx[2] * ww[2] + (float)hx[3] * ww[3];
  for (int o = 1; o < 64; o <<= 1) s += __shfl_xor(s, o);
  if (lane == 0) Y[row] = s + b[0];
}

// ---------------- softmax over b (48) per column ----------------
__global__ void k_softmax48(const float* __restrict__ Y, float* __restrict__ O) {
  int ss = blockIdx.x * 256 + threadIdx.x;
  if (ss >= 900) return;
  float m = -FLT_MAX;
  for (int b = 0; b < 48; ++b) m = fmaxf(m, Y[b * 900 + ss]);
  float sum = 0.0f;
  for (int b = 0; b < 48; ++b) sum += __expf(Y[b * 900 + ss] - m);
  float inv = 1.0f / sum;
  for (int b = 0; b < 48; ++b) O[b * 900 + ss] = __expf(Y[b * 900 + ss] - m) * inv;
}

extern "C" void kernel_launch(void* const* d_in, const int* in_sizes, int n_in,
                              void* d_out, int out_size, void* d_ws, size_t ws_size,
                              hipStream_t stream) {
  (void)in_sizes; (void)n_in; (void)out_size;
  const float* X_en = (const float*)d_in[0];
  const float* X_de = (const float*)d_in[1];
  const float* conv1_w = (const float*)d_in[2];
  const float* conv1_b = (const float*)d_in[3];
  const float* conv2_w = (const float*)d_in[4];
  const float* conv2_b = (const float*)d_in[5];
  const float* enc_wq = (const float*)d_in[6];
  const float* enc_wk = (const float*)d_in[7];
  const float* enc_wv = (const float*)d_in[8];
  const float* enc_rel = (const float*)d_in[9];
  const float* enc_f1w = (const float*)d_in[10];
  const float* enc_f1b = (const float*)d_in[11];
  const float* enc_f2w = (const float*)d_in[12];
  const float* enc_f2b = (const float*)d_in[13];
  const float* dm_wq = (const float*)d_in[14];
  const float* dm_wk = (const float*)d_in[15];
  const float* dm_wv = (const float*)d_in[16];
  const float* dm_rel = (const float*)d_in[17];
  const float* dm_l1w = (const float*)d_in[18];
  const float* dm_l1b = (const float*)d_in[19];
  const float* dm_l2w = (const float*)d_in[20];
  const float* dm_l2b = (const float*)d_in[21];
  const float* dc_wq = (const float*)d_in[22];
  const float* dc_wk = (const float*)d_in[23];
  const float* dc_wv = (const float*)d_in[24];
  const float* dc_rel = (const float*)d_in[25];
  const float* d_f1w = (const float*)d_in[26];
  const float* d_f1b = (const float*)d_in[27];
  const float* d_f2w = (const float*)d_in[28];
  const float* d_f2b = (const float*)d_in[29];
  const float* out_w = (const float*)d_in[30];
  const float* out_b = (const float*)d_in[31];
  float* OUT = (float*)d_out;

  // ---- workspace layout ----
  const size_t SLOT = 22118400;  // 43200*256 bf16
  char* ws = (char*)d_ws;
  size_t o = 0;
  bf16* S1 = (bf16*)(ws + o); o += SLOT;  // XEb -> ENCb
  bf16* S2 = (bf16*)(ws + o); o += SLOT;  // XDb -> (cross stats)
  bf16* S3 = (bf16*)(ws + o); o += SLOT;  // (enc RelT) -> o1 -> (dm stats) -> (cross RelT) -> h2
  bf16* S4 = (bf16*)(ws + o); o += SLOT;  // (enc stats) -> h1 -> h3
  bf16* S5 = (bf16*)(ws + o); o += SLOT;  // ffn-out / (dm RelT)
  char* U = ws + o; o += 33177600 + 3 * SLOT;  // Z + QKV, union { HID, XR+C1R }
  bf16* Zb = (bf16*)U;
  bf16* QKV = (bf16*)(U + 33177600);
  bf16* XR = (bf16*)U;                    // conv phase: 96*1024*32 bf16 = 12.6 MB
  bf16* C1R = (bf16*)(U + 12582912);      // conv phase: 96*900*256 bf16 = 44.2 MB
  bf16* HID = (bf16*)U;                   // FFN phase only
  bf16* wa = (bf16*)(ws + o); o += 4603904 + 16384;
  float* Y = (float*)(ws + o); o += 172800;
  if (ws_size < o) return;

  bf16* zpage = (bf16*)Y;  // 512 B zero page; Y dead until k_ydot
  float* encM = (float*)S4; float* encI = encM + 18432;
  float* dmM  = (float*)S3; float* dmI  = dmM + 18432;
  float* crM  = (float*)S2; float* crI  = crM + 18432;
  bf16* encRel = S3;   // free until o1 written
  bf16* dmRel  = S5;   // free until enc FFN2 writes S5? no — dm prep_rel runs after
  bf16* crRel  = S3;   // o1 dead after enc_out

  // weight arena (element offsets)
  bf16* c1p = wa;
  bf16* c2p = wa + 73728;
  bf16* EQKVw = wa + 663552;
  bf16* MQKVw = wa + 860160;
  bf16* cqw = wa + 1056768;
  bf16* CKVw = wa + 1122304;
  bf16* ef1 = wa + 1253376;
  bf16* ef2 = wa + 1515520;
  bf16* df1 = wa + 1777664;
  bf16* df2 = wa + 2039808;
  bf16* L1p = wa + 2301952;
  bf16* L2p = wa + 2305408;

  auto gemm = [&](const bf16* A, const bf16* B, const float* bias, bf16* C,
                  int M, int N, int K, int relu, int ldc, int coff) {
    k_gemm128<<<dim3((M + 127) / 128, N / 128), dim3(256), 0, stream>>>(
        A, A, B, B, N, bias, C, M, N, K, relu, ldc, coff);
  };

  // ---- weight prep ----
  k_prep_misc<<<dim3(1), dim3(256), 0, stream>>>(zpage, dm_l1w, dm_l2w, L1p, L2p);
  k_pack_conv<<<dim3(288), dim3(256), 0, stream>>>(conv1_w, c1p, 256, 32, 73728);
  k_pack_conv<<<dim3(2304), dim3(256), 0, stream>>>(conv2_w, c2p, 256, 256, 589824);
  {
    CastSegs sg;
    const float* srcs[13] = {enc_wq, enc_wk, enc_wv, dm_wq, dm_wk, dm_wv, dc_wq,
                             dc_wk, dc_wv, enc_f1w, enc_f2w, d_f1w, d_f2w};
    bf16* dsts[13] = {EQKVw, EQKVw + 65536, EQKVw + 131072, MQKVw, MQKVw + 65536,
                      MQKVw + 131072, cqw, CKVw, CKVw + 65536, ef1, ef2, df1, df2};
    int ns[13] = {65536, 65536, 65536, 65536, 65536, 65536, 65536, 65536, 65536,
                  262144, 262144, 262144, 262144};
    int total = 0;
    for (int k = 0; k < 13; ++k) { sg.s[k] = srcs[k]; sg.d[k] = dsts[k]; sg.n[k] = ns[k]; total += ns[k]; }
    k_cast_all<<<dim3((total + 255) / 256), dim3(256), 0, stream>>>(sg, total);
  }

  // ---- merged conv chain (96 batches: en then de; conv2 writes S1||S2 contiguously) ----
  k_prep_x<<<dim3(12288), dim3(256), 0, stream>>>(X_en, X_de, XR);
  k_conv128<32, 0, 32, 1024, 0, 0, 86400><<<dim3(675, 2), dim3(256), 0, stream>>>(
      XR, c1p, conv1_b, C1R, zpage);
  k_conv2x<<<dim3(675, 2), dim3(256), 0, stream>>>(C1R, c2p, conv2_b, S1, zpage);

  // ---- encoder ----
  gemm(S1, EQKVw, nullptr, QKV, 43200, 768, 256, 0, 768, 0);
  k_prep_rel<<<dim3(900), dim3(256), 0, stream>>>(enc_rel, encRel);
  k_attn_z<0><<<dim3(7200), dim3(256), 0, stream>>>(QKV, encRel, Zb, nullptr, nullptr, nullptr, nullptr);
  k_colstats<<<dim3(288), dim3(256), 0, stream>>>(Zb, encM, encI);
  k_attn_av<<<dim3(7200), dim3(256), 0, stream>>>(Zb, QKV, encM, encI, S1, S3);  // o1 = LN(S1+attn)
  gemm(S3, ef1, enc_f1b, HID, 43200, 1024, 256, 1, 1024, 0);
  gemm(HID, ef2, enc_f2b, S5, 43200, 256, 1024, 0, 256, 0);
  k_add_ln<<<dim3(10800), dim3(256), 0, stream>>>(S3, S5, S1);  // enc_out

  // ---- decoder masked self-attention ----
  gemm(S2, MQKVw, nullptr, QKV, 43200, 768, 256, 0, 768, 0);
  k_prep_rel<<<dim3(900), dim3(256), 0, stream>>>(dm_rel, dmRel);
  k_attn_z<1><<<dim3(7200), dim3(256), 0, stream>>>(QKV, dmRel, Zb, L1p, L2p, dm_l1b, dm_l2b);
  k_colstats<<<dim3(288), dim3(256), 0, stream>>>(Zb, dmM, dmI);
  k_attn_av<<<dim3(7200), dim3(256), 0, stream>>>(Zb, QKV, dmM, dmI, S2, S4);  // h1 = LN(S2+attn)

  // ---- cross attention (q + kv merged into one dual-GEMM launch) ----
  k_gemm128<<<dim3(338, 6), dim3(256), 0, stream>>>(
      S4, S1, cqw, CKVw, 256, nullptr, QKV, 43200, 768, 256, 0, 768, 0);
  k_prep_rel<<<dim3(900), dim3(256), 0, stream>>>(dc_rel, crRel);
  k_attn_z<0><<<dim3(7200), dim3(256), 0, stream>>>(QKV, crRel, Zb, nullptr, nullptr, nullptr, nullptr);
  k_colstats<<<dim3(288), dim3(256), 0, stream>>>(Zb, crM, crI);
  k_attn_av<<<dim3(7200), dim3(256), 0, stream>>>(Zb, QKV, crM, crI, S4, S3);  // h2 = LN(h1+attn)

  // ---- decoder FFN + head ----
  gemm(S3, df1, d_f1b, HID, 43200, 1024, 256, 1, 1024, 0);
  gemm(HID, df2, d_f2b, S5, 43200, 256, 1024, 0, 256, 0);
  k_add_ln<<<dim3(10800), dim3(256), 0, stream>>>(S3, S5, S4);  // h3
  k_ydot<<<dim3(10800), dim3(256), 0, stream>>>(S4, out_w, out_b, Y);
  k_softmax48<<<dim3(4), dim3(256), 0, stream>>>(Y, OUT);
}

// Round 8
// 973.130 us; speedup vs baseline: 1.0556x; 1.0215x over previous
//
#include <hip/hip_runtime.h>
#include <float.h>

typedef __bf16 bf16;
typedef __attribute__((ext_vector_type(8))) __bf16 bf16x8;
typedef __attribute__((ext_vector_type(4))) __bf16 bf16x4;
typedef __attribute__((ext_vector_type(4))) float f32x4;

__device__ __forceinline__ int imin(int a, int b) { return a < b ? a : b; }

// async global->LDS, 16B per lane; LDS dest = wave-uniform base + lane*16
__device__ __forceinline__ void gl2lds(const bf16* g, bf16* l) {
  __builtin_amdgcn_global_load_lds(
      (const __attribute__((address_space(1))) void*)g,
      (__attribute__((address_space(3))) void*)l, 16, 0, 0);
}

// ---------------- zero-page + padded lin weights (fused tiny prep) ----------------
__global__ void k_prep_misc(bf16* zp, const float* __restrict__ l1w,
                            const float* __restrict__ l2w,
                            bf16* __restrict__ L1p, bf16* __restrict__ L2p) {
  zp[threadIdx.x] = (bf16)0.0f;
  for (int i = threadIdx.x; i < 3456; i += 256) {
    int r = i / 72, c = i - r * 72;
    L1p[i] = (c < 48) ? (bf16)l1w[r * 48 + c] : (bf16)0.0f;
    L2p[i] = (c < 48) ? (bf16)l2w[r * 48 + c] : (bf16)0.0f;
  }
}

// ---------------- fused f32->bf16 casts (13 segments) ----------------
struct CastSegs { const float* s[13]; bf16* d[13]; int n[13]; };
__global__ void k_cast_all(CastSegs sg, int total) {
  int i = blockIdx.x * 256 + threadIdx.x;
  if (i >= total) return;
  for (int k = 0; k < 13; ++k) {
    if (i < sg.n[k]) { sg.d[k][i] = (bf16)sg.s[k][i]; return; }
    i -= sg.n[k];
  }
}

// ---------------- rel transpose via LDS: (sh, k*48+j) fp32 -> (sh, j*32+k) bf16 ----------------
__global__ __launch_bounds__(256) void k_prep_rel(const float* __restrict__ rel,
                                                  bf16* __restrict__ RelT) {
  __shared__ float tile[32 * 49];
  const int t = threadIdx.x;
  for (int u = 0; u < 8; ++u) {
    const size_t sh = (size_t)blockIdx.x * 8 + u;
    const float* src = rel + sh * 1536;
    bf16* dst = RelT + sh * 1536;
    __syncthreads();
    for (int i = t; i < 1536; i += 256) {
      int k = i / 48, j = i - k * 48;
      tile[k * 49 + j] = src[i];
    }
    __syncthreads();
    for (int i = t; i < 1536; i += 256) {
      int j = i >> 5, k = i & 31;
      dst[i] = (bf16)tile[k * 49 + j];
    }
  }
}

// ---------------- X_en|X_de (b,32,32,32) -> XR rows (96*1024, 32ch) bf16 ----------------
__global__ void k_prep_x(const float* __restrict__ XE, const float* __restrict__ XD,
                         bf16* __restrict__ XR) {
  int idx = blockIdx.x * 256 + threadIdx.x;
  if (idx >= 96 * 1024 * 32) return;
  int b = idx >> 15, r = idx & 32767, pos = r >> 5, ic = r & 31;
  const float* X = (b < 48) ? XE : XD;
  int bl = (b < 48) ? b : b - 48;
  XR[idx] = (bf16)X[((size_t)(bl * 32 + ic) << 10) + pos];
}

// ---------------- conv weight pack: (OC,IC,3,3) -> 9 x (OC,IC) bf16 ----------------
__global__ void k_pack_conv(const float* __restrict__ w, bf16* __restrict__ dst,
                            int OC, int IC, int total) {
  int idx = blockIdx.x * 256 + threadIdx.x;
  if (idx >= total) return;
  int t = idx / (OC * IC);
  int rem = idx - t * OC * IC;
  int oc = rem / IC, ic = rem - oc * IC;
  dst[idx] = (bf16)w[(size_t)(oc * IC + ic) * 9 + t];
}

// ---------------- 128x128 GEMM, BK=64, single-buffered, conflict-free LDS ----------
// LDS: A [128][64] at 0, B [128][64] at +8192 (128-B row pitch).
// Swizzle involution: seg' = seg ^ (row&7) (16-B segs, 8/row); gl2lds dest linear,
// SOURCE pre-swizzled, reads swizzled with the same XOR.
// If n0 >= nsplit: use A2/B2 with local n (merged dual-GEMM launch). K%64==0, N%128==0.
__global__ __launch_bounds__(256, 2) void k_gemm128(
    const bf16* __restrict__ A, const bf16* __restrict__ A2,
    const bf16* __restrict__ B, const bf16* __restrict__ B2, int nsplit,
    const float* __restrict__ bias, bf16* __restrict__ C,
    int M, int N, int K, int relu, int ldc, int coff) {
  __shared__ alignas(16) bf16 SM[16384];
  const int t = threadIdx.x, wave = t >> 6;
  const int lane = t & 63, fr = lane & 15, kq = lane >> 4;
  const int wm = wave & 1, wn = wave >> 1;
  const int m0 = blockIdx.x * 128, n0 = blockIdx.y * 128;
  const bf16* Ause = A; const bf16* Buse = B; int nloc = n0;
  if (n0 >= nsplit) { Ause = A2; Buse = B2; nloc = n0 - nsplit; }
  // staging map: thread t covers (row = r*32 + (t>>3), seg = t&7), r = 0..3 for A and B
  const int srow = t >> 3;
  const int sg8 = (((t & 7) ^ (srow & 7)) << 3);  // pre-swizzled source k-seg (elements)
  const bf16* gA[4]; const bf16* gB[4];
#pragma unroll
  for (int r = 0; r < 4; ++r) {
    gA[r] = Ause + (size_t)imin(m0 + r * 32 + srow, M - 1) * K + sg8;
    gB[r] = Buse + (size_t)(nloc + r * 32 + srow) * K + sg8;
  }
  // fragment-read offsets (elements); ^32 switches k-halves
  const int swz = (kq ^ (fr & 7)) << 3;
  const int aoff = (wm * 64 + fr) * 64 + swz;
  const int boff = 8192 + (wn * 64 + fr) * 64 + swz;
  f32x4 acc[4][4] = {};
  for (int k0 = 0; k0 < K; k0 += 64) {
    bf16* db = SM + wave * 512;
#pragma unroll
    for (int r = 0; r < 4; ++r) gl2lds(gA[r] + k0, db + r * 2048);
#pragma unroll
    for (int r = 0; r < 4; ++r) gl2lds(gB[r] + k0, db + 8192 + r * 2048);
    __syncthreads();
#pragma unroll
    for (int kk = 0; kk < 2; ++kk) {
      const int xo = kk << 5;
      bf16x8 af[4], bw[4];
#pragma unroll
      for (int mt = 0; mt < 4; ++mt)
        af[mt] = *(const bf16x8*)(SM + ((aoff + mt * 1024) ^ xo));
#pragma unroll
      for (int nt = 0; nt < 4; ++nt)
        bw[nt] = *(const bf16x8*)(SM + ((boff + nt * 1024) ^ xo));
#pragma unroll
      for (int mt = 0; mt < 4; ++mt)
#pragma unroll
        for (int nt = 0; nt < 4; ++nt)
          acc[mt][nt] = __builtin_amdgcn_mfma_f32_16x16x32_bf16(af[mt], bw[nt], acc[mt][nt], 0, 0, 0);
    }
    __syncthreads();
  }
  bf16* Cst = SM;  // 64 x 136 (padded pitch: conflict-free epilogue)
  for (int half = 0; half < 2; ++half) {
    if (wm == half) {
      for (int mt = 0; mt < 4; ++mt)
        for (int nt = 0; nt < 4; ++nt) {
          int n = n0 + wn * 64 + nt * 16 + fr;
          float bv = bias ? bias[n] : 0.0f;
          for (int r = 0; r < 4; ++r) {
            float v = acc[mt][nt][r] + bv;
            if (relu) v = fmaxf(v, 0.0f);
            Cst[(mt * 16 + kq * 4 + r) * 136 + wn * 64 + nt * 16 + fr] = (bf16)v;
          }
        }
    }
    __syncthreads();
    for (int i = t; i < 1024; i += 256) {
      int r = i >> 4, cs = i & 15;
      int gm = m0 + half * 64 + r;
      if (gm < M)
        *(bf16x8*)(C + (size_t)gm * ldc + coff + n0 + cs * 8) = *(const bf16x8*)(Cst + r * 136 + cs * 8);
    }
    __syncthreads();
  }
}

// ---------------- conv1 (BK=32): shifted 128x128 GEMM, merged 96 batches ----------------
template <int CIN, int PAD, int SRCW, int SRCROWS, int CHECK, int TRANS, int MTOT>
__global__ __launch_bounds__(256, 2) void k_conv128(
    const bf16* __restrict__ A, const bf16* __restrict__ Bp,
    const float* __restrict__ bias, bf16* __restrict__ C,
    const bf16* __restrict__ zpage) {
  __shared__ alignas(16) bf16 SM[8192];
  bf16* As = SM;
  bf16* Bs = SM + 4096;
  const int t = threadIdx.x, wave = t >> 6;
  const int lane = t & 63, fr = lane & 15, kq = lane >> 4;
  const int wm = wave & 1, wn = wave >> 1;
  const int m0 = blockIdx.x * 128, n0 = blockIdx.y * 128;
  const int srow = t >> 2, kseg = (t & 3) * 8;
  f32x4 acc[4][4] = {};
  int bb[2], yy[2], xx[2];
  for (int hf = 0; hf < 2; ++hf) {
    int m = imin(m0 + hf * 64 + srow, MTOT - 1);
    int b = m / 900, p = m - b * 900;
    bb[hf] = b; yy[hf] = p / 30; xx[hf] = p - (p / 30) * 30;
  }
  bf16* sA0 = As + wave * 512;
  bf16* sA1 = As + 2048 + wave * 512;
  bf16* sB0 = Bs + wave * 512;
  bf16* sB1 = Bs + 2048 + wave * 512;
  for (int k0 = 0; k0 < CIN; k0 += 32) {
    for (int t9 = 0; t9 < 9; ++t9) {
      const int ky = t9 / 3, kx = t9 - ky * 3;
      const bf16* ga[2];
      for (int hf = 0; hf < 2; ++hf) {
        int sy = yy[hf] + ky - PAD, sx = xx[hf] + kx - PAD;
        bool valid = !CHECK || (sy >= 0 && sy < SRCW && sx >= 0 && sx < SRCW);
        ga[hf] = (valid ? A + (size_t)(bb[hf] * SRCROWS + sy * SRCW + sx) * CIN : zpage) + kseg;
      }
      const bf16* gb = Bp + (size_t)(t9 * 256 + n0 + srow) * CIN + kseg;
      gl2lds(ga[0] + k0, sA0);
      gl2lds(ga[1] + k0, sA1);
      gl2lds(gb + k0, sB0);
      gl2lds(gb + (size_t)64 * CIN + k0, sB1);
      __syncthreads();
      bf16x8 af[4], bw[4];
      for (int mt = 0; mt < 4; ++mt)
        af[mt] = *(const bf16x8*)(As + (wm * 64 + mt * 16 + fr) * 32 + kq * 8);
      for (int nt = 0; nt < 4; ++nt)
        bw[nt] = *(const bf16x8*)(Bs + (wn * 64 + nt * 16 + fr) * 32 + kq * 8);
      for (int mt = 0; mt < 4; ++mt)
        for (int nt = 0; nt < 4; ++nt)
          acc[mt][nt] = __builtin_amdgcn_mfma_f32_16x16x32_bf16(af[mt], bw[nt], acc[mt][nt], 0, 0, 0);
      __syncthreads();
    }
  }
  bf16* Cst = SM;
  for (int half = 0; half < 2; ++half) {
    if (wm == half) {
      for (int mt = 0; mt < 4; ++mt)
        for (int nt = 0; nt < 4; ++nt) {
          int n = n0 + wn * 64 + nt * 16 + fr;
          float bv = bias[n];
          for (int r = 0; r < 4; ++r) {
            float v = acc[mt][nt][r] + bv;
            if (TRANS)
              Cst[(wn * 64 + nt * 16 + fr) * 64 + mt * 16 + kq * 4 + r] = (bf16)v;
            else
              Cst[(mt * 16 + kq * 4 + r) * 128 + wn * 64 + nt * 16 + fr] = (bf16)v;
          }
        }
    }
    __syncthreads();
    if (TRANS) {
      for (int i = t; i < 2048; i += 256) {
        int oc = i >> 4, pc = i & 15;
        int gm = m0 + half * 64 + pc * 4;
        if (gm < MTOT) {
          int b = gm / 900, p = gm - b * 900;
          *(bf16x4*)(C + (size_t)(b * 256 + n0 + oc) * 900 + p) = *(const bf16x4*)(Cst + oc * 64 + pc * 4);
        }
      }
    } else {
      for (int i = t; i < 1024; i += 256) {
        int r = i >> 4, cs = i & 15;
        int gm = m0 + half * 64 + r;
        if (gm < MTOT)
          *(bf16x8*)(C + (size_t)gm * 256 + n0 + cs * 8) = *(const bf16x8*)(Cst + r * 128 + cs * 8);
      }
    }
    __syncthreads();
  }
}

// ---------------- conv2 (CIN=256, pad=1): k0-outer/tap-inner (L2-tight), BK=64,
// single-buffered 32 KiB, conflict-free [128][64] swizzled LDS, merged 96 batches ----
__global__ __launch_bounds__(256, 2) void k_conv2x(
    const bf16* __restrict__ A, const bf16* __restrict__ Bp,
    const float* __restrict__ bias, bf16* __restrict__ C,
    const bf16* __restrict__ zpage) {
  __shared__ alignas(16) bf16 SM[16384];
  const int t = threadIdx.x, wave = t >> 6;
  const int lane = t & 63, fr = lane & 15, kq = lane >> 4;
  const int wm = wave & 1, wn = wave >> 1;
  const int m0 = blockIdx.x * 128, n0 = blockIdx.y * 128;
  const int srow = t >> 3;                            // staged row slot (0..31)
  const int sg8 = (((t & 7) ^ (srow & 7)) << 3);      // pre-swizzled source k-seg
  // decode the 4 A-rows this thread stages (positions, clamped)
  int pb[4], py[4], px[4];
#pragma unroll
  for (int r = 0; r < 4; ++r) {
    int m = imin(m0 + r * 32 + srow, 86399);
    int b = m / 900, p = m - b * 900;
    pb[r] = b * 900; py[r] = p / 30; px[r] = p - (p / 30) * 30;
  }
  const int swz = (kq ^ (fr & 7)) << 3;
  const int aoff = (wm * 64 + fr) * 64 + swz;
  const int boff = 8192 + (wn * 64 + fr) * 64 + swz;
  f32x4 acc[4][4] = {};
  for (int k0 = 0; k0 < 256; k0 += 64) {
    for (int t9 = 0; t9 < 9; ++t9) {
      const int ky = t9 / 3, kx = t9 - ky * 3;
      bf16* db = SM + wave * 512;
#pragma unroll
      for (int r = 0; r < 4; ++r) {
        int sy = py[r] + ky - 1, sx = px[r] + kx - 1;
        bool valid = (sy >= 0 && sy < 30 && sx >= 0 && sx < 30);
        const bf16* g = valid ? (A + (size_t)(pb[r] + sy * 30 + sx) * 256 + k0 + sg8)
                              : (zpage + sg8);
        gl2lds(g, db + r * 2048);
      }
#pragma unroll
      for (int r = 0; r < 4; ++r)
        gl2lds(Bp + (size_t)(t9 * 256 + n0 + r * 32 + srow) * 256 + k0 + sg8,
               db + 8192 + r * 2048);
      __syncthreads();
#pragma unroll
      for (int kk = 0; kk < 2; ++kk) {
        const int xo = kk << 5;
        bf16x8 af[4], bw[4];
#pragma unroll
        for (int mt = 0; mt < 4; ++mt)
          af[mt] = *(const bf16x8*)(SM + ((aoff + mt * 1024) ^ xo));
#pragma unroll
        for (int nt = 0; nt < 4; ++nt)
          bw[nt] = *(const bf16x8*)(SM + ((boff + nt * 1024) ^ xo));
#pragma unroll
        for (int mt = 0; mt < 4; ++mt)
#pragma unroll
          for (int nt = 0; nt < 4; ++nt)
            acc[mt][nt] = __builtin_amdgcn_mfma_f32_16x16x32_bf16(af[mt], bw[nt], acc[mt][nt], 0, 0, 0);
      }
      __syncthreads();
    }
  }
  bf16* Cst = SM;  // 128 oc x 68 (padded pitch: conflict-free epilogue)
  for (int half = 0; half < 2; ++half) {
    if (wm == half) {
      for (int mt = 0; mt < 4; ++mt)
        for (int nt = 0; nt < 4; ++nt) {
          int n = n0 + wn * 64 + nt * 16 + fr;
          float bv = bias[n];
          for (int r = 0; r < 4; ++r) {
            float v = acc[mt][nt][r] + bv;
            Cst[(wn * 64 + nt * 16 + fr) * 68 + mt * 16 + kq * 4 + r] = (bf16)v;
          }
        }
    }
    __syncthreads();
    for (int i = t; i < 2048; i += 256) {
      int oc = i >> 4, pc = i & 15;
      int gm = m0 + half * 64 + pc * 4;
      int b = gm / 900, p = gm - b * 900;
      *(bf16x4*)(C + (size_t)(b * 256 + n0 + oc) * 900 + p) = *(const bf16x4*)(Cst + oc * 68 + pc * 4);
    }
    __syncthreads();
  }
}

// ---------------- attention logits z for one (s,h) ----------------
template <int MASKED>
__global__ __launch_bounds__(256, MASKED ? 4 : 5) void k_attn_z(
    const bf16* __restrict__ QKV, const bf16* __restrict__ RelT, bf16* __restrict__ Z,
    const bf16* __restrict__ L1p, const bf16* __restrict__ L2p,
    const float* __restrict__ l1b, const float* __restrict__ l2b) {
  __shared__ alignas(16) bf16 QKs[2][48 * 40];
  __shared__ float EMD[48 * 49];
  __shared__ alignas(16) bf16 zst[48 * 48];
  __shared__ alignas(16) bf16 Sc[MASKED ? 48 * 72 : 8];
  __shared__ alignas(16) bf16 T2b[MASKED ? 48 * 72 : 8];
  const int sh = blockIdx.x, s = sh >> 3, h = sh & 7;
  const int t = threadIdx.x, wave = t >> 6, lane = t & 63, fr = lane & 15, kq = lane >> 4;
  const float scale = 0.17677669529663687f;  // 1/sqrt(32)
  for (int c = t; c < 384; c += 256) {
    int half = c >= 192 ? 1 : 0, cc = c - half * 192;
    int row = cc >> 2, seg = cc & 3;
    *(bf16x8*)(&QKs[half][row * 40 + seg * 8]) =
        *(const bf16x8*)(QKV + (size_t)(s * 48 + row) * 768 + half * 256 + h * 32 + seg * 8);
  }
  if constexpr (MASKED) {
    for (int i = t; i < 768; i += 256) {
      int r = i >> 4, c = 48 + (i & 15);
      Sc[r * 72 + c] = (bf16)0.0f;
      T2b[r * 72 + c] = (bf16)0.0f;
    }
  }
  __syncthreads();
  const bf16* relb = RelT + (size_t)sh * 1536;
  f32x4 sreg[3];
  int u = 0;
  for (int t9 = wave; t9 < 9; t9 += 4, ++u) {
    int ti = t9 / 3, tj = t9 - ti * 3;
    bf16x8 af = *(const bf16x8*)(&QKs[0][(ti * 16 + fr) * 40 + kq * 8]);
    bf16x8 bk = *(const bf16x8*)(&QKs[1][(tj * 16 + fr) * 40 + kq * 8]);
    bf16x8 rf = *(const bf16x8*)(relb + (tj * 16 + fr) * 32 + kq * 8);
    f32x4 sacc = {}, eacc = {};
    sacc = __builtin_amdgcn_mfma_f32_16x16x32_bf16(af, bk, sacc, 0, 0, 0);
    eacc = __builtin_amdgcn_mfma_f32_16x16x32_bf16(af, rf, eacc, 0, 0, 0);
    for (int r = 0; r < 4; ++r)
      EMD[(ti * 16 + kq * 4 + r) * 49 + tj * 16 + fr] = eacc[r];
    if constexpr (MASKED) {
      for (int r = 0; r < 4; ++r)
        Sc[(ti * 16 + kq * 4 + r) * 72 + tj * 16 + fr] = (bf16)(sacc[r] * scale);
    } else {
      for (int r = 0; r < 4; ++r) sreg[u][r] = sacc[r] * scale;
    }
  }
  __syncthreads();
  if constexpr (!MASKED) {
    u = 0;
    for (int t9 = wave; t9 < 9; t9 += 4, ++u) {
      int ti = t9 / 3, tj = t9 - ti * 3;
      for (int r = 0; r < 4; ++r) {
        int i = ti * 16 + kq * 4 + r, j = tj * 16 + fr;
        float v = sreg[u][r];
        if (j <= i) v += EMD[i * 49 + 47 + j - i];
        zst[i * 48 + j] = (bf16)v;
      }
    }
  } else {
    for (int t9 = wave; t9 < 9; t9 += 4) {
      int ti = t9 / 3, tj = t9 - ti * 3;
      f32x4 a2 = {};
      for (int k0 = 0; k0 < 64; k0 += 32) {
        bf16x8 af = *(const bf16x8*)(Sc + (ti * 16 + fr) * 72 + k0 + kq * 8);
        bf16x8 bw = *(const bf16x8*)(L1p + (tj * 16 + fr) * 72 + k0 + kq * 8);
        a2 = __builtin_amdgcn_mfma_f32_16x16x32_bf16(af, bw, a2, 0, 0, 0);
      }
      for (int r = 0; r < 4; ++r) {
        int i = ti * 16 + kq * 4 + r, a = tj * 16 + fr;
        T2b[a * 72 + i] = (bf16)(a2[r] + l1b[a]);
      }
    }
    __syncthreads();
    for (int t9 = wave; t9 < 9; t9 += 4) {
      int ti = t9 / 3, tj = t9 - ti * 3;
      f32x4 a2 = {};
      for (int k0 = 0; k0 < 64; k0 += 32) {
        bf16x8 af = *(const bf16x8*)(T2b + (ti * 16 + fr) * 72 + k0 + kq * 8);
        bf16x8 bw = *(const bf16x8*)(L2p + (tj * 16 + fr) * 72 + k0 + kq * 8);
        a2 = __builtin_amdgcn_mfma_f32_16x16x32_bf16(af, bw, a2, 0, 0, 0);
      }
      for (int r = 0; r < 4; ++r) {
        int aa = ti * 16 + kq * 4 + r, cc = tj * 16 + fr;
        float v;
        if (cc > aa) v = -10000.0f;  // masked column -> exactly uniform after softmax
        else v = a2[r] + l2b[cc] + EMD[aa * 49 + 47 + cc - aa];
        zst[aa * 48 + cc] = (bf16)v;
      }
    }
  }
  __syncthreads();
  bf16* zb = Z + (size_t)sh * 2304;
  for (int c = t; c < 288; c += 256)
    *(bf16x8*)(zb + c * 8) = *(const bf16x8*)(zst + c * 8);
}

// ---------------- per-column (over s=900) online max & inverse-sum ----------------
// grid 288: 64 cols/block (8 thr x 8 cols, bf16x8) x 32 s-groups of 29
__global__ __launch_bounds__(256) void k_colstats(const bf16* __restrict__ Z,
                                                  float* __restrict__ Mc, float* __restrict__ Ic) {
  __shared__ float rm[32][72], rs[32][72];
  const int t = threadIdx.x, cg = t & 7, sg = t >> 3;
  const bf16* p = Z + blockIdx.x * 64 + cg * 8;
  const int s0 = sg * 29, s1 = imin(900, s0 + 29);
  float m[8], ss[8];
  for (int e = 0; e < 8; ++e) { m[e] = -FLT_MAX; ss[e] = 0.0f; }
  for (int s = s0; s < s1; ++s) {
    bf16x8 zv = *(const bf16x8*)(p + (size_t)s * 18432);
    for (int e = 0; e < 8; ++e) {
      float v = (float)zv[e];
      if (v > m[e]) { ss[e] *= __expf(m[e] - v); m[e] = v; }
      ss[e] += __expf(v - m[e]);
    }
  }
  for (int e = 0; e < 8; ++e) { rm[sg][cg * 8 + e] = m[e]; rs[sg][cg * 8 + e] = ss[e]; }
  __syncthreads();
  if (t < 64) {
    float M2 = -FLT_MAX;
    for (int g = 0; g < 32; ++g) M2 = fmaxf(M2, rm[g][t]);
    float S2 = 0.0f;
    for (int g = 0; g < 32; ++g) S2 += rs[g][t] * __expf(rm[g][t] - M2);
    Mc[blockIdx.x * 64 + t] = M2;
    Ic[blockIdx.x * 64 + t] = 1.0f / S2;
  }
}

// ---------------- O = LN(RES + softmax(Z) V) for one (s,h); writes 6 rows of 256 ----
// attn output for block sh is 1536 contiguous elements = flat rows [6*sh, 6*sh+6) of
// the (b, sl, 256) view; each row is fully block-local, so add+LN fuses here.
__global__ __launch_bounds__(256, 6) void k_attn_av(
    const bf16* __restrict__ Z, const bf16* __restrict__ QKV,
    const float* __restrict__ Mc, const float* __restrict__ Ic,
    const bf16* __restrict__ RES, bf16* __restrict__ O) {
  __shared__ alignas(16) bf16 Ps[48 * 72];
  __shared__ alignas(16) bf16 Vt[32 * 72];
  __shared__ alignas(16) bf16 Ost[48 * 32];
  const int sh = blockIdx.x, s = sh >> 3, h = sh & 7;
  const int t = threadIdx.x, wave = t >> 6, lane = t & 63, fr = lane & 15, kq = lane >> 4;
  for (int i = t; i < 768; i += 256) Ps[(i >> 4) * 72 + 48 + (i & 15)] = (bf16)0.0f;
  for (int i = t; i < 512; i += 256) Vt[(i >> 4) * 72 + 48 + (i & 15)] = (bf16)0.0f;
  const bf16* zb = Z + (size_t)sh * 2304;
  const float* mc = Mc + h * 2304;
  const float* ic = Ic + h * 2304;
  for (int c = t; c < 288; c += 256) {
    int r = c / 6, seg = c - r * 6;
    int idx = r * 48 + seg * 8;
    bf16x8 zv = *(const bf16x8*)(zb + idx);
    f32x4 m0v = *(const f32x4*)(mc + idx), m1v = *(const f32x4*)(mc + idx + 4);
    f32x4 i0v = *(const f32x4*)(ic + idx), i1v = *(const f32x4*)(ic + idx + 4);
    bf16x8 pv;
    for (int e = 0; e < 4; ++e) pv[e] = (bf16)(__expf((float)zv[e] - m0v[e]) * i0v[e]);
    for (int e = 0; e < 4; ++e) pv[4 + e] = (bf16)(__expf((float)zv[4 + e] - m1v[e]) * i1v[e]);
    *(bf16x8*)(Ps + r * 72 + seg * 8) = pv;
  }
  for (int c = t; c < 192; c += 256) {
    int j = c >> 2, seg = c & 3;
    bf16x8 v = *(const bf16x8*)(QKV + (size_t)(s * 48 + j) * 768 + 512 + h * 32 + seg * 8);
    for (int e = 0; e < 8; ++e) Vt[(seg * 8 + e) * 72 + j] = v[e];
  }
  __syncthreads();
  for (int t6 = wave; t6 < 6; t6 += 4) {
    int ti = t6 >> 1, td = t6 & 1;
    f32x4 a2 = {};
    for (int k0 = 0; k0 < 64; k0 += 32) {
      bf16x8 af = *(const bf16x8*)(Ps + (ti * 16 + fr) * 72 + k0 + kq * 8);
      bf16x8 bv = *(const bf16x8*)(Vt + (td * 16 + fr) * 72 + k0 + kq * 8);
      a2 = __builtin_amdgcn_mfma_f32_16x16x32_bf16(af, bv, a2, 0, 0, 0);
    }
    for (int r = 0; r < 4; ++r)
      Ost[(ti * 16 + kq * 4 + r) * 32 + td * 16 + fr] = (bf16)a2[r];
  }
  __syncthreads();
  // fused add + LayerNorm: 6 rows of 256, 1 row per wave (2 rounds) — k_add_ln math
  const size_t base = (size_t)sh * 1536;
  for (int r = wave; r < 6; r += 4) {
    const size_t off = base + r * 256 + lane * 4;
    bf16x4 av = *(const bf16x4*)(Ost + r * 256 + lane * 4);
    bf16x4 bv = *(const bf16x4*)(RES + off);
    f32x4 x;
    for (int c = 0; c < 4; ++c) x[c] = (float)av[c] + (float)bv[c];
    float sum = x[0] + x[1] + x[2] + x[3];
    for (int o = 1; o < 64; o <<= 1) sum += __shfl_xor(sum, o);
    float mean = sum * (1.0f / 256.0f);
    float q = 0.0f;
    for (int c = 0; c < 4; ++c) { float d = x[c] - mean; q += d * d; }
    for (int o = 1; o < 64; o <<= 1) q += __shfl_xor(q, o);
    float rstd = rsqrtf(q * (1.0f / 256.0f) + 1e-5f);
    bf16x4 y;
    for (int c = 0; c < 4; ++c) y[c] = (bf16)((x[c] - mean) * rstd);
    *(bf16x4*)(O + off) = y;
  }
}

// ---------------- out = LN(Xa + Xb), rows of 256, bf16 ----------------
__global__ __launch_bounds__(256) void k_add_ln(
    const bf16* __restrict__ Xa, const bf16* __restrict__ Xb, bf16* __restrict__ out) {
  const int t = threadIdx.x, lane = t & 63, w = t >> 6;
  const size_t off = ((size_t)blockIdx.x * 4 + w) * 256 + lane * 4;
  bf16x4 av = *(const bf16x4*)(Xa + off);
  bf16x4 bv = *(const bf16x4*)(Xb + off);
  f32x4 x;
  for (int c = 0; c < 4; ++c) x[c] = (float)av[c] + (float)bv[c];
  float sum = x[0] + x[1] + x[2] + x[3];
  for (int o = 1; o < 64; o <<= 1) sum += __shfl_xor(sum, o);
  float mean = sum * (1.0f / 256.0f);
  float q = 0.0f;
  for (int c = 0; c < 4; ++c) { float d = x[c] - mean; q += d * d; }
  for (int o = 1; o < 64; o <<= 1) q += __shfl_xor(q, o);
  float rstd = rsqrtf(q * (1.0f / 256.0f) + 1e-5f);
  bf16x4 y;
  for (int c = 0; c < 4; ++c) y[c] = (bf16)((x[c] - mean) * rstd);
  *(bf16x4*)(out + off) = y;
}

// ---------------- Y[row] = dot(LN(Xa+Xb)[row], w) + b  (h3 never materialized) ----
__global__ __launch_bounds__(256) void k_add_ln_ydot(
    const bf16* __restrict__ Xa, const bf16* __restrict__ Xb,
    const float* __restrict__ w, const float* __restrict__ b,
    float* __restrict__ Y) {
  const int t = threadIdx.x, lane = t & 63, wv = t >> 6;
  const size_t row = (size_t)blockIdx.x * 4 + wv;
  const size_t off = row * 256 + lane * 4;
  bf16x4 av = *(const bf16x4*)(Xa + off);
  bf16x4 bv = *(const bf16x4*)(Xb + off);
  f32x4 x;
  for (int c = 0; c < 4; ++c) x[c] = (float)av[c] + (float)bv[c];
  float sum = x[0] + x[1] + x[2] + x[3];
  for (int o = 1; o < 64; o <<= 1) sum += __shfl_xor(sum, o);
  float mean = sum * (1.0f / 256.0f);
  float q = 0.0f;
  for (int c = 0; c < 4; ++c) { float d = x[c] - mean; q += d * d; }
  for (int o = 1; o < 64; o <<= 1) q += __shfl_xor(q, o);
  float rstd = rsqrtf(q * (1.0f / 256.0f) + 1e-5f);
  f32x4 ww = *(const f32x4*)(w + lane * 4);
  float yv = 0.0f;
  for (int c = 0; c < 4; ++c) yv += (x[c] - mean) * rstd * ww[c];
  for (int o = 1; o < 64; o <<= 1) yv += __shfl_xor(yv, o);
  if (lane == 0) Y[row] = yv + b[0];
}

// ---------------- softmax over b (48) per column ----------------
__global__ void k_softmax48(const float* __restrict__ Y, float* __restrict__ O) {
  int ss = blockIdx.x * 256 + threadIdx.x;
  if (ss >= 900) return;
  float m = -FLT_MAX;
  for (int b = 0; b < 48; ++b) m = fmaxf(m, Y[b * 900 + ss]);
  float sum = 0.0f;
  for (int b = 0; b < 48; ++b) sum += __expf(Y[b * 900 + ss] - m);
  float inv = 1.0f / sum;
  for (int b = 0; b < 48; ++b) O[b * 900 + ss] = __expf(Y[b * 900 + ss] - m) * inv;
}

extern "C" void kernel_launch(void* const* d_in, const int* in_sizes, int n_in,
                              void* d_out, int out_size, void* d_ws, size_t ws_size,
                              hipStream_t stream) {
  (void)in_sizes; (void)n_in; (void)out_size;
  const float* X_en = (const float*)d_in[0];
  const float* X_de = (const float*)d_in[1];
  const float* conv1_w = (const float*)d_in[2];
  const float* conv1_b = (const float*)d_in[3];
  const float* conv2_w = (const float*)d_in[4];
  const float* conv2_b = (const float*)d_in[5];
  const float* enc_wq = (const float*)d_in[6];
  const float* enc_wk = (const float*)d_in[7];
  const float* enc_wv = (const float*)d_in[8];
  const float* enc_rel = (const float*)d_in[9];
  const float* enc_f1w = (const float*)d_in[10];
  const float* enc_f1b = (const float*)d_in[11];
  const float* enc_f2w = (const float*)d_in[12];
  const float* enc_f2b = (const float*)d_in[13];
  const float* dm_wq = (const float*)d_in[14];
  const float* dm_wk = (const float*)d_in[15];
  const float* dm_wv = (const float*)d_in[16];
  const float* dm_rel = (const float*)d_in[17];
  const float* dm_l1w = (const float*)d_in[18];
  const float* dm_l1b = (const float*)d_in[19];
  const float* dm_l2w = (const float*)d_in[20];
  const float* dm_l2b = (const float*)d_in[21];
  const float* dc_wq = (const float*)d_in[22];
  const float* dc_wk = (const float*)d_in[23];
  const float* dc_wv = (const float*)d_in[24];
  const float* dc_rel = (const float*)d_in[25];
  const float* d_f1w = (const float*)d_in[26];
  const float* d_f1b = (const float*)d_in[27];
  const float* d_f2w = (const float*)d_in[28];
  const float* d_f2b = (const float*)d_in[29];
  const float* out_w = (const float*)d_in[30];
  const float* out_b = (const float*)d_in[31];
  float* OUT = (float*)d_out;

  // ---- workspace layout ----
  const size_t SLOT = 22118400;  // 43200*256 bf16
  char* ws = (char*)d_ws;
  size_t o = 0;
  bf16* S1 = (bf16*)(ws + o); o += SLOT;  // XEb -> ENCb
  bf16* S2 = (bf16*)(ws + o); o += SLOT;  // XDb -> (cross stats)
  bf16* S3 = (bf16*)(ws + o); o += SLOT;  // (enc RelT) -> o1 -> (dm stats) -> (cross RelT) -> h2
  bf16* S4 = (bf16*)(ws + o); o += SLOT;  // (enc stats) -> h1
  bf16* S5 = (bf16*)(ws + o); o += SLOT;  // ffn-out / (dm RelT)
  char* U = ws + o; o += 33177600 + 3 * SLOT;  // Z + QKV, union { HID, XR+C1R }
  bf16* Zb = (bf16*)U;
  bf16* QKV = (bf16*)(U + 33177600);
  bf16* XR = (bf16*)U;                    // conv phase: 96*1024*32 bf16 = 12.6 MB
  bf16* C1R = (bf16*)(U + 12582912);      // conv phase: 96*900*256 bf16 = 44.2 MB
  bf16* HID = (bf16*)U;                   // FFN phase only
  bf16* wa = (bf16*)(ws + o); o += 4603904 + 16384;
  float* Y = (float*)(ws + o); o += 172800;
  if (ws_size < o) return;

  bf16* zpage = (bf16*)Y;  // 512 B zero page; Y dead until k_add_ln_ydot
  float* encM = (float*)S4; float* encI = encM + 18432;
  float* dmM  = (float*)S3; float* dmI  = dmM + 18432;
  float* crM  = (float*)S2; float* crI  = crM + 18432;
  bf16* encRel = S3;   // free until o1 written
  bf16* dmRel  = S5;   // free until dm attn_av writes S5
  bf16* crRel  = S3;   // o1 dead after enc_out

  // weight arena (element offsets)
  bf16* c1p = wa;
  bf16* c2p = wa + 73728;
  bf16* EQKVw = wa + 663552;
  bf16* MQKVw = wa + 860160;
  bf16* cqw = wa + 1056768;
  bf16* CKVw = wa + 1122304;
  bf16* ef1 = wa + 1253376;
  bf16* ef2 = wa + 1515520;
  bf16* df1 = wa + 1777664;
  bf16* df2 = wa + 2039808;
  bf16* L1p = wa + 2301952;
  bf16* L2p = wa + 2305408;

  auto gemm = [&](const bf16* A, const bf16* B, const float* bias, bf16* C,
                  int M, int N, int K, int relu, int ldc, int coff) {
    k_gemm128<<<dim3((M + 127) / 128, N / 128), dim3(256), 0, stream>>>(
        A, A, B, B, N, bias, C, M, N, K, relu, ldc, coff);
  };

  // ---- weight prep ----
  k_prep_misc<<<dim3(1), dim3(256), 0, stream>>>(zpage, dm_l1w, dm_l2w, L1p, L2p);
  k_pack_conv<<<dim3(288), dim3(256), 0, stream>>>(conv1_w, c1p, 256, 32, 73728);
  k_pack_conv<<<dim3(2304), dim3(256), 0, stream>>>(conv2_w, c2p, 256, 256, 589824);
  {
    CastSegs sg;
    const float* srcs[13] = {enc_wq, enc_wk, enc_wv, dm_wq, dm_wk, dm_wv, dc_wq,
                             dc_wk, dc_wv, enc_f1w, enc_f2w, d_f1w, d_f2w};
    bf16* dsts[13] = {EQKVw, EQKVw + 65536, EQKVw + 131072, MQKVw, MQKVw + 65536,
                      MQKVw + 131072, cqw, CKVw, CKVw + 65536, ef1, ef2, df1, df2};
    int ns[13] = {65536, 65536, 65536, 65536, 65536, 65536, 65536, 65536, 65536,
                  262144, 262144, 262144, 262144};
    int total = 0;
    for (int k = 0; k < 13; ++k) { sg.s[k] = srcs[k]; sg.d[k] = dsts[k]; sg.n[k] = ns[k]; total += ns[k]; }
    k_cast_all<<<dim3((total + 255) / 256), dim3(256), 0, stream>>>(sg, total);
  }

  // ---- merged conv chain (96 batches: en then de; conv2 writes S1||S2 contiguously) ----
  k_prep_x<<<dim3(12288), dim3(256), 0, stream>>>(X_en, X_de, XR);
  k_conv128<32, 0, 32, 1024, 0, 0, 86400><<<dim3(675, 2), dim3(256), 0, stream>>>(
      XR, c1p, conv1_b, C1R, zpage);
  k_conv2x<<<dim3(675, 2), dim3(256), 0, stream>>>(C1R, c2p, conv2_b, S1, zpage);

  // ---- encoder ----
  gemm(S1, EQKVw, nullptr, QKV, 43200, 768, 256, 0, 768, 0);
  k_prep_rel<<<dim3(900), dim3(256), 0, stream>>>(enc_rel, encRel);
  k_attn_z<0><<<dim3(7200), dim3(256), 0, stream>>>(QKV, encRel, Zb, nullptr, nullptr, nullptr, nullptr);
  k_colstats<<<dim3(288), dim3(256), 0, stream>>>(Zb, encM, encI);
  k_attn_av<<<dim3(7200), dim3(256), 0, stream>>>(Zb, QKV, encM, encI, S1, S3);  // o1 = LN(S1+attn)
  gemm(S3, ef1, enc_f1b, HID, 43200, 1024, 256, 1, 1024, 0);
  gemm(HID, ef2, enc_f2b, S5, 43200, 256, 1024, 0, 256, 0);
  k_add_ln<<<dim3(10800), dim3(256), 0, stream>>>(S3, S5, S1);  // enc_out

  // ---- decoder masked self-attention ----
  gemm(S2, MQKVw, nullptr, QKV, 43200, 768, 256, 0, 768, 0);
  k_prep_rel<<<dim3(900), dim3(256), 0, stream>>>(dm_rel, dmRel);
  k_attn_z<1><<<dim3(7200), dim3(256), 0, stream>>>(QKV, dmRel, Zb, L1p, L2p, dm_l1b, dm_l2b);
  k_colstats<<<dim3(288), dim3(256), 0, stream>>>(Zb, dmM, dmI);
  k_attn_av<<<dim3(7200), dim3(256), 0, stream>>>(Zb, QKV, dmM, dmI, S2, S4);  // h1 = LN(S2+attn)

  // ---- cross attention (q + kv merged into one dual-GEMM launch) ----
  k_gemm128<<<dim3(338, 6), dim3(256), 0, stream>>>(
      S4, S1, cqw, CKVw, 256, nullptr, QKV, 43200, 768, 256, 0, 768, 0);
  k_prep_rel<<<dim3(900), dim3(256), 0, stream>>>(dc_rel, crRel);
  k_attn_z<0><<<dim3(7200), dim3(256), 0, stream>>>(QKV, crRel, Zb, nullptr, nullptr, nullptr, nullptr);
  k_colstats<<<dim3(288), dim3(256), 0, stream>>>(Zb, crM, crI);
  k_attn_av<<<dim3(7200), dim3(256), 0, stream>>>(Zb, QKV, crM, crI, S4, S3);  // h2 = LN(h1+attn)

  // ---- decoder FFN + head (h3 fused away: Y = dot(LN(h2 + FFN2), out_w) + out_b) ----
  gemm(S3, df1, d_f1b, HID, 43200, 1024, 256, 1, 1024, 0);
  gemm(HID, df2, d_f2b, S5, 43200, 256, 1024, 0, 256, 0);
  k_add_ln_ydot<<<dim3(10800), dim3(256), 0, stream>>>(S3, S5, out_w, out_b, Y);
  k_softmax48<<<dim3(4), dim3(256), 0, stream>>>(Y, OUT);
}

// Round 9
// 960.569 us; speedup vs baseline: 1.0694x; 1.0131x over previous
//
#include <hip/hip_runtime.h>
#include <float.h>

typedef __bf16 bf16;
typedef __attribute__((ext_vector_type(8))) __bf16 bf16x8;
typedef __attribute__((ext_vector_type(4))) __bf16 bf16x4;
typedef __attribute__((ext_vector_type(4))) float f32x4;

__device__ __forceinline__ int imin(int a, int b) { return a < b ? a : b; }

// async global->LDS, 16B per lane; LDS dest = wave-uniform base + lane*16
__device__ __forceinline__ void gl2lds(const bf16* g, bf16* l) {
  __builtin_amdgcn_global_load_lds(
      (const __attribute__((address_space(1))) void*)g,
      (__attribute__((address_space(3))) void*)l, 16, 0, 0);
}

// ---------------- zero-page + padded lin weights (fused tiny prep) ----------------
__global__ void k_prep_misc(bf16* zp, const float* __restrict__ l1w,
                            const float* __restrict__ l2w,
                            bf16* __restrict__ L1p, bf16* __restrict__ L2p) {
  zp[threadIdx.x] = (bf16)0.0f;
  for (int i = threadIdx.x; i < 3456; i += 256) {
    int r = i / 72, c = i - r * 72;
    L1p[i] = (c < 48) ? (bf16)l1w[r * 48 + c] : (bf16)0.0f;
    L2p[i] = (c < 48) ? (bf16)l2w[r * 48 + c] : (bf16)0.0f;
  }
}

// ---------------- fused f32->bf16 casts (13 segments) ----------------
struct CastSegs { const float* s[13]; bf16* d[13]; int n[13]; };
__global__ void k_cast_all(CastSegs sg, int total) {
  int i = blockIdx.x * 256 + threadIdx.x;
  if (i >= total) return;
  for (int k = 0; k < 13; ++k) {
    if (i < sg.n[k]) { sg.d[k][i] = (bf16)sg.s[k][i]; return; }
    i -= sg.n[k];
  }
}

// ---------------- X_en|X_de (b,32,32,32) -> XR rows (96*1024, 32ch) bf16 ----------------
__global__ void k_prep_x(const float* __restrict__ XE, const float* __restrict__ XD,
                         bf16* __restrict__ XR) {
  int idx = blockIdx.x * 256 + threadIdx.x;
  if (idx >= 96 * 1024 * 32) return;
  int b = idx >> 15, r = idx & 32767, pos = r >> 5, ic = r & 31;
  const float* X = (b < 48) ? XE : XD;
  int bl = (b < 48) ? b : b - 48;
  XR[idx] = (bf16)X[((size_t)(bl * 32 + ic) << 10) + pos];
}

// ---------------- conv weight pack: (OC,IC,3,3) -> 9 x (OC,IC) bf16 ----------------
__global__ void k_pack_conv(const float* __restrict__ w, bf16* __restrict__ dst,
                            int OC, int IC, int total) {
  int idx = blockIdx.x * 256 + threadIdx.x;
  if (idx >= total) return;
  int t = idx / (OC * IC);
  int rem = idx - t * OC * IC;
  int oc = rem / IC, ic = rem - oc * IC;
  dst[idx] = (bf16)w[(size_t)(oc * IC + ic) * 9 + t];
}

// ---------------- 128x128 GEMM, BK=64, single-buffered, conflict-free LDS ----------
// LDS: A [128][64] at 0, B [128][64] at +8192 (128-B row pitch).
// Swizzle involution: seg' = seg ^ (row&7) (16-B segs, 8/row); gl2lds dest linear,
// SOURCE pre-swizzled, reads swizzled with the same XOR.
// If n0 >= nsplit: use A2/B2 with local n (merged dual-GEMM launch). K%64==0, N%128==0.
__global__ __launch_bounds__(256, 2) void k_gemm128(
    const bf16* __restrict__ A, const bf16* __restrict__ A2,
    const bf16* __restrict__ B, const bf16* __restrict__ B2, int nsplit,
    const float* __restrict__ bias, bf16* __restrict__ C,
    int M, int N, int K, int relu, int ldc, int coff) {
  __shared__ alignas(16) bf16 SM[16384];
  const int t = threadIdx.x, wave = t >> 6;
  const int lane = t & 63, fr = lane & 15, kq = lane >> 4;
  const int wm = wave & 1, wn = wave >> 1;
  const int m0 = blockIdx.x * 128, n0 = blockIdx.y * 128;
  const bf16* Ause = A; const bf16* Buse = B; int nloc = n0;
  if (n0 >= nsplit) { Ause = A2; Buse = B2; nloc = n0 - nsplit; }
  // staging map: thread t covers (row = r*32 + (t>>3), seg = t&7), r = 0..3 for A and B
  const int srow = t >> 3;
  const int sg8 = (((t & 7) ^ (srow & 7)) << 3);  // pre-swizzled source k-seg (elements)
  const bf16* gA[4]; const bf16* gB[4];
#pragma unroll
  for (int r = 0; r < 4; ++r) {
    gA[r] = Ause + (size_t)imin(m0 + r * 32 + srow, M - 1) * K + sg8;
    gB[r] = Buse + (size_t)(nloc + r * 32 + srow) * K + sg8;
  }
  // fragment-read offsets (elements); ^32 switches k-halves
  const int swz = (kq ^ (fr & 7)) << 3;
  const int aoff = (wm * 64 + fr) * 64 + swz;
  const int boff = 8192 + (wn * 64 + fr) * 64 + swz;
  f32x4 acc[4][4] = {};
  for (int k0 = 0; k0 < K; k0 += 64) {
    bf16* db = SM + wave * 512;
#pragma unroll
    for (int r = 0; r < 4; ++r) gl2lds(gA[r] + k0, db + r * 2048);
#pragma unroll
    for (int r = 0; r < 4; ++r) gl2lds(gB[r] + k0, db + 8192 + r * 2048);
    __syncthreads();
#pragma unroll
    for (int kk = 0; kk < 2; ++kk) {
      const int xo = kk << 5;
      bf16x8 af[4], bw[4];
#pragma unroll
      for (int mt = 0; mt < 4; ++mt)
        af[mt] = *(const bf16x8*)(SM + ((aoff + mt * 1024) ^ xo));
#pragma unroll
      for (int nt = 0; nt < 4; ++nt)
        bw[nt] = *(const bf16x8*)(SM + ((boff + nt * 1024) ^ xo));
#pragma unroll
      for (int mt = 0; mt < 4; ++mt)
#pragma unroll
        for (int nt = 0; nt < 4; ++nt)
          acc[mt][nt] = __builtin_amdgcn_mfma_f32_16x16x32_bf16(af[mt], bw[nt], acc[mt][nt], 0, 0, 0);
    }
    __syncthreads();
  }
  bf16* Cst = SM;  // 64 x 136 (padded pitch: conflict-free epilogue)
  for (int half = 0; half < 2; ++half) {
    if (wm == half) {
      for (int mt = 0; mt < 4; ++mt)
        for (int nt = 0; nt < 4; ++nt) {
          int n = n0 + wn * 64 + nt * 16 + fr;
          float bv = bias ? bias[n] : 0.0f;
          for (int r = 0; r < 4; ++r) {
            float v = acc[mt][nt][r] + bv;
            if (relu) v = fmaxf(v, 0.0f);
            Cst[(mt * 16 + kq * 4 + r) * 136 + wn * 64 + nt * 16 + fr] = (bf16)v;
          }
        }
    }
    __syncthreads();
    for (int i = t; i < 1024; i += 256) {
      int r = i >> 4, cs = i & 15;
      int gm = m0 + half * 64 + r;
      if (gm < M)
        *(bf16x8*)(C + (size_t)gm * ldc + coff + n0 + cs * 8) = *(const bf16x8*)(Cst + r * 136 + cs * 8);
    }
    __syncthreads();
  }
}

// ---------------- conv1 (BK=32): shifted 128x128 GEMM, merged 96 batches ----------------
template <int CIN, int PAD, int SRCW, int SRCROWS, int CHECK, int TRANS, int MTOT>
__global__ __launch_bounds__(256, 2) void k_conv128(
    const bf16* __restrict__ A, const bf16* __restrict__ Bp,
    const float* __restrict__ bias, bf16* __restrict__ C,
    const bf16* __restrict__ zpage) {
  __shared__ alignas(16) bf16 SM[8192];
  bf16* As = SM;
  bf16* Bs = SM + 4096;
  const int t = threadIdx.x, wave = t >> 6;
  const int lane = t & 63, fr = lane & 15, kq = lane >> 4;
  const int wm = wave & 1, wn = wave >> 1;
  const int m0 = blockIdx.x * 128, n0 = blockIdx.y * 128;
  const int srow = t >> 2, kseg = (t & 3) * 8;
  f32x4 acc[4][4] = {};
  int bb[2], yy[2], xx[2];
  for (int hf = 0; hf < 2; ++hf) {
    int m = imin(m0 + hf * 64 + srow, MTOT - 1);
    int b = m / 900, p = m - b * 900;
    bb[hf] = b; yy[hf] = p / 30; xx[hf] = p - (p / 30) * 30;
  }
  bf16* sA0 = As + wave * 512;
  bf16* sA1 = As + 2048 + wave * 512;
  bf16* sB0 = Bs + wave * 512;
  bf16* sB1 = Bs + 2048 + wave * 512;
  for (int k0 = 0; k0 < CIN; k0 += 32) {
    for (int t9 = 0; t9 < 9; ++t9) {
      const int ky = t9 / 3, kx = t9 - ky * 3;
      const bf16* ga[2];
      for (int hf = 0; hf < 2; ++hf) {
        int sy = yy[hf] + ky - PAD, sx = xx[hf] + kx - PAD;
        bool valid = !CHECK || (sy >= 0 && sy < SRCW && sx >= 0 && sx < SRCW);
        ga[hf] = (valid ? A + (size_t)(bb[hf] * SRCROWS + sy * SRCW + sx) * CIN : zpage) + kseg;
      }
      const bf16* gb = Bp + (size_t)(t9 * 256 + n0 + srow) * CIN + kseg;
      gl2lds(ga[0] + k0, sA0);
      gl2lds(ga[1] + k0, sA1);
      gl2lds(gb + k0, sB0);
      gl2lds(gb + (size_t)64 * CIN + k0, sB1);
      __syncthreads();
      bf16x8 af[4], bw[4];
      for (int mt = 0; mt < 4; ++mt)
        af[mt] = *(const bf16x8*)(As + (wm * 64 + mt * 16 + fr) * 32 + kq * 8);
      for (int nt = 0; nt < 4; ++nt)
        bw[nt] = *(const bf16x8*)(Bs + (wn * 64 + nt * 16 + fr) * 32 + kq * 8);
      for (int mt = 0; mt < 4; ++mt)
        for (int nt = 0; nt < 4; ++nt)
          acc[mt][nt] = __builtin_amdgcn_mfma_f32_16x16x32_bf16(af[mt], bw[nt], acc[mt][nt], 0, 0, 0);
      __syncthreads();
    }
  }
  bf16* Cst = SM;
  for (int half = 0; half < 2; ++half) {
    if (wm == half) {
      for (int mt = 0; mt < 4; ++mt)
        for (int nt = 0; nt < 4; ++nt) {
          int n = n0 + wn * 64 + nt * 16 + fr;
          float bv = bias[n];
          for (int r = 0; r < 4; ++r) {
            float v = acc[mt][nt][r] + bv;
            if (TRANS)
              Cst[(wn * 64 + nt * 16 + fr) * 64 + mt * 16 + kq * 4 + r] = (bf16)v;
            else
              Cst[(mt * 16 + kq * 4 + r) * 128 + wn * 64 + nt * 16 + fr] = (bf16)v;
          }
        }
    }
    __syncthreads();
    if (TRANS) {
      for (int i = t; i < 2048; i += 256) {
        int oc = i >> 4, pc = i & 15;
        int gm = m0 + half * 64 + pc * 4;
        if (gm < MTOT) {
          int b = gm / 900, p = gm - b * 900;
          *(bf16x4*)(C + (size_t)(b * 256 + n0 + oc) * 900 + p) = *(const bf16x4*)(Cst + oc * 64 + pc * 4);
        }
      }
    } else {
      for (int i = t; i < 1024; i += 256) {
        int r = i >> 4, cs = i & 15;
        int gm = m0 + half * 64 + r;
        if (gm < MTOT)
          *(bf16x8*)(C + (size_t)gm * 256 + n0 + cs * 8) = *(const bf16x8*)(Cst + r * 128 + cs * 8);
      }
    }
    __syncthreads();
  }
}

// ---------------- conv2 (CIN=256, pad=1): k0-outer/tap-inner (L2-tight), BK=64,
// single-buffered 32 KiB, conflict-free [128][64] swizzled LDS, merged 96 batches ----
__global__ __launch_bounds__(256, 2) void k_conv2x(
    const bf16* __restrict__ A, const bf16* __restrict__ Bp,
    const float* __restrict__ bias, bf16* __restrict__ C,
    const bf16* __restrict__ zpage) {
  __shared__ alignas(16) bf16 SM[16384];
  const int t = threadIdx.x, wave = t >> 6;
  const int lane = t & 63, fr = lane & 15, kq = lane >> 4;
  const int wm = wave & 1, wn = wave >> 1;
  const int m0 = blockIdx.x * 128, n0 = blockIdx.y * 128;
  const int srow = t >> 3;                            // staged row slot (0..31)
  const int sg8 = (((t & 7) ^ (srow & 7)) << 3);      // pre-swizzled source k-seg
  // decode the 4 A-rows this thread stages (positions, clamped)
  int pb[4], py[4], px[4];
#pragma unroll
  for (int r = 0; r < 4; ++r) {
    int m = imin(m0 + r * 32 + srow, 86399);
    int b = m / 900, p = m - b * 900;
    pb[r] = b * 900; py[r] = p / 30; px[r] = p - (p / 30) * 30;
  }
  const int swz = (kq ^ (fr & 7)) << 3;
  const int aoff = (wm * 64 + fr) * 64 + swz;
  const int boff = 8192 + (wn * 64 + fr) * 64 + swz;
  f32x4 acc[4][4] = {};
  for (int k0 = 0; k0 < 256; k0 += 64) {
    for (int t9 = 0; t9 < 9; ++t9) {
      const int ky = t9 / 3, kx = t9 - ky * 3;
      bf16* db = SM + wave * 512;
#pragma unroll
      for (int r = 0; r < 4; ++r) {
        int sy = py[r] + ky - 1, sx = px[r] + kx - 1;
        bool valid = (sy >= 0 && sy < 30 && sx >= 0 && sx < 30);
        const bf16* g = valid ? (A + (size_t)(pb[r] + sy * 30 + sx) * 256 + k0 + sg8)
                              : (zpage + sg8);
        gl2lds(g, db + r * 2048);
      }
#pragma unroll
      for (int r = 0; r < 4; ++r)
        gl2lds(Bp + (size_t)(t9 * 256 + n0 + r * 32 + srow) * 256 + k0 + sg8,
               db + 8192 + r * 2048);
      __syncthreads();
#pragma unroll
      for (int kk = 0; kk < 2; ++kk) {
        const int xo = kk << 5;
        bf16x8 af[4], bw[4];
#pragma unroll
        for (int mt = 0; mt < 4; ++mt)
          af[mt] = *(const bf16x8*)(SM + ((aoff + mt * 1024) ^ xo));
#pragma unroll
        for (int nt = 0; nt < 4; ++nt)
          bw[nt] = *(const bf16x8*)(SM + ((boff + nt * 1024) ^ xo));
#pragma unroll
        for (int mt = 0; mt < 4; ++mt)
#pragma unroll
          for (int nt = 0; nt < 4; ++nt)
            acc[mt][nt] = __builtin_amdgcn_mfma_f32_16x16x32_bf16(af[mt], bw[nt], acc[mt][nt], 0, 0, 0);
      }
      __syncthreads();
    }
  }
  bf16* Cst = SM;  // 128 oc x 68 (padded pitch: conflict-free epilogue)
  for (int half = 0; half < 2; ++half) {
    if (wm == half) {
      for (int mt = 0; mt < 4; ++mt)
        for (int nt = 0; nt < 4; ++nt) {
          int n = n0 + wn * 64 + nt * 16 + fr;
          float bv = bias[n];
          for (int r = 0; r < 4; ++r) {
            float v = acc[mt][nt][r] + bv;
            Cst[(wn * 64 + nt * 16 + fr) * 68 + mt * 16 + kq * 4 + r] = (bf16)v;
          }
        }
    }
    __syncthreads();
    for (int i = t; i < 2048; i += 256) {
      int oc = i >> 4, pc = i & 15;
      int gm = m0 + half * 64 + pc * 4;
      int b = gm / 900, p = gm - b * 900;
      *(bf16x4*)(C + (size_t)(b * 256 + n0 + oc) * 900 + p) = *(const bf16x4*)(Cst + oc * 68 + pc * 4);
    }
    __syncthreads();
  }
}

// ---------------- attention logits z for one (s,h); rel transposed in-prologue ----
template <int MASKED>
__global__ __launch_bounds__(256, MASKED ? 4 : 5) void k_attn_z(
    const bf16* __restrict__ QKV, const float* __restrict__ Rel, bf16* __restrict__ Z,
    const bf16* __restrict__ L1p, const bf16* __restrict__ L2p,
    const float* __restrict__ l1b, const float* __restrict__ l2b) {
  __shared__ alignas(16) bf16 QKs[2][48 * 40];
  __shared__ alignas(16) bf16 RelS[48 * 32];
  __shared__ float EMD[48 * 49];
  __shared__ alignas(16) bf16 zst[48 * 48];
  __shared__ alignas(16) bf16 Sc[MASKED ? 48 * 72 : 8];
  __shared__ alignas(16) bf16 T2b[MASKED ? 48 * 72 : 8];
  const int sh = blockIdx.x, s = sh >> 3, h = sh & 7;
  const int t = threadIdx.x, wave = t >> 6, lane = t & 63, fr = lane & 15, kq = lane >> 4;
  const float scale = 0.17677669529663687f;  // 1/sqrt(32)
  for (int c = t; c < 384; c += 256) {
    int half = c >= 192 ? 1 : 0, cc = c - half * 192;
    int row = cc >> 2, seg = cc & 3;
    *(bf16x8*)(&QKs[half][row * 40 + seg * 8]) =
        *(const bf16x8*)(QKV + (size_t)(s * 48 + row) * 768 + half * 256 + h * 32 + seg * 8);
  }
  // rel slice (k*48+j) f32 -> RelS (j*32+k) bf16 (was k_prep_rel; coalesced f32 reads)
  {
    const float* relsrc = Rel + (size_t)sh * 1536;
    for (int i = t; i < 1536; i += 256) {
      int k = i / 48, j = i - k * 48;
      RelS[j * 32 + k] = (bf16)relsrc[i];
    }
  }
  if constexpr (MASKED) {
    for (int i = t; i < 768; i += 256) {
      int r = i >> 4, c = 48 + (i & 15);
      Sc[r * 72 + c] = (bf16)0.0f;
      T2b[r * 72 + c] = (bf16)0.0f;
    }
  }
  __syncthreads();
  f32x4 sreg[3];
  int u = 0;
  for (int t9 = wave; t9 < 9; t9 += 4, ++u) {
    int ti = t9 / 3, tj = t9 - ti * 3;
    bf16x8 af = *(const bf16x8*)(&QKs[0][(ti * 16 + fr) * 40 + kq * 8]);
    bf16x8 bk = *(const bf16x8*)(&QKs[1][(tj * 16 + fr) * 40 + kq * 8]);
    bf16x8 rf = *(const bf16x8*)(RelS + (tj * 16 + fr) * 32 + kq * 8);
    f32x4 sacc = {}, eacc = {};
    sacc = __builtin_amdgcn_mfma_f32_16x16x32_bf16(af, bk, sacc, 0, 0, 0);
    eacc = __builtin_amdgcn_mfma_f32_16x16x32_bf16(af, rf, eacc, 0, 0, 0);
    for (int r = 0; r < 4; ++r)
      EMD[(ti * 16 + kq * 4 + r) * 49 + tj * 16 + fr] = eacc[r];
    if constexpr (MASKED) {
      for (int r = 0; r < 4; ++r)
        Sc[(ti * 16 + kq * 4 + r) * 72 + tj * 16 + fr] = (bf16)(sacc[r] * scale);
    } else {
      for (int r = 0; r < 4; ++r) sreg[u][r] = sacc[r] * scale;
    }
  }
  __syncthreads();
  if constexpr (!MASKED) {
    u = 0;
    for (int t9 = wave; t9 < 9; t9 += 4, ++u) {
      int ti = t9 / 3, tj = t9 - ti * 3;
      for (int r = 0; r < 4; ++r) {
        int i = ti * 16 + kq * 4 + r, j = tj * 16 + fr;
        float v = sreg[u][r];
        if (j <= i) v += EMD[i * 49 + 47 + j - i];
        zst[i * 48 + j] = (bf16)v;
      }
    }
  } else {
    for (int t9 = wave; t9 < 9; t9 += 4) {
      int ti = t9 / 3, tj = t9 - ti * 3;
      f32x4 a2 = {};
      for (int k0 = 0; k0 < 64; k0 += 32) {
        bf16x8 af = *(const bf16x8*)(Sc + (ti * 16 + fr) * 72 + k0 + kq * 8);
        bf16x8 bw = *(const bf16x8*)(L1p + (tj * 16 + fr) * 72 + k0 + kq * 8);
        a2 = __builtin_amdgcn_mfma_f32_16x16x32_bf16(af, bw, a2, 0, 0, 0);
      }
      for (int r = 0; r < 4; ++r) {
        int i = ti * 16 + kq * 4 + r, a = tj * 16 + fr;
        T2b[a * 72 + i] = (bf16)(a2[r] + l1b[a]);
      }
    }
    __syncthreads();
    for (int t9 = wave; t9 < 9; t9 += 4) {
      int ti = t9 / 3, tj = t9 - ti * 3;
      f32x4 a2 = {};
      for (int k0 = 0; k0 < 64; k0 += 32) {
        bf16x8 af = *(const bf16x8*)(T2b + (ti * 16 + fr) * 72 + k0 + kq * 8);
        bf16x8 bw = *(const bf16x8*)(L2p + (tj * 16 + fr) * 72 + k0 + kq * 8);
        a2 = __builtin_amdgcn_mfma_f32_16x16x32_bf16(af, bw, a2, 0, 0, 0);
      }
      for (int r = 0; r < 4; ++r) {
        int aa = ti * 16 + kq * 4 + r, cc = tj * 16 + fr;
        float v;
        if (cc > aa) v = -10000.0f;  // masked column -> exactly uniform after softmax
        else v = a2[r] + l2b[cc] + EMD[aa * 49 + 47 + cc - aa];
        zst[aa * 48 + cc] = (bf16)v;
      }
    }
  }
  __syncthreads();
  bf16* zb = Z + (size_t)sh * 2304;
  for (int c = t; c < 288; c += 256)
    *(bf16x8*)(zb + c * 8) = *(const bf16x8*)(zst + c * 8);
}

// ---------------- per-column (over s=900) online max & inverse-sum ----------------
// grid 288: 64 cols/block (8 thr x 8 cols, bf16x8) x 32 s-groups of 29
__global__ __launch_bounds__(256) void k_colstats(const bf16* __restrict__ Z,
                                                  float* __restrict__ Mc, float* __restrict__ Ic) {
  __shared__ float rm[32][72], rs[32][72];
  const int t = threadIdx.x, cg = t & 7, sg = t >> 3;
  const bf16* p = Z + blockIdx.x * 64 + cg * 8;
  const int s0 = sg * 29, s1 = imin(900, s0 + 29);
  float m[8], ss[8];
  for (int e = 0; e < 8; ++e) { m[e] = -FLT_MAX; ss[e] = 0.0f; }
  for (int s = s0; s < s1; ++s) {
    bf16x8 zv = *(const bf16x8*)(p + (size_t)s * 18432);
    for (int e = 0; e < 8; ++e) {
      float v = (float)zv[e];
      if (v > m[e]) { ss[e] *= __expf(m[e] - v); m[e] = v; }
      ss[e] += __expf(v - m[e]);
    }
  }
  for (int e = 0; e < 8; ++e) { rm[sg][cg * 8 + e] = m[e]; rs[sg][cg * 8 + e] = ss[e]; }
  __syncthreads();
  if (t < 64) {
    float M2 = -FLT_MAX;
    for (int g = 0; g < 32; ++g) M2 = fmaxf(M2, rm[g][t]);
    float S2 = 0.0f;
    for (int g = 0; g < 32; ++g) S2 += rs[g][t] * __expf(rm[g][t] - M2);
    Mc[blockIdx.x * 64 + t] = M2;
    Ic[blockIdx.x * 64 + t] = 1.0f / S2;
  }
}

// ---------------- O = LN(RES + softmax(Z) V) for one (s,h); writes 6 rows of 256 ----
// attn output for block sh is 1536 contiguous elements = flat rows [6*sh, 6*sh+6) of
// the (b, sl, 256) view; each row is fully block-local, so add+LN fuses here.
__global__ __launch_bounds__(256, 6) void k_attn_av(
    const bf16* __restrict__ Z, const bf16* __restrict__ QKV,
    const float* __restrict__ Mc, const float* __restrict__ Ic,
    const bf16* __restrict__ RES, bf16* __restrict__ O) {
  __shared__ alignas(16) bf16 Ps[48 * 72];
  __shared__ alignas(16) bf16 Vt[32 * 72];
  __shared__ alignas(16) bf16 Ost[48 * 32];
  const int sh = blockIdx.x, s = sh >> 3, h = sh & 7;
  const int t = threadIdx.x, wave = t >> 6, lane = t & 63, fr = lane & 15, kq = lane >> 4;
  for (int i = t; i < 768; i += 256) Ps[(i >> 4) * 72 + 48 + (i & 15)] = (bf16)0.0f;
  for (int i = t; i < 512; i += 256) Vt[(i >> 4) * 72 + 48 + (i & 15)] = (bf16)0.0f;
  const bf16* zb = Z + (size_t)sh * 2304;
  const float* mc = Mc + h * 2304;
  const float* ic = Ic + h * 2304;
  for (int c = t; c < 288; c += 256) {
    int r = c / 6, seg = c - r * 6;
    int idx = r * 48 + seg * 8;
    bf16x8 zv = *(const bf16x8*)(zb + idx);
    f32x4 m0v = *(const f32x4*)(mc + idx), m1v = *(const f32x4*)(mc + idx + 4);
    f32x4 i0v = *(const f32x4*)(ic + idx), i1v = *(const f32x4*)(ic + idx + 4);
    bf16x8 pv;
    for (int e = 0; e < 4; ++e) pv[e] = (bf16)(__expf((float)zv[e] - m0v[e]) * i0v[e]);
    for (int e = 0; e < 4; ++e) pv[4 + e] = (bf16)(__expf((float)zv[4 + e] - m1v[e]) * i1v[e]);
    *(bf16x8*)(Ps + r * 72 + seg * 8) = pv;
  }
  for (int c = t; c < 192; c += 256) {
    int j = c >> 2, seg = c & 3;
    bf16x8 v = *(const bf16x8*)(QKV + (size_t)(s * 48 + j) * 768 + 512 + h * 32 + seg * 8);
    for (int e = 0; e < 8; ++e) Vt[(seg * 8 + e) * 72 + j] = v[e];
  }
  __syncthreads();
  for (int t6 = wave; t6 < 6; t6 += 4) {
    int ti = t6 >> 1, td = t6 & 1;
    f32x4 a2 = {};
    for (int k0 = 0; k0 < 64; k0 += 32) {
      bf16x8 af = *(const bf16x8*)(Ps + (ti * 16 + fr) * 72 + k0 + kq * 8);
      bf16x8 bv = *(const bf16x8*)(Vt + (td * 16 + fr) * 72 + k0 + kq * 8);
      a2 = __builtin_amdgcn_mfma_f32_16x16x32_bf16(af, bv, a2, 0, 0, 0);
    }
    for (int r = 0; r < 4; ++r)
      Ost[(ti * 16 + kq * 4 + r) * 32 + td * 16 + fr] = (bf16)a2[r];
  }
  __syncthreads();
  // fused add + LayerNorm: 6 rows of 256, 1 row per wave (2 rounds) — k_add_ln math
  const size_t base = (size_t)sh * 1536;
  for (int r = wave; r < 6; r += 4) {
    const size_t off = base + r * 256 + lane * 4;
    bf16x4 av = *(const bf16x4*)(Ost + r * 256 + lane * 4);
    bf16x4 bv = *(const bf16x4*)(RES + off);
    f32x4 x;
    for (int c = 0; c < 4; ++c) x[c] = (float)av[c] + (float)bv[c];
    float sum = x[0] + x[1] + x[2] + x[3];
    for (int o = 1; o < 64; o <<= 1) sum += __shfl_xor(sum, o);
    float mean = sum * (1.0f / 256.0f);
    float q = 0.0f;
    for (int c = 0; c < 4; ++c) { float d = x[c] - mean; q += d * d; }
    for (int o = 1; o < 64; o <<= 1) q += __shfl_xor(q, o);
    float rstd = rsqrtf(q * (1.0f / 256.0f) + 1e-5f);
    bf16x4 y;
    for (int c = 0; c < 4; ++c) y[c] = (bf16)((x[c] - mean) * rstd);
    *(bf16x4*)(O + off) = y;
  }
}

// ---------------- out = LN(Xa + Xb), rows of 256, bf16 ----------------
__global__ __launch_bounds__(256) void k_add_ln(
    const bf16* __restrict__ Xa, const bf16* __restrict__ Xb, bf16* __restrict__ out) {
  const int t = threadIdx.x, lane = t & 63, w = t >> 6;
  const size_t off = ((size_t)blockIdx.x * 4 + w) * 256 + lane * 4;
  bf16x4 av = *(const bf16x4*)(Xa + off);
  bf16x4 bv = *(const bf16x4*)(Xb + off);
  f32x4 x;
  for (int c = 0; c < 4; ++c) x[c] = (float)av[c] + (float)bv[c];
  float sum = x[0] + x[1] + x[2] + x[3];
  for (int o = 1; o < 64; o <<= 1) sum += __shfl_xor(sum, o);
  float mean = sum * (1.0f / 256.0f);
  float q = 0.0f;
  for (int c = 0; c < 4; ++c) { float d = x[c] - mean; q += d * d; }
  for (int o = 1; o < 64; o <<= 1) q += __shfl_xor(q, o);
  float rstd = rsqrtf(q * (1.0f / 256.0f) + 1e-5f);
  bf16x4 y;
  for (int c = 0; c < 4; ++c) y[c] = (bf16)((x[c] - mean) * rstd);
  *(bf16x4*)(out + off) = y;
}

// ---------------- Y[row] = dot(LN(Xa+Xb)[row], w) + b  (h3 never materialized) ----
__global__ __launch_bounds__(256) void k_add_ln_ydot(
    const bf16* __restrict__ Xa, const bf16* __restrict__ Xb,
    const float* __restrict__ w, const float* __restrict__ b,
    float* __restrict__ Y) {
  const int t = threadIdx.x, lane = t & 63, wv = t >> 6;
  const size_t row = (size_t)blockIdx.x * 4 + wv;
  const size_t off = row * 256 + lane * 4;
  bf16x4 av = *(const bf16x4*)(Xa + off);
  bf16x4 bv = *(const bf16x4*)(Xb + off);
  f32x4 x;
  for (int c = 0; c < 4; ++c) x[c] = (float)av[c] + (float)bv[c];
  float sum = x[0] + x[1] + x[2] + x[3];
  for (int o = 1; o < 64; o <<= 1) sum += __shfl_xor(sum, o);
  float mean = sum * (1.0f / 256.0f);
  float q = 0.0f;
  for (int c = 0; c < 4; ++c) { float d = x[c] - mean; q += d * d; }
  for (int o = 1; o < 64; o <<= 1) q += __shfl_xor(q, o);
  float rstd = rsqrtf(q * (1.0f / 256.0f) + 1e-5f);
  f32x4 ww = *(const f32x4*)(w + lane * 4);
  float yv = 0.0f;
  for (int c = 0; c < 4; ++c) yv += (x[c] - mean) * rstd * ww[c];
  for (int o = 1; o < 64; o <<= 1) yv += __shfl_xor(yv, o);
  if (lane == 0) Y[row] = yv + b[0];
}

// ---------------- softmax over b (48) per column ----------------
__global__ void k_softmax48(const float* __restrict__ Y, float* __restrict__ O) {
  int ss = blockIdx.x * 256 + threadIdx.x;
  if (ss >= 900) return;
  float m = -FLT_MAX;
  for (int b = 0; b < 48; ++b) m = fmaxf(m, Y[b * 900 + ss]);
  float sum = 0.0f;
  for (int b = 0; b < 48; ++b) sum += __expf(Y[b * 900 + ss] - m);
  float inv = 1.0f / sum;
  for (int b = 0; b < 48; ++b) O[b * 900 + ss] = __expf(Y[b * 900 + ss] - m) * inv;
}

extern "C" void kernel_launch(void* const* d_in, const int* in_sizes, int n_in,
                              void* d_out, int out_size, void* d_ws, size_t ws_size,
                              hipStream_t stream) {
  (void)in_sizes; (void)n_in; (void)out_size;
  const float* X_en = (const float*)d_in[0];
  const float* X_de = (const float*)d_in[1];
  const float* conv1_w = (const float*)d_in[2];
  const float* conv1_b = (const float*)d_in[3];
  const float* conv2_w = (const float*)d_in[4];
  const float* conv2_b = (const float*)d_in[5];
  const float* enc_wq = (const float*)d_in[6];
  const float* enc_wk = (const float*)d_in[7];
  const float* enc_wv = (const float*)d_in[8];
  const float* enc_rel = (const float*)d_in[9];
  const float* enc_f1w = (const float*)d_in[10];
  const float* enc_f1b = (const float*)d_in[11];
  const float* enc_f2w = (const float*)d_in[12];
  const float* enc_f2b = (const float*)d_in[13];
  const float* dm_wq = (const float*)d_in[14];
  const float* dm_wk = (const float*)d_in[15];
  const float* dm_wv = (const float*)d_in[16];
  const float* dm_rel = (const float*)d_in[17];
  const float* dm_l1w = (const float*)d_in[18];
  const float* dm_l1b = (const float*)d_in[19];
  const float* dm_l2w = (const float*)d_in[20];
  const float* dm_l2b = (const float*)d_in[21];
  const float* dc_wq = (const float*)d_in[22];
  const float* dc_wk = (const float*)d_in[23];
  const float* dc_wv = (const float*)d_in[24];
  const float* dc_rel = (const float*)d_in[25];
  const float* d_f1w = (const float*)d_in[26];
  const float* d_f1b = (const float*)d_in[27];
  const float* d_f2w = (const float*)d_in[28];
  const float* d_f2b = (const float*)d_in[29];
  const float* out_w = (const float*)d_in[30];
  const float* out_b = (const float*)d_in[31];
  float* OUT = (float*)d_out;

  // ---- workspace layout ----
  const size_t SLOT = 22118400;  // 43200*256 bf16
  char* ws = (char*)d_ws;
  size_t o = 0;
  bf16* S1 = (bf16*)(ws + o); o += SLOT;  // XEb -> ENCb
  bf16* S2 = (bf16*)(ws + o); o += SLOT;  // XDb -> (cross stats)
  bf16* S3 = (bf16*)(ws + o); o += SLOT;  // o1 -> (dm stats) -> h2
  bf16* S4 = (bf16*)(ws + o); o += SLOT;  // (enc stats) -> h1
  bf16* S5 = (bf16*)(ws + o); o += SLOT;  // ffn-out
  char* U = ws + o; o += 33177600 + 3 * SLOT;  // Z + QKV, union { HID, XR+C1R }
  bf16* Zb = (bf16*)U;
  bf16* QKV = (bf16*)(U + 33177600);
  bf16* XR = (bf16*)U;                    // conv phase: 96*1024*32 bf16 = 12.6 MB
  bf16* C1R = (bf16*)(U + 12582912);      // conv phase: 96*900*256 bf16 = 44.2 MB
  bf16* HID = (bf16*)U;                   // FFN phase only
  bf16* wa = (bf16*)(ws + o); o += 4603904 + 16384;
  float* Y = (float*)(ws + o); o += 172800;
  if (ws_size < o) return;

  bf16* zpage = (bf16*)Y;  // 512 B zero page; Y dead until k_add_ln_ydot
  float* encM = (float*)S4; float* encI = encM + 18432;
  float* dmM  = (float*)S3; float* dmI  = dmM + 18432;
  float* crM  = (float*)S2; float* crI  = crM + 18432;

  // weight arena (element offsets)
  bf16* c1p = wa;
  bf16* c2p = wa + 73728;
  bf16* EQKVw = wa + 663552;
  bf16* MQKVw = wa + 860160;
  bf16* cqw = wa + 1056768;
  bf16* CKVw = wa + 1122304;
  bf16* ef1 = wa + 1253376;
  bf16* ef2 = wa + 1515520;
  bf16* df1 = wa + 1777664;
  bf16* df2 = wa + 2039808;
  bf16* L1p = wa + 2301952;
  bf16* L2p = wa + 2305408;

  auto gemm = [&](const bf16* A, const bf16* B, const float* bias, bf16* C,
                  int M, int N, int K, int relu, int ldc, int coff) {
    k_gemm128<<<dim3((M + 127) / 128, N / 128), dim3(256), 0, stream>>>(
        A, A, B, B, N, bias, C, M, N, K, relu, ldc, coff);
  };

  // ---- weight prep ----
  k_prep_misc<<<dim3(1), dim3(256), 0, stream>>>(zpage, dm_l1w, dm_l2w, L1p, L2p);
  k_pack_conv<<<dim3(288), dim3(256), 0, stream>>>(conv1_w, c1p, 256, 32, 73728);
  k_pack_conv<<<dim3(2304), dim3(256), 0, stream>>>(conv2_w, c2p, 256, 256, 589824);
  {
    CastSegs sg;
    const float* srcs[13] = {enc_wq, enc_wk, enc_wv, dm_wq, dm_wk, dm_wv, dc_wq,
                             dc_wk, dc_wv, enc_f1w, enc_f2w, d_f1w, d_f2w};
    bf16* dsts[13] = {EQKVw, EQKVw + 65536, EQKVw + 131072, MQKVw, MQKVw + 65536,
                      MQKVw + 131072, cqw, CKVw, CKVw + 65536, ef1, ef2, df1, df2};
    int ns[13] = {65536, 65536, 65536, 65536, 65536, 65536, 65536, 65536, 65536,
                  262144, 262144, 262144, 262144};
    int total = 0;
    for (int k = 0; k < 13; ++k) { sg.s[k] = srcs[k]; sg.d[k] = dsts[k]; sg.n[k] = ns[k]; total += ns[k]; }
    k_cast_all<<<dim3((total + 255) / 256), dim3(256), 0, stream>>>(sg, total);
  }

  // ---- merged conv chain (96 batches: en then de; conv2 writes S1||S2 contiguously) ----
  k_prep_x<<<dim3(12288), dim3(256), 0, stream>>>(X_en, X_de, XR);
  k_conv128<32, 0, 32, 1024, 0, 0, 86400><<<dim3(675, 2), dim3(256), 0, stream>>>(
      XR, c1p, conv1_b, C1R, zpage);
  k_conv2x<<<dim3(675, 2), dim3(256), 0, stream>>>(C1R, c2p, conv2_b, S1, zpage);

  // ---- encoder ----
  gemm(S1, EQKVw, nullptr, QKV, 43200, 768, 256, 0, 768, 0);
  k_attn_z<0><<<dim3(7200), dim3(256), 0, stream>>>(QKV, enc_rel, Zb, nullptr, nullptr, nullptr, nullptr);
  k_colstats<<<dim3(288), dim3(256), 0, stream>>>(Zb, encM, encI);
  k_attn_av<<<dim3(7200), dim3(256), 0, stream>>>(Zb, QKV, encM, encI, S1, S3);  // o1 = LN(S1+attn)
  gemm(S3, ef1, enc_f1b, HID, 43200, 1024, 256, 1, 1024, 0);
  gemm(HID, ef2, enc_f2b, S5, 43200, 256, 1024, 0, 256, 0);
  k_add_ln<<<dim3(10800), dim3(256), 0, stream>>>(S3, S5, S1);  // enc_out

  // ---- decoder masked self-attention ----
  gemm(S2, MQKVw, nullptr, QKV, 43200, 768, 256, 0, 768, 0);
  k_attn_z<1><<<dim3(7200), dim3(256), 0, stream>>>(QKV, dm_rel, Zb, L1p, L2p, dm_l1b, dm_l2b);
  k_colstats<<<dim3(288), dim3(256), 0, stream>>>(Zb, dmM, dmI);
  k_attn_av<<<dim3(7200), dim3(256), 0, stream>>>(Zb, QKV, dmM, dmI, S2, S4);  // h1 = LN(S2+attn)

  // ---- cross attention (q + kv merged into one dual-GEMM launch) ----
  k_gemm128<<<dim3(338, 6), dim3(256), 0, stream>>>(
      S4, S1, cqw, CKVw, 256, nullptr, QKV, 43200, 768, 256, 0, 768, 0);
  k_attn_z<0><<<dim3(7200), dim3(256), 0, stream>>>(QKV, dc_rel, Zb, nullptr, nullptr, nullptr, nullptr);
  k_colstats<<<dim3(288), dim3(256), 0, stream>>>(Zb, crM, crI);
  k_attn_av<<<dim3(7200), dim3(256), 0, stream>>>(Zb, QKV, crM, crI, S4, S3);  // h2 = LN(h1+attn)

  // ---- decoder FFN + head (h3 fused away: Y = dot(LN(h2 + FFN2), out_w) + out_b) ----
  gemm(S3, df1, d_f1b, HID, 43200, 1024, 256, 1, 1024, 0);
  gemm(HID, df2, d_f2b, S5, 43200, 256, 1024, 0, 256, 0);
  k_add_ln_ydot<<<dim3(10800), dim3(256), 0, stream>>>(S3, S5, out_w, out_b, Y);
  k_softmax48<<<dim3(4), dim3(256), 0, stream>>>(Y, OUT);
}

// Round 11
// 932.898 us; speedup vs baseline: 1.1011x; 1.0297x over previous
//
#include <hip/hip_runtime.h>
#include <float.h>

typedef __bf16 bf16;
typedef __attribute__((ext_vector_type(8))) __bf16 bf16x8;
typedef __attribute__((ext_vector_type(4))) __bf16 bf16x4;
typedef __attribute__((ext_vector_type(4))) float f32x4;

__device__ __forceinline__ int imin(int a, int b) { return a < b ? a : b; }

// async global->LDS, 16B per lane; LDS dest = wave-uniform base + lane*16
__device__ __forceinline__ void gl2lds(const bf16* g, bf16* l) {
  __builtin_amdgcn_global_load_lds(
      (const __attribute__((address_space(1))) void*)g,
      (__attribute__((address_space(3))) void*)l, 16, 0, 0);
}

// ---------------- zero-page + padded lin weights (fused tiny prep) ----------------
__global__ void k_prep_misc(bf16* zp, const float* __restrict__ l1w,
                            const float* __restrict__ l2w,
                            bf16* __restrict__ L1p, bf16* __restrict__ L2p) {
  zp[threadIdx.x] = (bf16)0.0f;
  for (int i = threadIdx.x; i < 3456; i += 256) {
    int r = i / 72, c = i - r * 72;
    L1p[i] = (c < 48) ? (bf16)l1w[r * 48 + c] : (bf16)0.0f;
    L2p[i] = (c < 48) ? (bf16)l2w[r * 48 + c] : (bf16)0.0f;
  }
}

// ---------------- fused f32->bf16 casts (13 segments) ----------------
struct CastSegs { const float* s[13]; bf16* d[13]; int n[13]; };
__global__ void k_cast_all(CastSegs sg, int total) {
  int i = blockIdx.x * 256 + threadIdx.x;
  if (i >= total) return;
  for (int k = 0; k < 13; ++k) {
    if (i < sg.n[k]) { sg.d[k][i] = (bf16)sg.s[k][i]; return; }
    i -= sg.n[k];
  }
}

// ---------------- X_en|X_de (b,32,32,32) -> XR rows (96*1024, 32ch) bf16 ----------------
__global__ void k_prep_x(const float* __restrict__ XE, const float* __restrict__ XD,
                         bf16* __restrict__ XR) {
  int idx = blockIdx.x * 256 + threadIdx.x;
  if (idx >= 96 * 1024 * 32) return;
  int b = idx >> 15, r = idx & 32767, pos = r >> 5, ic = r & 31;
  const float* X = (b < 48) ? XE : XD;
  int bl = (b < 48) ? b : b - 48;
  XR[idx] = (bf16)X[((size_t)(bl * 32 + ic) << 10) + pos];
}

// ---------------- conv weight pack: (OC,IC,3,3) -> 9 x (OC,IC) bf16 ----------------
__global__ void k_pack_conv(const float* __restrict__ w, bf16* __restrict__ dst,
                            int OC, int IC, int total) {
  int idx = blockIdx.x * 256 + threadIdx.x;
  if (idx >= total) return;
  int t = idx / (OC * IC);
  int rem = idx - t * OC * IC;
  int oc = rem / IC, ic = rem - oc * IC;
  dst[idx] = (bf16)w[(size_t)(oc * IC + ic) * 9 + t];
}

// ---------------- 128x128 GEMM, BK=64, single-buffered, conflict-free LDS ----------
// LDS: A [128][64] at 0, B [128][64] at +8192 (128-B row pitch).
// Swizzle involution: seg' = seg ^ (row&7) (16-B segs, 8/row); gl2lds dest linear,
// SOURCE pre-swizzled, reads swizzled with the same XOR.
// If n0 >= nsplit: use A2/B2 with local n (merged dual-GEMM launch). K%64==0, N%128==0.
__global__ __launch_bounds__(256, 2) void k_gemm128(
    const bf16* __restrict__ A, const bf16* __restrict__ A2,
    const bf16* __restrict__ B, const bf16* __restrict__ B2, int nsplit,
    const float* __restrict__ bias, bf16* __restrict__ C,
    int M, int N, int K, int relu, int ldc, int coff) {
  __shared__ alignas(16) bf16 SM[16384];
  const int t = threadIdx.x, wave = t >> 6;
  const int lane = t & 63, fr = lane & 15, kq = lane >> 4;
  const int wm = wave & 1, wn = wave >> 1;
  const int m0 = blockIdx.x * 128, n0 = blockIdx.y * 128;
  const bf16* Ause = A; const bf16* Buse = B; int nloc = n0;
  if (n0 >= nsplit) { Ause = A2; Buse = B2; nloc = n0 - nsplit; }
  // staging map: thread t covers (row = r*32 + (t>>3), seg = t&7), r = 0..3 for A and B
  const int srow = t >> 3;
  const int sg8 = (((t & 7) ^ (srow & 7)) << 3);  // pre-swizzled source k-seg (elements)
  const bf16* gA[4]; const bf16* gB[4];
#pragma unroll
  for (int r = 0; r < 4; ++r) {
    gA[r] = Ause + (size_t)imin(m0 + r * 32 + srow, M - 1) * K + sg8;
    gB[r] = Buse + (size_t)(nloc + r * 32 + srow) * K + sg8;
  }
  // fragment-read offsets (elements); ^32 switches k-halves
  const int swz = (kq ^ (fr & 7)) << 3;
  const int aoff = (wm * 64 + fr) * 64 + swz;
  const int boff = 8192 + (wn * 64 + fr) * 64 + swz;
  f32x4 acc[4][4] = {};
  for (int k0 = 0; k0 < K; k0 += 64) {
    bf16* db = SM + wave * 512;
#pragma unroll
    for (int r = 0; r < 4; ++r) gl2lds(gA[r] + k0, db + r * 2048);
#pragma unroll
    for (int r = 0; r < 4; ++r) gl2lds(gB[r] + k0, db + 8192 + r * 2048);
    __syncthreads();
#pragma unroll
    for (int kk = 0; kk < 2; ++kk) {
      const int xo = kk << 5;
      bf16x8 af[4], bw[4];
#pragma unroll
      for (int mt = 0; mt < 4; ++mt)
        af[mt] = *(const bf16x8*)(SM + ((aoff + mt * 1024) ^ xo));
#pragma unroll
      for (int nt = 0; nt < 4; ++nt)
        bw[nt] = *(const bf16x8*)(SM + ((boff + nt * 1024) ^ xo));
#pragma unroll
      for (int mt = 0; mt < 4; ++mt)
#pragma unroll
        for (int nt = 0; nt < 4; ++nt)
          acc[mt][nt] = __builtin_amdgcn_mfma_f32_16x16x32_bf16(af[mt], bw[nt], acc[mt][nt], 0, 0, 0);
    }
    __syncthreads();
  }
  bf16* Cst = SM;  // 64 x 136 (padded pitch: conflict-free epilogue)
  for (int half = 0; half < 2; ++half) {
    if (wm == half) {
      for (int mt = 0; mt < 4; ++mt)
        for (int nt = 0; nt < 4; ++nt) {
          int n = n0 + wn * 64 + nt * 16 + fr;
          float bv = bias ? bias[n] : 0.0f;
          for (int r = 0; r < 4; ++r) {
            float v = acc[mt][nt][r] + bv;
            if (relu) v = fmaxf(v, 0.0f);
            Cst[(mt * 16 + kq * 4 + r) * 136 + wn * 64 + nt * 16 + fr] = (bf16)v;
          }
        }
    }
    __syncthreads();
    for (int i = t; i < 1024; i += 256) {
      int r = i >> 4, cs = i & 15;
      int gm = m0 + half * 64 + r;
      if (gm < M)
        *(bf16x8*)(C + (size_t)gm * ldc + coff + n0 + cs * 8) = *(const bf16x8*)(Cst + r * 136 + cs * 8);
    }
    __syncthreads();
  }
}

// ---------------- conv1 (BK=32): shifted 128x128 GEMM, merged 96 batches,
// conflict-free 4-seg swizzle: seg' = seg ^ (row&3); source pre-swizzled,
// linear gl2lds dest, read XOR kq ^ (fr&3) (same involution family as gemm128) ------
template <int CIN, int PAD, int SRCW, int SRCROWS, int CHECK, int TRANS, int MTOT>
__global__ __launch_bounds__(256, 2) void k_conv128(
    const bf16* __restrict__ A, const bf16* __restrict__ Bp,
    const float* __restrict__ bias, bf16* __restrict__ C,
    const bf16* __restrict__ zpage) {
  __shared__ alignas(16) bf16 SM[8192];
  bf16* As = SM;
  bf16* Bs = SM + 4096;
  const int t = threadIdx.x, wave = t >> 6;
  const int lane = t & 63, fr = lane & 15, kq = lane >> 4;
  const int wm = wave & 1, wn = wave >> 1;
  const int m0 = blockIdx.x * 128, n0 = blockIdx.y * 128;
  const int srow = t >> 2;
  const int sg4 = (((t & 3) ^ (srow & 3)) << 3);  // pre-swizzled source k-seg
  f32x4 acc[4][4] = {};
  int bb[2], yy[2], xx[2];
  for (int hf = 0; hf < 2; ++hf) {
    int m = imin(m0 + hf * 64 + srow, MTOT - 1);
    int b = m / 900, p = m - b * 900;
    bb[hf] = b; yy[hf] = p / 30; xx[hf] = p - (p / 30) * 30;
  }
  bf16* sA0 = As + wave * 512;
  bf16* sA1 = As + 2048 + wave * 512;
  bf16* sB0 = Bs + wave * 512;
  bf16* sB1 = Bs + 2048 + wave * 512;
  const int swz4 = (kq ^ (fr & 3)) << 3;  // fragment-read swizzle (LDS row & 3 == fr & 3)
  for (int k0 = 0; k0 < CIN; k0 += 32) {
    for (int t9 = 0; t9 < 9; ++t9) {
      const int ky = t9 / 3, kx = t9 - ky * 3;
      const bf16* ga[2];
      for (int hf = 0; hf < 2; ++hf) {
        int sy = yy[hf] + ky - PAD, sx = xx[hf] + kx - PAD;
        bool valid = !CHECK || (sy >= 0 && sy < SRCW && sx >= 0 && sx < SRCW);
        ga[hf] = (valid ? A + (size_t)(bb[hf] * SRCROWS + sy * SRCW + sx) * CIN : zpage) + sg4;
      }
      const bf16* gb = Bp + (size_t)(t9 * 256 + n0 + srow) * CIN + sg4;
      gl2lds(ga[0] + k0, sA0);
      gl2lds(ga[1] + k0, sA1);
      gl2lds(gb + k0, sB0);
      gl2lds(gb + (size_t)64 * CIN + k0, sB1);
      __syncthreads();
      bf16x8 af[4], bw[4];
      for (int mt = 0; mt < 4; ++mt)
        af[mt] = *(const bf16x8*)(As + (wm * 64 + mt * 16 + fr) * 32 + swz4);
      for (int nt = 0; nt < 4; ++nt)
        bw[nt] = *(const bf16x8*)(Bs + (wn * 64 + nt * 16 + fr) * 32 + swz4);
      for (int mt = 0; mt < 4; ++mt)
        for (int nt = 0; nt < 4; ++nt)
          acc[mt][nt] = __builtin_amdgcn_mfma_f32_16x16x32_bf16(af[mt], bw[nt], acc[mt][nt], 0, 0, 0);
      __syncthreads();
    }
  }
  bf16* Cst = SM;
  for (int half = 0; half < 2; ++half) {
    if (wm == half) {
      for (int mt = 0; mt < 4; ++mt)
        for (int nt = 0; nt < 4; ++nt) {
          int n = n0 + wn * 64 + nt * 16 + fr;
          float bv = bias[n];
          for (int r = 0; r < 4; ++r) {
            float v = acc[mt][nt][r] + bv;
            if (TRANS)
              Cst[(wn * 64 + nt * 16 + fr) * 64 + mt * 16 + kq * 4 + r] = (bf16)v;
            else
              Cst[(mt * 16 + kq * 4 + r) * 128 + wn * 64 + nt * 16 + fr] = (bf16)v;
          }
        }
    }
    __syncthreads();
    if (TRANS) {
      for (int i = t; i < 2048; i += 256) {
        int oc = i >> 4, pc = i & 15;
        int gm = m0 + half * 64 + pc * 4;
        if (gm < MTOT) {
          int b = gm / 900, p = gm - b * 900;
          *(bf16x4*)(C + (size_t)(b * 256 + n0 + oc) * 900 + p) = *(const bf16x4*)(Cst + oc * 64 + pc * 4);
        }
      }
    } else {
      for (int i = t; i < 1024; i += 256) {
        int r = i >> 4, cs = i & 15;
        int gm = m0 + half * 64 + r;
        if (gm < MTOT)
          *(bf16x8*)(C + (size_t)gm * 256 + n0 + cs * 8) = *(const bf16x8*)(Cst + r * 128 + cs * 8);
      }
    }
    __syncthreads();
  }
}

// ---------------- conv2 (CIN=256, pad=1): k0-outer/tap-inner (L2-tight), BK=64,
// single-buffered 32 KiB, conflict-free [128][64] swizzled LDS, merged 96 batches ----
__global__ __launch_bounds__(256, 2) void k_conv2x(
    const bf16* __restrict__ A, const bf16* __restrict__ Bp,
    const float* __restrict__ bias, bf16* __restrict__ C,
    const bf16* __restrict__ zpage) {
  __shared__ alignas(16) bf16 SM[16384];
  const int t = threadIdx.x, wave = t >> 6;
  const int lane = t & 63, fr = lane & 15, kq = lane >> 4;
  const int wm = wave & 1, wn = wave >> 1;
  const int m0 = blockIdx.x * 128, n0 = blockIdx.y * 128;
  const int srow = t >> 3;                            // staged row slot (0..31)
  const int sg8 = (((t & 7) ^ (srow & 7)) << 3);      // pre-swizzled source k-seg
  // decode the 4 A-rows this thread stages (positions, clamped)
  int pb[4], py[4], px[4];
#pragma unroll
  for (int r = 0; r < 4; ++r) {
    int m = imin(m0 + r * 32 + srow, 86399);
    int b = m / 900, p = m - b * 900;
    pb[r] = b * 900; py[r] = p / 30; px[r] = p - (p / 30) * 30;
  }
  const int swz = (kq ^ (fr & 7)) << 3;
  const int aoff = (wm * 64 + fr) * 64 + swz;
  const int boff = 8192 + (wn * 64 + fr) * 64 + swz;
  f32x4 acc[4][4] = {};
  for (int k0 = 0; k0 < 256; k0 += 64) {
    for (int t9 = 0; t9 < 9; ++t9) {
      const int ky = t9 / 3, kx = t9 - ky * 3;
      bf16* db = SM + wave * 512;
#pragma unroll
      for (int r = 0; r < 4; ++r) {
        int sy = py[r] + ky - 1, sx = px[r] + kx - 1;
        bool valid = (sy >= 0 && sy < 30 && sx >= 0 && sx < 30);
        const bf16* g = valid ? (A + (size_t)(pb[r] + sy * 30 + sx) * 256 + k0 + sg8)
                              : (zpage + sg8);
        gl2lds(g, db + r * 2048);
      }
#pragma unroll
      for (int r = 0; r < 4; ++r)
        gl2lds(Bp + (size_t)(t9 * 256 + n0 + r * 32 + srow) * 256 + k0 + sg8,
               db + 8192 + r * 2048);
      __syncthreads();
#pragma unroll
      for (int kk = 0; kk < 2; ++kk) {
        const int xo = kk << 5;
        bf16x8 af[4], bw[4];
#pragma unroll
        for (int mt = 0; mt < 4; ++mt)
          af[mt] = *(const bf16x8*)(SM + ((aoff + mt * 1024) ^ xo));
#pragma unroll
        for (int nt = 0; nt < 4; ++nt)
          bw[nt] = *(const bf16x8*)(SM + ((boff + nt * 1024) ^ xo));
#pragma unroll
        for (int mt = 0; mt < 4; ++mt)
#pragma unroll
          for (int nt = 0; nt < 4; ++nt)
            acc[mt][nt] = __builtin_amdgcn_mfma_f32_16x16x32_bf16(af[mt], bw[nt], acc[mt][nt], 0, 0, 0);
      }
      __syncthreads();
    }
  }
  bf16* Cst = SM;  // 128 oc x 68 (padded pitch: conflict-free epilogue)
  for (int half = 0; half < 2; ++half) {
    if (wm == half) {
      for (int mt = 0; mt < 4; ++mt)
        for (int nt = 0; nt < 4; ++nt) {
          int n = n0 + wn * 64 + nt * 16 + fr;
          float bv = bias[n];
          for (int r = 0; r < 4; ++r) {
            float v = acc[mt][nt][r] + bv;
            Cst[(wn * 64 + nt * 16 + fr) * 68 + mt * 16 + kq * 4 + r] = (bf16)v;
          }
        }
    }
    __syncthreads();
    for (int i = t; i < 2048; i += 256) {
      int oc = i >> 4, pc = i & 15;
      int gm = m0 + half * 64 + pc * 4;
      int b = gm / 900, p = gm - b * 900;
      *(bf16x4*)(C + (size_t)(b * 256 + n0 + oc) * 900 + p) = *(const bf16x4*)(Cst + oc * 68 + pc * 4);
    }
    __syncthreads();
  }
}

// ---------------- attention logits z for one (s,h); rel transposed in-prologue ----
template <int MASKED>
__global__ __launch_bounds__(256, MASKED ? 4 : 5) void k_attn_z(
    const bf16* __restrict__ QKV, const float* __restrict__ Rel, bf16* __restrict__ Z,
    const bf16* __restrict__ L1p, const bf16* __restrict__ L2p,
    const float* __restrict__ l1b, const float* __restrict__ l2b) {
  __shared__ alignas(16) bf16 QKs[2][48 * 40];
  __shared__ alignas(16) bf16 RelS[48 * 32];
  __shared__ float EMD[48 * 49];
  __shared__ alignas(16) bf16 zst[48 * 48];
  __shared__ alignas(16) bf16 Sc[MASKED ? 48 * 72 : 8];
  __shared__ alignas(16) bf16 T2b[MASKED ? 48 * 72 : 8];
  const int sh = blockIdx.x, s = sh >> 3, h = sh & 7;
  const int t = threadIdx.x, wave = t >> 6, lane = t & 63, fr = lane & 15, kq = lane >> 4;
  const float scale = 0.17677669529663687f;  // 1/sqrt(32)
  for (int c = t; c < 384; c += 256) {
    int half = c >= 192 ? 1 : 0, cc = c - half * 192;
    int row = cc >> 2, seg = cc & 3;
    *(bf16x8*)(&QKs[half][row * 40 + seg * 8]) =
        *(const bf16x8*)(QKV + (size_t)(s * 48 + row) * 768 + half * 256 + h * 32 + seg * 8);
  }
  // rel slice (k*48+j) f32 -> RelS (j*32+k) bf16 (was k_prep_rel; coalesced f32 reads)
  {
    const float* relsrc = Rel + (size_t)sh * 1536;
    for (int i = t; i < 1536; i += 256) {
      int k = i / 48, j = i - k * 48;
      RelS[j * 32 + k] = (bf16)relsrc[i];
    }
  }
  if constexpr (MASKED) {
    for (int i = t; i < 768; i += 256) {
      int r = i >> 4, c = 48 + (i & 15);
      Sc[r * 72 + c] = (bf16)0.0f;
      T2b[r * 72 + c] = (bf16)0.0f;
    }
  }
  __syncthreads();
  f32x4 sreg[3];
  int u = 0;
  for (int t9 = wave; t9 < 9; t9 += 4, ++u) {
    int ti = t9 / 3, tj = t9 - ti * 3;
    bf16x8 af = *(const bf16x8*)(&QKs[0][(ti * 16 + fr) * 40 + kq * 8]);
    bf16x8 bk = *(const bf16x8*)(&QKs[1][(tj * 16 + fr) * 40 + kq * 8]);
    bf16x8 rf = *(const bf16x8*)(RelS + (tj * 16 + fr) * 32 + kq * 8);
    f32x4 sacc = {}, eacc = {};
    sacc = __builtin_amdgcn_mfma_f32_16x16x32_bf16(af, bk, sacc, 0, 0, 0);
    eacc = __builtin_amdgcn_mfma_f32_16x16x32_bf16(af, rf, eacc, 0, 0, 0);
    for (int r = 0; r < 4; ++r)
      EMD[(ti * 16 + kq * 4 + r) * 49 + tj * 16 + fr] = eacc[r];
    if constexpr (MASKED) {
      for (int r = 0; r < 4; ++r)
        Sc[(ti * 16 + kq * 4 + r) * 72 + tj * 16 + fr] = (bf16)(sacc[r] * scale);
    } else {
      for (int r = 0; r < 4; ++r) sreg[u][r] = sacc[r] * scale;
    }
  }
  __syncthreads();
  if constexpr (!MASKED) {
    u = 0;
    for (int t9 = wave; t9 < 9; t9 += 4, ++u) {
      int ti = t9 / 3, tj = t9 - ti * 3;
      for (int r = 0; r < 4; ++r) {
        int i = ti * 16 + kq * 4 + r, j = tj * 16 + fr;
        float v = sreg[u][r];
        if (j <= i) v += EMD[i * 49 + 47 + j - i];
        zst[i * 48 + j] = (bf16)v;
      }
    }
  } else {
    for (int t9 = wave; t9 < 9; t9 += 4) {
      int ti = t9 / 3, tj = t9 - ti * 3;
      f32x4 a2 = {};
      for (int k0 = 0; k0 < 64; k0 += 32) {
        bf16x8 af = *(const bf16x8*)(Sc + (ti * 16 + fr) * 72 + k0 + kq * 8);
        bf16x8 bw = *(const bf16x8*)(L1p + (tj * 16 + fr) * 72 + k0 + kq * 8);
        a2 = __builtin_amdgcn_mfma_f32_16x16x32_bf16(af, bw, a2, 0, 0, 0);
      }
      for (int r = 0; r < 4; ++r) {
        int i = ti * 16 + kq * 4 + r, a = tj * 16 + fr;
        T2b[a * 72 + i] = (bf16)(a2[r] + l1b[a]);
      }
    }
    __syncthreads();
    for (int t9 = wave; t9 < 9; t9 += 4) {
      int ti = t9 / 3, tj = t9 - ti * 3;
      f32x4 a2 = {};
      for (int k0 = 0; k0 < 64; k0 += 32) {
        bf16x8 af = *(const bf16x8*)(T2b + (ti * 16 + fr) * 72 + k0 + kq * 8);
        bf16x8 bw = *(const bf16x8*)(L2p + (tj * 16 + fr) * 72 + k0 + kq * 8);
        a2 = __builtin_amdgcn_mfma_f32_16x16x32_bf16(af, bw, a2, 0, 0, 0);
      }
      for (int r = 0; r < 4; ++r) {
        int aa = ti * 16 + kq * 4 + r, cc = tj * 16 + fr;
        float v;
        if (cc > aa) v = -10000.0f;  // masked column -> exactly uniform after softmax
        else v = a2[r] + l2b[cc] + EMD[aa * 49 + 47 + cc - aa];
        zst[aa * 48 + cc] = (bf16)v;
      }
    }
  }
  __syncthreads();
  bf16* zb = Z + (size_t)sh * 2304;
  for (int c = t; c < 288; c += 256)
    *(bf16x8*)(zb + c * 8) = *(const bf16x8*)(zst + c * 8);
}

// ---------------- per-column (over s=900) online max & inverse-sum ----------------
// grid 288: 64 cols/block (8 thr x 8 cols, bf16x8) x 32 s-groups of 29
__global__ __launch_bounds__(256) void k_colstats(const bf16* __restrict__ Z,
                                                  float* __restrict__ Mc, float* __restrict__ Ic) {
  __shared__ float rm[32][72], rs[32][72];
  const int t = threadIdx.x, cg = t & 7, sg = t >> 3;
  const bf16* p = Z + blockIdx.x * 64 + cg * 8;
  const int s0 = sg * 29, s1 = imin(900, s0 + 29);
  float m[8], ss[8];
  for (int e = 0; e < 8; ++e) { m[e] = -FLT_MAX; ss[e] = 0.0f; }
  for (int s = s0; s < s1; ++s) {
    bf16x8 zv = *(const bf16x8*)(p + (size_t)s * 18432);
    for (int e = 0; e < 8; ++e) {
      float v = (float)zv[e];
      if (v > m[e]) { ss[e] *= __expf(m[e] - v); m[e] = v; }
      ss[e] += __expf(v - m[e]);
    }
  }
  for (int e = 0; e < 8; ++e) { rm[sg][cg * 8 + e] = m[e]; rs[sg][cg * 8 + e] = ss[e]; }
  __syncthreads();
  if (t < 64) {
    float M2 = -FLT_MAX;
    for (int g = 0; g < 32; ++g) M2 = fmaxf(M2, rm[g][t]);
    float S2 = 0.0f;
    for (int g = 0; g < 32; ++g) S2 += rs[g][t] * __expf(rm[g][t] - M2);
    Mc[blockIdx.x * 64 + t] = M2;
    Ic[blockIdx.x * 64 + t] = 1.0f / S2;
  }
}

// ---------------- O = LN(RES + softmax(Z) V) for one (s,h); writes 6 rows of 256 ----
// attn output for block sh is 1536 contiguous elements = flat rows [6*sh, 6*sh+6) of
// the (b, sl, 256) view; each row is fully block-local, so add+LN fuses here.
__global__ __launch_bounds__(256, 6) void k_attn_av(
    const bf16* __restrict__ Z, const bf16* __restrict__ QKV,
    const float* __restrict__ Mc, const float* __restrict__ Ic,
    const bf16* __restrict__ RES, bf16* __restrict__ O) {
  __shared__ alignas(16) bf16 Ps[48 * 72];
  __shared__ alignas(16) bf16 Vt[32 * 72];
  __shared__ alignas(16) bf16 Ost[48 * 32];
  const int sh = blockIdx.x, s = sh >> 3, h = sh & 7;
  const int t = threadIdx.x, wave = t >> 6, lane = t & 63, fr = lane & 15, kq = lane >> 4;
  for (int i = t; i < 768; i += 256) Ps[(i >> 4) * 72 + 48 + (i & 15)] = (bf16)0.0f;
  for (int i = t; i < 512; i += 256) Vt[(i >> 4) * 72 + 48 + (i & 15)] = (bf16)0.0f;
  const bf16* zb = Z + (size_t)sh * 2304;
  const float* mc = Mc + h * 2304;
  const float* ic = Ic + h * 2304;
  for (int c = t; c < 288; c += 256) {
    int r = c / 6, seg = c - r * 6;
    int idx = r * 48 + seg * 8;
    bf16x8 zv = *(const bf16x8*)(zb + idx);
    f32x4 m0v = *(const f32x4*)(mc + idx), m1v = *(const f32x4*)(mc + idx + 4);
    f32x4 i0v = *(const f32x4*)(ic + idx), i1v = *(const f32x4*)(ic + idx + 4);
    bf16x8 pv;
    for (int e = 0; e < 4; ++e) pv[e] = (bf16)(__expf((float)zv[e] - m0v[e]) * i0v[e]);
    for (int e = 0; e < 4; ++e) pv[4 + e] = (bf16)(__expf((float)zv[4 + e] - m1v[e]) * i1v[e]);
    *(bf16x8*)(Ps + r * 72 + seg * 8) = pv;
  }
  for (int c = t; c < 192; c += 256) {
    int j = c >> 2, seg = c & 3;
    bf16x8 v = *(const bf16x8*)(QKV + (size_t)(s * 48 + j) * 768 + 512 + h * 32 + seg * 8);
    for (int e = 0; e < 8; ++e) Vt[(seg * 8 + e) * 72 + j] = v[e];
  }
  __syncthreads();
  for (int t6 = wave; t6 < 6; t6 += 4) {
    int ti = t6 >> 1, td = t6 & 1;
    f32x4 a2 = {};
    for (int k0 = 0; k0 < 64; k0 += 32) {
      bf16x8 af = *(const bf16x8*)(Ps + (ti * 16 + fr) * 72 + k0 + kq * 8);
      bf16x8 bv = *(const bf16x8*)(Vt + (td * 16 + fr) * 72 + k0 + kq * 8);
      a2 = __builtin_amdgcn_mfma_f32_16x16x32_bf16(af, bv, a2, 0, 0, 0);
    }
    for (int r = 0; r < 4; ++r)
      Ost[(ti * 16 + kq * 4 + r) * 32 + td * 16 + fr] = (bf16)a2[r];
  }
  __syncthreads();
  // fused add + LayerNorm: 6 rows of 256, 1 row per wave (2 rounds) — k_add_ln math
  const size_t base = (size_t)sh * 1536;
  for (int r = wave; r < 6; r += 4) {
    const size_t off = base + r * 256 + lane * 4;
    bf16x4 av = *(const bf16x4*)(Ost + r * 256 + lane * 4);
    bf16x4 bv = *(const bf16x4*)(RES + off);
    f32x4 x;
    for (int c = 0; c < 4; ++c) x[c] = (float)av[c] + (float)bv[c];
    float sum = x[0] + x[1] + x[2] + x[3];
    for (int o = 1; o < 64; o <<= 1) sum += __shfl_xor(sum, o);
    float mean = sum * (1.0f / 256.0f);
    float q = 0.0f;
    for (int c = 0; c < 4; ++c) { float d = x[c] - mean; q += d * d; }
    for (int o = 1; o < 64; o <<= 1) q += __shfl_xor(q, o);
    float rstd = rsqrtf(q * (1.0f / 256.0f) + 1e-5f);
    bf16x4 y;
    for (int c = 0; c < 4; ++c) y[c] = (bf16)((x[c] - mean) * rstd);
    *(bf16x4*)(O + off) = y;
  }
}

// ---------------- out = LN(Xa + Xb), rows of 256, bf16 ----------------
__global__ __launch_bounds__(256) void k_add_ln(
    const bf16* __restrict__ Xa, const bf16* __restrict__ Xb, bf16* __restrict__ out) {
  const int t = threadIdx.x, lane = t & 63, w = t >> 6;
  const size_t off = ((size_t)blockIdx.x * 4 + w) * 256 + lane * 4;
  bf16x4 av = *(const bf16x4*)(Xa + off);
  bf16x4 bv = *(const bf16x4*)(Xb + off);
  f32x4 x;
  for (int c = 0; c < 4; ++c) x[c] = (float)av[c] + (float)bv[c];
  float sum = x[0] + x[1] + x[2] + x[3];
  for (int o = 1; o < 64; o <<= 1) sum += __shfl_xor(sum, o);
  float mean = sum * (1.0f / 256.0f);
  float q = 0.0f;
  for (int c = 0; c < 4; ++c) { float d = x[c] - mean; q += d * d; }
  for (int o = 1; o < 64; o <<= 1) q += __shfl_xor(q, o);
  float rstd = rsqrtf(q * (1.0f / 256.0f) + 1e-5f);
  bf16x4 y;
  for (int c = 0; c < 4; ++c) y[c] = (bf16)((x[c] - mean) * rstd);
  *(bf16x4*)(out + off) = y;
}

// ---------------- Y[row] = dot(LN(Xa+Xb)[row], w) + b  (h3 never materialized) ----
__global__ __launch_bounds__(256) void k_add_ln_ydot(
    const bf16* __restrict__ Xa, const bf16* __restrict__ Xb,
    const float* __restrict__ w, const float* __restrict__ b,
    float* __restrict__ Y) {
  const int t = threadIdx.x, lane = t & 63, wv = t >> 6;
  const size_t row = (size_t)blockIdx.x * 4 + wv;
  const size_t off = row * 256 + lane * 4;
  bf16x4 av = *(const bf16x4*)(Xa + off);
  bf16x4 bv = *(const bf16x4*)(Xb + off);
  f32x4 x;
  for (int c = 0; c < 4; ++c) x[c] = (float)av[c] + (float)bv[c];
  float sum = x[0] + x[1] + x[2] + x[3];
  for (int o = 1; o < 64; o <<= 1) sum += __shfl_xor(sum, o);
  float mean = sum * (1.0f / 256.0f);
  float q = 0.0f;
  for (int c = 0; c < 4; ++c) { float d = x[c] - mean; q += d * d; }
  for (int o = 1; o < 64; o <<= 1) q += __shfl_xor(q, o);
  float rstd = rsqrtf(q * (1.0f / 256.0f) + 1e-5f);
  f32x4 ww = *(const f32x4*)(w + lane * 4);
  float yv = 0.0f;
  for (int c = 0; c < 4; ++c) yv += (x[c] - mean) * rstd * ww[c];
  for (int o = 1; o < 64; o <<= 1) yv += __shfl_xor(yv, o);
  if (lane == 0) Y[row] = yv + b[0];
}

// ---------------- softmax over b (48) per column ----------------
__global__ void k_softmax48(const float* __restrict__ Y, float* __restrict__ O) {
  int ss = blockIdx.x * 256 + threadIdx.x;
  if (ss >= 900) return;
  float m = -FLT_MAX;
  for (int b = 0; b < 48; ++b) m = fmaxf(m, Y[b * 900 + ss]);
  float sum = 0.0f;
  for (int b = 0; b < 48; ++b) sum += __expf(Y[b * 900 + ss] - m);
  float inv = 1.0f / sum;
  for (int b = 0; b < 48; ++b) O[b * 900 + ss] = __expf(Y[b * 900 + ss] - m) * inv;
}

extern "C" void kernel_launch(void* const* d_in, const int* in_sizes, int n_in,
                              void* d_out, int out_size, void* d_ws, size_t ws_size,
                              hipStream_t stream) {
  (void)in_sizes; (void)n_in; (void)out_size;
  const float* X_en = (const float*)d_in[0];
  const float* X_de = (const float*)d_in[1];
  const float* conv1_w = (const float*)d_in[2];
  const float* conv1_b = (const float*)d_in[3];
  const float* conv2_w = (const float*)d_in[4];
  const float* conv2_b = (const float*)d_in[5];
  const float* enc_wq = (const float*)d_in[6];
  const float* enc_wk = (const float*)d_in[7];
  const float* enc_wv = (const float*)d_in[8];
  const float* enc_rel = (const float*)d_in[9];
  const float* enc_f1w = (const float*)d_in[10];
  const float* enc_f1b = (const float*)d_in[11];
  const float* enc_f2w = (const float*)d_in[12];
  const float* enc_f2b = (const float*)d_in[13];
  const float* dm_wq = (const float*)d_in[14];
  const float* dm_wk = (const float*)d_in[15];
  const float* dm_wv = (const float*)d_in[16];
  const float* dm_rel = (const float*)d_in[17];
  const float* dm_l1w = (const float*)d_in[18];
  const float* dm_l1b = (const float*)d_in[19];
  const float* dm_l2w = (const float*)d_in[20];
  const float* dm_l2b = (const float*)d_in[21];
  const float* dc_wq = (const float*)d_in[22];
  const float* dc_wk = (const float*)d_in[23];
  const float* dc_wv = (const float*)d_in[24];
  const float* dc_rel = (const float*)d_in[25];
  const float* d_f1w = (const float*)d_in[26];
  const float* d_f1b = (const float*)d_in[27];
  const float* d_f2w = (const float*)d_in[28];
  const float* d_f2b = (const float*)d_in[29];
  const float* out_w = (const float*)d_in[30];
  const float* out_b = (const float*)d_in[31];
  float* OUT = (float*)d_out;

  // ---- workspace layout ----
  const size_t SLOT = 22118400;  // 43200*256 bf16
  char* ws = (char*)d_ws;
  size_t o = 0;
  bf16* S1 = (bf16*)(ws + o); o += SLOT;  // XEb -> ENCb
  bf16* S2 = (bf16*)(ws + o); o += SLOT;  // XDb -> (cross stats)
  bf16* S3 = (bf16*)(ws + o); o += SLOT;  // o1 -> (dm stats) -> h2
  bf16* S4 = (bf16*)(ws + o); o += SLOT;  // (enc stats) -> h1
  bf16* S5 = (bf16*)(ws + o); o += SLOT;  // ffn-out
  char* U = ws + o; o += 33177600 + 3 * SLOT;  // Z + QKV, union { HID, XR+C1R }
  bf16* Zb = (bf16*)U;
  bf16* QKV = (bf16*)(U + 33177600);
  bf16* XR = (bf16*)U;                    // conv phase: 96*1024*32 bf16 = 12.6 MB
  bf16* C1R = (bf16*)(U + 12582912);      // conv phase: 96*900*256 bf16 = 44.2 MB
  bf16* HID = (bf16*)U;                   // FFN phase only
  bf16* wa = (bf16*)(ws + o); o += 4603904 + 16384;
  float* Y = (float*)(ws + o); o += 172800;
  if (ws_size < o) return;

  bf16* zpage = (bf16*)Y;  // 512 B zero page; Y dead until k_add_ln_ydot
  float* encM = (float*)S4; float* encI = encM + 18432;
  float* dmM  = (float*)S3; float* dmI  = dmM + 18432;
  float* crM  = (float*)S2; float* crI  = crM + 18432;

  // weight arena (element offsets)
  bf16* c1p = wa;
  bf16* c2p = wa + 73728;
  bf16* EQKVw = wa + 663552;
  bf16* MQKVw = wa + 860160;
  bf16* cqw = wa + 1056768;
  bf16* CKVw = wa + 1122304;
  bf16* ef1 = wa + 1253376;
  bf16* ef2 = wa + 1515520;
  bf16* df1 = wa + 1777664;
  bf16* df2 = wa + 2039808;
  bf16* L1p = wa + 2301952;
  bf16* L2p = wa + 2305408;

  auto gemm = [&](const bf16* A, const bf16* B, const float* bias, bf16* C,
                  int M, int N, int K, int relu, int ldc, int coff) {
    k_gemm128<<<dim3((M + 127) / 128, N / 128), dim3(256), 0, stream>>>(
        A, A, B, B, N, bias, C, M, N, K, relu, ldc, coff);
  };

  // ---- weight prep ----
  k_prep_misc<<<dim3(1), dim3(256), 0, stream>>>(zpage, dm_l1w, dm_l2w, L1p, L2p);
  k_pack_conv<<<dim3(288), dim3(256), 0, stream>>>(conv1_w, c1p, 256, 32, 73728);
  k_pack_conv<<<dim3(2304), dim3(256), 0, stream>>>(conv2_w, c2p, 256, 256, 589824);
  {
    CastSegs sg;
    const float* srcs[13] = {enc_wq, enc_wk, enc_wv, dm_wq, dm_wk, dm_wv, dc_wq,
                             dc_wk, dc_wv, enc_f1w, enc_f2w, d_f1w, d_f2w};
    bf16* dsts[13] = {EQKVw, EQKVw + 65536, EQKVw + 131072, MQKVw, MQKVw + 65536,
                      MQKVw + 131072, cqw, CKVw, CKVw + 65536, ef1, ef2, df1, df2};
    int ns[13] = {65536, 65536, 65536, 65536, 65536, 65536, 65536, 65536, 65536,
                  262144, 262144, 262144, 262144};
    int total = 0;
    for (int k = 0; k < 13; ++k) { sg.s[k] = srcs[k]; sg.d[k] = dsts[k]; sg.n[k] = ns[k]; total += ns[k]; }
    k_cast_all<<<dim3((total + 255) / 256), dim3(256), 0, stream>>>(sg, total);
  }

  // ---- merged conv chain (96 batches: en then de; conv2 writes S1||S2 contiguously) ----
  k_prep_x<<<dim3(12288), dim3(256), 0, stream>>>(X_en, X_de, XR);
  k_conv128<32, 0, 32, 1024, 0, 0, 86400><<<dim3(675, 2), dim3(256), 0, stream>>>(
      XR, c1p, conv1_b, C1R, zpage);
  k_conv2x<<<dim3(675, 2), dim3(256), 0, stream>>>(C1R, c2p, conv2_b, S1, zpage);

  // ---- encoder ----
  gemm(S1, EQKVw, nullptr, QKV, 43200, 768, 256, 0, 768, 0);
  k_attn_z<0><<<dim3(7200), dim3(256), 0, stream>>>(QKV, enc_rel, Zb, nullptr, nullptr, nullptr, nullptr);
  k_colstats<<<dim3(288), dim3(256), 0, stream>>>(Zb, encM, encI);
  k_attn_av<<<dim3(7200), dim3(256), 0, stream>>>(Zb, QKV, encM, encI, S1, S3);  // o1 = LN(S1+attn)
  gemm(S3, ef1, enc_f1b, HID, 43200, 1024, 256, 1, 1024, 0);
  gemm(HID, ef2, enc_f2b, S5, 43200, 256, 1024, 0, 256, 0);
  k_add_ln<<<dim3(10800), dim3(256), 0, stream>>>(S3, S5, S1);  // enc_out

  // ---- decoder masked self-attention ----
  gemm(S2, MQKVw, nullptr, QKV, 43200, 768, 256, 0, 768, 0);
  k_attn_z<1><<<dim3(7200), dim3(256), 0, stream>>>(QKV, dm_rel, Zb, L1p, L2p, dm_l1b, dm_l2b);
  k_colstats<<<dim3(288), dim3(256), 0, stream>>>(Zb, dmM, dmI);
  k_attn_av<<<dim3(7200), dim3(256), 0, stream>>>(Zb, QKV, dmM, dmI, S2, S4);  // h1 = LN(S2+attn)

  // ---- cross attention (q + kv merged into one dual-GEMM launch) ----
  k_gemm128<<<dim3(338, 6), dim3(256), 0, stream>>>(
      S4, S1, cqw, CKVw, 256, nullptr, QKV, 43200, 768, 256, 0, 768, 0);
  k_attn_z<0><<<dim3(7200), dim3(256), 0, stream>>>(QKV, dc_rel, Zb, nullptr, nullptr, nullptr, nullptr);
  k_colstats<<<dim3(288), dim3(256), 0, stream>>>(Zb, crM, crI);
  k_attn_av<<<dim3(7200), dim3(256), 0, stream>>>(Zb, QKV, crM, crI, S4, S3);  // h2 = LN(h1+attn)

  // ---- decoder FFN + head (h3 fused away: Y = dot(LN(h2 + FFN2), out_w) + out_b) ----
  gemm(S3, df1, d_f1b, HID, 43200, 1024, 256, 1, 1024, 0);
  gemm(HID, df2, d_f2b, S5, 43200, 256, 1024, 0, 256, 0);
  k_add_ln_ydot<<<dim3(10800), dim3(256), 0, stream>>>(S3, S5, out_w, out_b, Y);
  k_softmax48<<<dim3(4), dim3(256), 0, stream>>>(Y, OUT);
}

// Round 12
// 920.838 us; speedup vs baseline: 1.1155x; 1.0131x over previous
//
#include <hip/hip_runtime.h>
#include <float.h>

typedef __bf16 bf16;
typedef __attribute__((ext_vector_type(8))) __bf16 bf16x8;
typedef __attribute__((ext_vector_type(4))) __bf16 bf16x4;
typedef __attribute__((ext_vector_type(4))) float f32x4;

__device__ __forceinline__ int imin(int a, int b) { return a < b ? a : b; }

// async global->LDS, 16B per lane; LDS dest = wave-uniform base + lane*16
__device__ __forceinline__ void gl2lds(const bf16* g, bf16* l) {
  __builtin_amdgcn_global_load_lds(
      (const __attribute__((address_space(1))) void*)g,
      (__attribute__((address_space(3))) void*)l, 16, 0, 0);
}

// ---------------- zero-page + padded lin weights (fused tiny prep) ----------------
__global__ void k_prep_misc(bf16* zp, const float* __restrict__ l1w,
                            const float* __restrict__ l2w,
                            bf16* __restrict__ L1p, bf16* __restrict__ L2p) {
  zp[threadIdx.x] = (bf16)0.0f;
  for (int i = threadIdx.x; i < 3456; i += 256) {
    int r = i / 72, c = i - r * 72;
    L1p[i] = (c < 48) ? (bf16)l1w[r * 48 + c] : (bf16)0.0f;
    L2p[i] = (c < 48) ? (bf16)l2w[r * 48 + c] : (bf16)0.0f;
  }
}

// ---------------- fused f32->bf16 casts (13 segments) ----------------
struct CastSegs { const float* s[13]; bf16* d[13]; int n[13]; };
__global__ void k_cast_all(CastSegs sg, int total) {
  int i = blockIdx.x * 256 + threadIdx.x;
  if (i >= total) return;
  for (int k = 0; k < 13; ++k) {
    if (i < sg.n[k]) { sg.d[k][i] = (bf16)sg.s[k][i]; return; }
    i -= sg.n[k];
  }
}

// ---------------- X_en|X_de -> XR rows, LDS-tiled transpose (coalesced both sides) --
// block = (bgl, pos-tile of 64): read X[bl][ic][pos0+p] coalesced along p,
// write XR[(bgl*1024+pos0+p)*32 + ic] coalesced along ic. Same mapping as the
// original scalar kernel, element-for-element.
__global__ __launch_bounds__(256) void k_prep_x(const float* __restrict__ XE,
                                                const float* __restrict__ XD,
                                                bf16* __restrict__ XR) {
  __shared__ float tile[32][65];
  const int t = threadIdx.x;
  const int bgl = blockIdx.x >> 4, pos0 = (blockIdx.x & 15) << 6;
  const float* X = (bgl < 48) ? XE : XD;
  const int bl = (bgl < 48) ? bgl : bgl - 48;
  for (int i = t; i < 2048; i += 256) {
    int ic = i >> 6, p = i & 63;
    tile[ic][p] = X[((size_t)(bl * 32 + ic) << 10) + pos0 + p];
  }
  __syncthreads();
  for (int i = t; i < 2048; i += 256) {
    int p = i >> 5, ic = i & 31;
    XR[(size_t)(bgl * 1024 + pos0 + p) * 32 + ic] = (bf16)tile[ic][p];
  }
}

// ---------------- conv weight pack: (OC,IC,3,3) -> 9 x (OC,IC) bf16 ----------------
__global__ void k_pack_conv(const float* __restrict__ w, bf16* __restrict__ dst,
                            int OC, int IC, int total) {
  int idx = blockIdx.x * 256 + threadIdx.x;
  if (idx >= total) return;
  int t = idx / (OC * IC);
  int rem = idx - t * OC * IC;
  int oc = rem / IC, ic = rem - oc * IC;
  dst[idx] = (bf16)w[(size_t)(oc * IC + ic) * 9 + t];
}

// ---------------- 128x128 GEMM, BK=64, single-buffered, conflict-free LDS ----------
// LDS: A [128][64] at 0, B [128][64] at +8192 (128-B row pitch).
// Swizzle involution: seg' = seg ^ (row&7) (16-B segs, 8/row); gl2lds dest linear,
// SOURCE pre-swizzled, reads swizzled with the same XOR.
// If n0 >= nsplit: use A2/B2 with local n (merged dual-GEMM launch). K%64==0, N%128==0.
__global__ __launch_bounds__(256, 2) void k_gemm128(
    const bf16* __restrict__ A, const bf16* __restrict__ A2,
    const bf16* __restrict__ B, const bf16* __restrict__ B2, int nsplit,
    const float* __restrict__ bias, bf16* __restrict__ C,
    int M, int N, int K, int relu, int ldc, int coff) {
  __shared__ alignas(16) bf16 SM[16384];
  const int t = threadIdx.x, wave = t >> 6;
  const int lane = t & 63, fr = lane & 15, kq = lane >> 4;
  const int wm = wave & 1, wn = wave >> 1;
  const int m0 = blockIdx.x * 128, n0 = blockIdx.y * 128;
  const bf16* Ause = A; const bf16* Buse = B; int nloc = n0;
  if (n0 >= nsplit) { Ause = A2; Buse = B2; nloc = n0 - nsplit; }
  // staging map: thread t covers (row = r*32 + (t>>3), seg = t&7), r = 0..3 for A and B
  const int srow = t >> 3;
  const int sg8 = (((t & 7) ^ (srow & 7)) << 3);  // pre-swizzled source k-seg (elements)
  const bf16* gA[4]; const bf16* gB[4];
#pragma unroll
  for (int r = 0; r < 4; ++r) {
    gA[r] = Ause + (size_t)imin(m0 + r * 32 + srow, M - 1) * K + sg8;
    gB[r] = Buse + (size_t)(nloc + r * 32 + srow) * K + sg8;
  }
  // fragment-read offsets (elements); ^32 switches k-halves
  const int swz = (kq ^ (fr & 7)) << 3;
  const int aoff = (wm * 64 + fr) * 64 + swz;
  const int boff = 8192 + (wn * 64 + fr) * 64 + swz;
  f32x4 acc[4][4] = {};
  for (int k0 = 0; k0 < K; k0 += 64) {
    bf16* db = SM + wave * 512;
#pragma unroll
    for (int r = 0; r < 4; ++r) gl2lds(gA[r] + k0, db + r * 2048);
#pragma unroll
    for (int r = 0; r < 4; ++r) gl2lds(gB[r] + k0, db + 8192 + r * 2048);
    __syncthreads();
#pragma unroll
    for (int kk = 0; kk < 2; ++kk) {
      const int xo = kk << 5;
      bf16x8 af[4], bw[4];
#pragma unroll
      for (int mt = 0; mt < 4; ++mt)
        af[mt] = *(const bf16x8*)(SM + ((aoff + mt * 1024) ^ xo));
#pragma unroll
      for (int nt = 0; nt < 4; ++nt)
        bw[nt] = *(const bf16x8*)(SM + ((boff + nt * 1024) ^ xo));
#pragma unroll
      for (int mt = 0; mt < 4; ++mt)
#pragma unroll
        for (int nt = 0; nt < 4; ++nt)
          acc[mt][nt] = __builtin_amdgcn_mfma_f32_16x16x32_bf16(af[mt], bw[nt], acc[mt][nt], 0, 0, 0);
    }
    __syncthreads();
  }
  bf16* Cst = SM;  // 64 x 136 (padded pitch: conflict-free epilogue)
  for (int half = 0; half < 2; ++half) {
    if (wm == half) {
      for (int mt = 0; mt < 4; ++mt)
        for (int nt = 0; nt < 4; ++nt) {
          int n = n0 + wn * 64 + nt * 16 + fr;
          float bv = bias ? bias[n] : 0.0f;
          for (int r = 0; r < 4; ++r) {
            float v = acc[mt][nt][r] + bv;
            if (relu) v = fmaxf(v, 0.0f);
            Cst[(mt * 16 + kq * 4 + r) * 136 + wn * 64 + nt * 16 + fr] = (bf16)v;
          }
        }
    }
    __syncthreads();
    for (int i = t; i < 1024; i += 256) {
      int r = i >> 4, cs = i & 15;
      int gm = m0 + half * 64 + r;
      if (gm < M)
        *(bf16x8*)(C + (size_t)gm * ldc + coff + n0 + cs * 8) = *(const bf16x8*)(Cst + r * 136 + cs * 8);
    }
    __syncthreads();
  }
}

// ---------------- conv1 (BK=32): shifted 128x128 GEMM, merged 96 batches,
// conflict-free 4-seg swizzle: seg' = seg ^ (row&3); source pre-swizzled,
// linear gl2lds dest, read XOR kq ^ (fr&3) (same involution family as gemm128) ------
template <int CIN, int PAD, int SRCW, int SRCROWS, int CHECK, int TRANS, int MTOT>
__global__ __launch_bounds__(256, 2) void k_conv128(
    const bf16* __restrict__ A, const bf16* __restrict__ Bp,
    const float* __restrict__ bias, bf16* __restrict__ C,
    const bf16* __restrict__ zpage) {
  __shared__ alignas(16) bf16 SM[8192];
  bf16* As = SM;
  bf16* Bs = SM + 4096;
  const int t = threadIdx.x, wave = t >> 6;
  const int lane = t & 63, fr = lane & 15, kq = lane >> 4;
  const int wm = wave & 1, wn = wave >> 1;
  const int m0 = blockIdx.x * 128, n0 = blockIdx.y * 128;
  const int srow = t >> 2;
  const int sg4 = (((t & 3) ^ (srow & 3)) << 3);  // pre-swizzled source k-seg
  f32x4 acc[4][4] = {};
  int bb[2], yy[2], xx[2];
  for (int hf = 0; hf < 2; ++hf) {
    int m = imin(m0 + hf * 64 + srow, MTOT - 1);
    int b = m / 900, p = m - b * 900;
    bb[hf] = b; yy[hf] = p / 30; xx[hf] = p - (p / 30) * 30;
  }
  bf16* sA0 = As + wave * 512;
  bf16* sA1 = As + 2048 + wave * 512;
  bf16* sB0 = Bs + wave * 512;
  bf16* sB1 = Bs + 2048 + wave * 512;
  const int swz4 = (kq ^ (fr & 3)) << 3;  // fragment-read swizzle (LDS row & 3 == fr & 3)
  for (int k0 = 0; k0 < CIN; k0 += 32) {
    for (int t9 = 0; t9 < 9; ++t9) {
      const int ky = t9 / 3, kx = t9 - ky * 3;
      const bf16* ga[2];
      for (int hf = 0; hf < 2; ++hf) {
        int sy = yy[hf] + ky - PAD, sx = xx[hf] + kx - PAD;
        bool valid = !CHECK || (sy >= 0 && sy < SRCW && sx >= 0 && sx < SRCW);
        ga[hf] = (valid ? A + (size_t)(bb[hf] * SRCROWS + sy * SRCW + sx) * CIN : zpage) + sg4;
      }
      const bf16* gb = Bp + (size_t)(t9 * 256 + n0 + srow) * CIN + sg4;
      gl2lds(ga[0] + k0, sA0);
      gl2lds(ga[1] + k0, sA1);
      gl2lds(gb + k0, sB0);
      gl2lds(gb + (size_t)64 * CIN + k0, sB1);
      __syncthreads();
      bf16x8 af[4], bw[4];
      for (int mt = 0; mt < 4; ++mt)
        af[mt] = *(const bf16x8*)(As + (wm * 64 + mt * 16 + fr) * 32 + swz4);
      for (int nt = 0; nt < 4; ++nt)
        bw[nt] = *(const bf16x8*)(Bs + (wn * 64 + nt * 16 + fr) * 32 + swz4);
      for (int mt = 0; mt < 4; ++mt)
        for (int nt = 0; nt < 4; ++nt)
          acc[mt][nt] = __builtin_amdgcn_mfma_f32_16x16x32_bf16(af[mt], bw[nt], acc[mt][nt], 0, 0, 0);
      __syncthreads();
    }
  }
  bf16* Cst = SM;
  for (int half = 0; half < 2; ++half) {
    if (wm == half) {
      for (int mt = 0; mt < 4; ++mt)
        for (int nt = 0; nt < 4; ++nt) {
          int n = n0 + wn * 64 + nt * 16 + fr;
          float bv = bias[n];
          for (int r = 0; r < 4; ++r) {
            float v = acc[mt][nt][r] + bv;
            if (TRANS)
              Cst[(wn * 64 + nt * 16 + fr) * 64 + mt * 16 + kq * 4 + r] = (bf16)v;
            else
              Cst[(mt * 16 + kq * 4 + r) * 128 + wn * 64 + nt * 16 + fr] = (bf16)v;
          }
        }
    }
    __syncthreads();
    if (TRANS) {
      for (int i = t; i < 2048; i += 256) {
        int oc = i >> 4, pc = i & 15;
        int gm = m0 + half * 64 + pc * 4;
        if (gm < MTOT) {
          int b = gm / 900, p = gm - b * 900;
          *(bf16x4*)(C + (size_t)(b * 256 + n0 + oc) * 900 + p) = *(const bf16x4*)(Cst + oc * 64 + pc * 4);
        }
      }
    } else {
      for (int i = t; i < 1024; i += 256) {
        int r = i >> 4, cs = i & 15;
        int gm = m0 + half * 64 + r;
        if (gm < MTOT)
          *(bf16x8*)(C + (size_t)gm * 256 + n0 + cs * 8) = *(const bf16x8*)(Cst + r * 128 + cs * 8);
      }
    }
    __syncthreads();
  }
}

// ---------------- conv2 (CIN=256, pad=1): k0-outer/tap-inner (L2-tight), BK=64,
// single-buffered 32 KiB, conflict-free [128][64] swizzled LDS, merged 96 batches ----
__global__ __launch_bounds__(256, 2) void k_conv2x(
    const bf16* __restrict__ A, const bf16* __restrict__ Bp,
    const float* __restrict__ bias, bf16* __restrict__ C,
    const bf16* __restrict__ zpage) {
  __shared__ alignas(16) bf16 SM[16384];
  const int t = threadIdx.x, wave = t >> 6;
  const int lane = t & 63, fr = lane & 15, kq = lane >> 4;
  const int wm = wave & 1, wn = wave >> 1;
  const int m0 = blockIdx.x * 128, n0 = blockIdx.y * 128;
  const int srow = t >> 3;                            // staged row slot (0..31)
  const int sg8 = (((t & 7) ^ (srow & 7)) << 3);      // pre-swizzled source k-seg
  // decode the 4 A-rows this thread stages (positions, clamped)
  int pb[4], py[4], px[4];
#pragma unroll
  for (int r = 0; r < 4; ++r) {
    int m = imin(m0 + r * 32 + srow, 86399);
    int b = m / 900, p = m - b * 900;
    pb[r] = b * 900; py[r] = p / 30; px[r] = p - (p / 30) * 30;
  }
  const int swz = (kq ^ (fr & 7)) << 3;
  const int aoff = (wm * 64 + fr) * 64 + swz;
  const int boff = 8192 + (wn * 64 + fr) * 64 + swz;
  f32x4 acc[4][4] = {};
  for (int k0 = 0; k0 < 256; k0 += 64) {
    for (int t9 = 0; t9 < 9; ++t9) {
      const int ky = t9 / 3, kx = t9 - ky * 3;
      bf16* db = SM + wave * 512;
#pragma unroll
      for (int r = 0; r < 4; ++r) {
        int sy = py[r] + ky - 1, sx = px[r] + kx - 1;
        bool valid = (sy >= 0 && sy < 30 && sx >= 0 && sx < 30);
        const bf16* g = valid ? (A + (size_t)(pb[r] + sy * 30 + sx) * 256 + k0 + sg8)
                              : (zpage + sg8);
        gl2lds(g, db + r * 2048);
      }
#pragma unroll
      for (int r = 0; r < 4; ++r)
        gl2lds(Bp + (size_t)(t9 * 256 + n0 + r * 32 + srow) * 256 + k0 + sg8,
               db + 8192 + r * 2048);
      __syncthreads();
#pragma unroll
      for (int kk = 0; kk < 2; ++kk) {
        const int xo = kk << 5;
        bf16x8 af[4], bw[4];
#pragma unroll
        for (int mt = 0; mt < 4; ++mt)
          af[mt] = *(const bf16x8*)(SM + ((aoff + mt * 1024) ^ xo));
#pragma unroll
        for (int nt = 0; nt < 4; ++nt)
          bw[nt] = *(const bf16x8*)(SM + ((boff + nt * 1024) ^ xo));
#pragma unroll
        for (int mt = 0; mt < 4; ++mt)
#pragma unroll
          for (int nt = 0; nt < 4; ++nt)
            acc[mt][nt] = __builtin_amdgcn_mfma_f32_16x16x32_bf16(af[mt], bw[nt], acc[mt][nt], 0, 0, 0);
      }
      __syncthreads();
    }
  }
  bf16* Cst = SM;  // 128 oc x 68 (padded pitch: conflict-free epilogue)
  for (int half = 0; half < 2; ++half) {
    if (wm == half) {
      for (int mt = 0; mt < 4; ++mt)
        for (int nt = 0; nt < 4; ++nt) {
          int n = n0 + wn * 64 + nt * 16 + fr;
          float bv = bias[n];
          for (int r = 0; r < 4; ++r) {
            float v = acc[mt][nt][r] + bv;
            Cst[(wn * 64 + nt * 16 + fr) * 68 + mt * 16 + kq * 4 + r] = (bf16)v;
          }
        }
    }
    __syncthreads();
    for (int i = t; i < 2048; i += 256) {
      int oc = i >> 4, pc = i & 15;
      int gm = m0 + half * 64 + pc * 4;
      int b = gm / 900, p = gm - b * 900;
      *(bf16x4*)(C + (size_t)(b * 256 + n0 + oc) * 900 + p) = *(const bf16x4*)(Cst + oc * 68 + pc * 4);
    }
    __syncthreads();
  }
}

// ---------------- attention logits z for one (s,h); rel transposed in-prologue ----
template <int MASKED>
__global__ __launch_bounds__(256, MASKED ? 4 : 5) void k_attn_z(
    const bf16* __restrict__ QKV, const float* __restrict__ Rel, bf16* __restrict__ Z,
    const bf16* __restrict__ L1p, const bf16* __restrict__ L2p,
    const float* __restrict__ l1b, const float* __restrict__ l2b) {
  __shared__ alignas(16) bf16 QKs[2][48 * 40];
  __shared__ alignas(16) bf16 RelS[48 * 32];
  __shared__ float EMD[48 * 49];
  __shared__ alignas(16) bf16 zst[48 * 48];
  __shared__ alignas(16) bf16 Sc[MASKED ? 48 * 72 : 8];
  __shared__ alignas(16) bf16 T2b[MASKED ? 48 * 72 : 8];
  const int sh = blockIdx.x, s = sh >> 3, h = sh & 7;
  const int t = threadIdx.x, wave = t >> 6, lane = t & 63, fr = lane & 15, kq = lane >> 4;
  const float scale = 0.17677669529663687f;  // 1/sqrt(32)
  for (int c = t; c < 384; c += 256) {
    int half = c >= 192 ? 1 : 0, cc = c - half * 192;
    int row = cc >> 2, seg = cc & 3;
    *(bf16x8*)(&QKs[half][row * 40 + seg * 8]) =
        *(const bf16x8*)(QKV + (size_t)(s * 48 + row) * 768 + half * 256 + h * 32 + seg * 8);
  }
  // rel slice (k*48+j) f32 -> RelS (j*32+k) bf16 (was k_prep_rel; coalesced f32 reads)
  {
    const float* relsrc = Rel + (size_t)sh * 1536;
    for (int i = t; i < 1536; i += 256) {
      int k = i / 48, j = i - k * 48;
      RelS[j * 32 + k] = (bf16)relsrc[i];
    }
  }
  if constexpr (MASKED) {
    for (int i = t; i < 768; i += 256) {
      int r = i >> 4, c = 48 + (i & 15);
      Sc[r * 72 + c] = (bf16)0.0f;
      T2b[r * 72 + c] = (bf16)0.0f;
    }
  }
  __syncthreads();
  f32x4 sreg[3];
  int u = 0;
  for (int t9 = wave; t9 < 9; t9 += 4, ++u) {
    int ti = t9 / 3, tj = t9 - ti * 3;
    bf16x8 af = *(const bf16x8*)(&QKs[0][(ti * 16 + fr) * 40 + kq * 8]);
    bf16x8 bk = *(const bf16x8*)(&QKs[1][(tj * 16 + fr) * 40 + kq * 8]);
    bf16x8 rf = *(const bf16x8*)(RelS + (tj * 16 + fr) * 32 + kq * 8);
    f32x4 sacc = {}, eacc = {};
    sacc = __builtin_amdgcn_mfma_f32_16x16x32_bf16(af, bk, sacc, 0, 0, 0);
    eacc = __builtin_amdgcn_mfma_f32_16x16x32_bf16(af, rf, eacc, 0, 0, 0);
    for (int r = 0; r < 4; ++r)
      EMD[(ti * 16 + kq * 4 + r) * 49 + tj * 16 + fr] = eacc[r];
    if constexpr (MASKED) {
      for (int r = 0; r < 4; ++r)
        Sc[(ti * 16 + kq * 4 + r) * 72 + tj * 16 + fr] = (bf16)(sacc[r] * scale);
    } else {
      for (int r = 0; r < 4; ++r) sreg[u][r] = sacc[r] * scale;
    }
  }
  __syncthreads();
  if constexpr (!MASKED) {
    u = 0;
    for (int t9 = wave; t9 < 9; t9 += 4, ++u) {
      int ti = t9 / 3, tj = t9 - ti * 3;
      for (int r = 0; r < 4; ++r) {
        int i = ti * 16 + kq * 4 + r, j = tj * 16 + fr;
        float v = sreg[u][r];
        if (j <= i) v += EMD[i * 49 + 47 + j - i];
        zst[i * 48 + j] = (bf16)v;
      }
    }
  } else {
    for (int t9 = wave; t9 < 9; t9 += 4) {
      int ti = t9 / 3, tj = t9 - ti * 3;
      f32x4 a2 = {};
      for (int k0 = 0; k0 < 64; k0 += 32) {
        bf16x8 af = *(const bf16x8*)(Sc + (ti * 16 + fr) * 72 + k0 + kq * 8);
        bf16x8 bw = *(const bf16x8*)(L1p + (tj * 16 + fr) * 72 + k0 + kq * 8);
        a2 = __builtin_amdgcn_mfma_f32_16x16x32_bf16(af, bw, a2, 0, 0, 0);
      }
      for (int r = 0; r < 4; ++r) {
        int i = ti * 16 + kq * 4 + r, a = tj * 16 + fr;
        T2b[a * 72 + i] = (bf16)(a2[r] + l1b[a]);
      }
    }
    __syncthreads();
    for (int t9 = wave; t9 < 9; t9 += 4) {
      int ti = t9 / 3, tj = t9 - ti * 3;
      f32x4 a2 = {};
      for (int k0 = 0; k0 < 64; k0 += 32) {
        bf16x8 af = *(const bf16x8*)(T2b + (ti * 16 + fr) * 72 + k0 + kq * 8);
        bf16x8 bw = *(const bf16x8*)(L2p + (tj * 16 + fr) * 72 + k0 + kq * 8);
        a2 = __builtin_amdgcn_mfma_f32_16x16x32_bf16(af, bw, a2, 0, 0, 0);
      }
      for (int r = 0; r < 4; ++r) {
        int aa = ti * 16 + kq * 4 + r, cc = tj * 16 + fr;
        float v;
        if (cc > aa) v = -10000.0f;  // masked column -> exactly uniform after softmax
        else v = a2[r] + l2b[cc] + EMD[aa * 49 + 47 + cc - aa];
        zst[aa * 48 + cc] = (bf16)v;
      }
    }
  }
  __syncthreads();
  bf16* zb = Z + (size_t)sh * 2304;
  for (int c = t; c < 288; c += 256)
    *(bf16x8*)(zb + c * 8) = *(const bf16x8*)(zst + c * 8);
}

// ---------------- per-column (over s=900) online max & inverse-sum ----------------
// grid 288: 64 cols/block (8 thr x 8 cols, bf16x8) x 32 s-groups of 29
__global__ __launch_bounds__(256) void k_colstats(const bf16* __restrict__ Z,
                                                  float* __restrict__ Mc, float* __restrict__ Ic) {
  __shared__ float rm[32][72], rs[32][72];
  const int t = threadIdx.x, cg = t & 7, sg = t >> 3;
  const bf16* p = Z + blockIdx.x * 64 + cg * 8;
  const int s0 = sg * 29, s1 = imin(900, s0 + 29);
  float m[8], ss[8];
  for (int e = 0; e < 8; ++e) { m[e] = -FLT_MAX; ss[e] = 0.0f; }
  for (int s = s0; s < s1; ++s) {
    bf16x8 zv = *(const bf16x8*)(p + (size_t)s * 18432);
    for (int e = 0; e < 8; ++e) {
      float v = (float)zv[e];
      if (v > m[e]) { ss[e] *= __expf(m[e] - v); m[e] = v; }
      ss[e] += __expf(v - m[e]);
    }
  }
  for (int e = 0; e < 8; ++e) { rm[sg][cg * 8 + e] = m[e]; rs[sg][cg * 8 + e] = ss[e]; }
  __syncthreads();
  if (t < 64) {
    float M2 = -FLT_MAX;
    for (int g = 0; g < 32; ++g) M2 = fmaxf(M2, rm[g][t]);
    float S2 = 0.0f;
    for (int g = 0; g < 32; ++g) S2 += rs[g][t] * __expf(rm[g][t] - M2);
    Mc[blockIdx.x * 64 + t] = M2;
    Ic[blockIdx.x * 64 + t] = 1.0f / S2;
  }
}

// ---------------- O = LN(RES + softmax(Z) V) for one (s,h); writes 6 rows of 256 ----
// attn output for block sh is 1536 contiguous elements = flat rows [6*sh, 6*sh+6) of
// the (b, sl, 256) view; each row is fully block-local, so add+LN fuses here.
__global__ __launch_bounds__(256, 6) void k_attn_av(
    const bf16* __restrict__ Z, const bf16* __restrict__ QKV,
    const float* __restrict__ Mc, const float* __restrict__ Ic,
    const bf16* __restrict__ RES, bf16* __restrict__ O) {
  __shared__ alignas(16) bf16 Ps[48 * 72];
  __shared__ alignas(16) bf16 Vt[32 * 72];
  __shared__ alignas(16) bf16 Ost[48 * 32];
  const int sh = blockIdx.x, s = sh >> 3, h = sh & 7;
  const int t = threadIdx.x, wave = t >> 6, lane = t & 63, fr = lane & 15, kq = lane >> 4;
  for (int i = t; i < 768; i += 256) Ps[(i >> 4) * 72 + 48 + (i & 15)] = (bf16)0.0f;
  for (int i = t; i < 512; i += 256) Vt[(i >> 4) * 72 + 48 + (i & 15)] = (bf16)0.0f;
  const bf16* zb = Z + (size_t)sh * 2304;
  const float* mc = Mc + h * 2304;
  const float* ic = Ic + h * 2304;
  for (int c = t; c < 288; c += 256) {
    int r = c / 6, seg = c - r * 6;
    int idx = r * 48 + seg * 8;
    bf16x8 zv = *(const bf16x8*)(zb + idx);
    f32x4 m0v = *(const f32x4*)(mc + idx), m1v = *(const f32x4*)(mc + idx + 4);
    f32x4 i0v = *(const f32x4*)(ic + idx), i1v = *(const f32x4*)(ic + idx + 4);
    bf16x8 pv;
    for (int e = 0; e < 4; ++e) pv[e] = (bf16)(__expf((float)zv[e] - m0v[e]) * i0v[e]);
    for (int e = 0; e < 4; ++e) pv[4 + e] = (bf16)(__expf((float)zv[4 + e] - m1v[e]) * i1v[e]);
    *(bf16x8*)(Ps + r * 72 + seg * 8) = pv;
  }
  for (int c = t; c < 192; c += 256) {
    int j = c >> 2, seg = c & 3;
    bf16x8 v = *(const bf16x8*)(QKV + (size_t)(s * 48 + j) * 768 + 512 + h * 32 + seg * 8);
    for (int e = 0; e < 8; ++e) Vt[(seg * 8 + e) * 72 + j] = v[e];
  }
  __syncthreads();
  for (int t6 = wave; t6 < 6; t6 += 4) {
    int ti = t6 >> 1, td = t6 & 1;
    f32x4 a2 = {};
    for (int k0 = 0; k0 < 64; k0 += 32) {
      bf16x8 af = *(const bf16x8*)(Ps + (ti * 16 + fr) * 72 + k0 + kq * 8);
      bf16x8 bv = *(const bf16x8*)(Vt + (td * 16 + fr) * 72 + k0 + kq * 8);
      a2 = __builtin_amdgcn_mfma_f32_16x16x32_bf16(af, bv, a2, 0, 0, 0);
    }
    for (int r = 0; r < 4; ++r)
      Ost[(ti * 16 + kq * 4 + r) * 32 + td * 16 + fr] = (bf16)a2[r];
  }
  __syncthreads();
  // fused add + LayerNorm: 6 rows of 256, 1 row per wave (2 rounds) — k_add_ln math
  const size_t base = (size_t)sh * 1536;
  for (int r = wave; r < 6; r += 4) {
    const size_t off = base + r * 256 + lane * 4;
    bf16x4 av = *(const bf16x4*)(Ost + r * 256 + lane * 4);
    bf16x4 bv = *(const bf16x4*)(RES + off);
    f32x4 x;
    for (int c = 0; c < 4; ++c) x[c] = (float)av[c] + (float)bv[c];
    float sum = x[0] + x[1] + x[2] + x[3];
    for (int o = 1; o < 64; o <<= 1) sum += __shfl_xor(sum, o);
    float mean = sum * (1.0f / 256.0f);
    float q = 0.0f;
    for (int c = 0; c < 4; ++c) { float d = x[c] - mean; q += d * d; }
    for (int o = 1; o < 64; o <<= 1) q += __shfl_xor(q, o);
    float rstd = rsqrtf(q * (1.0f / 256.0f) + 1e-5f);
    bf16x4 y;
    for (int c = 0; c < 4; ++c) y[c] = (bf16)((x[c] - mean) * rstd);
    *(bf16x4*)(O + off) = y;
  }
}

// ---------------- out = LN(Xa + Xb), rows of 256, bf16 ----------------
__global__ __launch_bounds__(256) void k_add_ln(
    const bf16* __restrict__ Xa, const bf16* __restrict__ Xb, bf16* __restrict__ out) {
  const int t = threadIdx.x, lane = t & 63, w = t >> 6;
  const size_t off = ((size_t)blockIdx.x * 4 + w) * 256 + lane * 4;
  bf16x4 av = *(const bf16x4*)(Xa + off);
  bf16x4 bv = *(const bf16x4*)(Xb + off);
  f32x4 x;
  for (int c = 0; c < 4; ++c) x[c] = (float)av[c] + (float)bv[c];
  float sum = x[0] + x[1] + x[2] + x[3];
  for (int o = 1; o < 64; o <<= 1) sum += __shfl_xor(sum, o);
  float mean = sum * (1.0f / 256.0f);
  float q = 0.0f;
  for (int c = 0; c < 4; ++c) { float d = x[c] - mean; q += d * d; }
  for (int o = 1; o < 64; o <<= 1) q += __shfl_xor(q, o);
  float rstd = rsqrtf(q * (1.0f / 256.0f) + 1e-5f);
  bf16x4 y;
  for (int c = 0; c < 4; ++c) y[c] = (bf16)((x[c] - mean) * rstd);
  *(bf16x4*)(out + off) = y;
}

// ---------------- Y[row] = dot(LN(Xa+Xb)[row], w) + b  (h3 never materialized) ----
__global__ __launch_bounds__(256) void k_add_ln_ydot(
    const bf16* __restrict__ Xa, const bf16* __restrict__ Xb,
    const float* __restrict__ w, const float* __restrict__ b,
    float* __restrict__ Y) {
  const int t = threadIdx.x, lane = t & 63, wv = t >> 6;
  const size_t row = (size_t)blockIdx.x * 4 + wv;
  const size_t off = row * 256 + lane * 4;
  bf16x4 av = *(const bf16x4*)(Xa + off);
  bf16x4 bv = *(const bf16x4*)(Xb + off);
  f32x4 x;
  for (int c = 0; c < 4; ++c) x[c] = (float)av[c] + (float)bv[c];
  float sum = x[0] + x[1] + x[2] + x[3];
  for (int o = 1; o < 64; o <<= 1) sum += __shfl_xor(sum, o);
  float mean = sum * (1.0f / 256.0f);
  float q = 0.0f;
  for (int c = 0; c < 4; ++c) { float d = x[c] - mean; q += d * d; }
  for (int o = 1; o < 64; o <<= 1) q += __shfl_xor(q, o);
  float rstd = rsqrtf(q * (1.0f / 256.0f) + 1e-5f);
  f32x4 ww = *(const f32x4*)(w + lane * 4);
  float yv = 0.0f;
  for (int c = 0; c < 4; ++c) yv += (x[c] - mean) * rstd * ww[c];
  for (int o = 1; o < 64; o <<= 1) yv += __shfl_xor(yv, o);
  if (lane == 0) Y[row] = yv + b[0];
}

// ---------------- softmax over b (48) per column ----------------
__global__ void k_softmax48(const float* __restrict__ Y, float* __restrict__ O) {
  int ss = blockIdx.x * 256 + threadIdx.x;
  if (ss >= 900) return;
  float m = -FLT_MAX;
  for (int b = 0; b < 48; ++b) m = fmaxf(m, Y[b * 900 + ss]);
  float sum = 0.0f;
  for (int b = 0; b < 48; ++b) sum += __expf(Y[b * 900 + ss] - m);
  float inv = 1.0f / sum;
  for (int b = 0; b < 48; ++b) O[b * 900 + ss] = __expf(Y[b * 900 + ss] - m) * inv;
}

extern "C" void kernel_launch(void* const* d_in, const int* in_sizes, int n_in,
                              void* d_out, int out_size, void* d_ws, size_t ws_size,
                              hipStream_t stream) {
  (void)in_sizes; (void)n_in; (void)out_size;
  const float* X_en = (const float*)d_in[0];
  const float* X_de = (const float*)d_in[1];
  const float* conv1_w = (const float*)d_in[2];
  const float* conv1_b = (const float*)d_in[3];
  const float* conv2_w = (const float*)d_in[4];
  const float* conv2_b = (const float*)d_in[5];
  const float* enc_wq = (const float*)d_in[6];
  const float* enc_wk = (const float*)d_in[7];
  const float* enc_wv = (const float*)d_in[8];
  const float* enc_rel = (const float*)d_in[9];
  const float* enc_f1w = (const float*)d_in[10];
  const float* enc_f1b = (const float*)d_in[11];
  const float* enc_f2w = (const float*)d_in[12];
  const float* enc_f2b = (const float*)d_in[13];
  const float* dm_wq = (const float*)d_in[14];
  const float* dm_wk = (const float*)d_in[15];
  const float* dm_wv = (const float*)d_in[16];
  const float* dm_rel = (const float*)d_in[17];
  const float* dm_l1w = (const float*)d_in[18];
  const float* dm_l1b = (const float*)d_in[19];
  const float* dm_l2w = (const float*)d_in[20];
  const float* dm_l2b = (const float*)d_in[21];
  const float* dc_wq = (const float*)d_in[22];
  const float* dc_wk = (const float*)d_in[23];
  const float* dc_wv = (const float*)d_in[24];
  const float* dc_rel = (const float*)d_in[25];
  const float* d_f1w = (const float*)d_in[26];
  const float* d_f1b = (const float*)d_in[27];
  const float* d_f2w = (const float*)d_in[28];
  const float* d_f2b = (const float*)d_in[29];
  const float* out_w = (const float*)d_in[30];
  const float* out_b = (const float*)d_in[31];
  float* OUT = (float*)d_out;

  // ---- workspace layout ----
  const size_t SLOT = 22118400;  // 43200*256 bf16
  char* ws = (char*)d_ws;
  size_t o = 0;
  bf16* S1 = (bf16*)(ws + o); o += SLOT;  // XEb -> ENCb
  bf16* S2 = (bf16*)(ws + o); o += SLOT;  // XDb -> (cross stats)
  bf16* S3 = (bf16*)(ws + o); o += SLOT;  // o1 -> (dm stats) -> h2
  bf16* S4 = (bf16*)(ws + o); o += SLOT;  // (enc stats) -> h1
  bf16* S5 = (bf16*)(ws + o); o += SLOT;  // ffn-out
  char* U = ws + o; o += 33177600 + 3 * SLOT;  // Z + QKV, union { HID, XR+C1R }
  bf16* Zb = (bf16*)U;
  bf16* QKV = (bf16*)(U + 33177600);
  bf16* XR = (bf16*)U;                    // conv phase: 96*1024*32 bf16 = 12.6 MB
  bf16* C1R = (bf16*)(U + 12582912);      // conv phase: 96*900*256 bf16 = 44.2 MB
  bf16* HID = (bf16*)U;                   // FFN phase only
  bf16* wa = (bf16*)(ws + o); o += 4603904 + 16384;
  float* Y = (float*)(ws + o); o += 172800;
  if (ws_size < o) return;

  bf16* zpage = (bf16*)Y;  // 512 B zero page; Y dead until k_add_ln_ydot
  float* encM = (float*)S4; float* encI = encM + 18432;
  float* dmM  = (float*)S3; float* dmI  = dmM + 18432;
  float* crM  = (float*)S2; float* crI  = crM + 18432;

  // weight arena (element offsets)
  bf16* c1p = wa;
  bf16* c2p = wa + 73728;
  bf16* EQKVw = wa + 663552;
  bf16* MQKVw = wa + 860160;
  bf16* cqw = wa + 1056768;
  bf16* CKVw = wa + 1122304;
  bf16* ef1 = wa + 1253376;
  bf16* ef2 = wa + 1515520;
  bf16* df1 = wa + 1777664;
  bf16* df2 = wa + 2039808;
  bf16* L1p = wa + 2301952;
  bf16* L2p = wa + 2305408;

  auto gemm = [&](const bf16* A, const bf16* B, const float* bias, bf16* C,
                  int M, int N, int K, int relu, int ldc, int coff) {
    k_gemm128<<<dim3((M + 127) / 128, N / 128), dim3(256), 0, stream>>>(
        A, A, B, B, N, bias, C, M, N, K, relu, ldc, coff);
  };

  // ---- weight prep ----
  k_prep_misc<<<dim3(1), dim3(256), 0, stream>>>(zpage, dm_l1w, dm_l2w, L1p, L2p);
  k_pack_conv<<<dim3(288), dim3(256), 0, stream>>>(conv1_w, c1p, 256, 32, 73728);
  k_pack_conv<<<dim3(2304), dim3(256), 0, stream>>>(conv2_w, c2p, 256, 256, 589824);
  {
    CastSegs sg;
    const float* srcs[13] = {enc_wq, enc_wk, enc_wv, dm_wq, dm_wk, dm_wv, dc_wq,
                             dc_wk, dc_wv, enc_f1w, enc_f2w, d_f1w, d_f2w};
    bf16* dsts[13] = {EQKVw, EQKVw + 65536, EQKVw + 131072, MQKVw, MQKVw + 65536,
                      MQKVw + 131072, cqw, CKVw, CKVw + 65536, ef1, ef2, df1, df2};
    int ns[13] = {65536, 65536, 65536, 65536, 65536, 65536, 65536, 65536, 65536,
                  262144, 262144, 262144, 262144};
    int total = 0;
    for (int k = 0; k < 13; ++k) { sg.s[k] = srcs[k]; sg.d[k] = dsts[k]; sg.n[k] = ns[k]; total += ns[k]; }
    k_cast_all<<<dim3((total + 255) / 256), dim3(256), 0, stream>>>(sg, total);
  }

  // ---- merged conv chain (96 batches: en then de; conv2 writes S1||S2 contiguously) ----
  k_prep_x<<<dim3(1536), dim3(256), 0, stream>>>(X_en, X_de, XR);
  k_conv128<32, 0, 32, 1024, 0, 0, 86400><<<dim3(675, 2), dim3(256), 0, stream>>>(
      XR, c1p, conv1_b, C1R, zpage);
  k_conv2x<<<dim3(675, 2), dim3(256), 0, stream>>>(C1R, c2p, conv2_b, S1, zpage);

  // ---- encoder ----
  gemm(S1, EQKVw, nullptr, QKV, 43200, 768, 256, 0, 768, 0);
  k_attn_z<0><<<dim3(7200), dim3(256), 0, stream>>>(QKV, enc_rel, Zb, nullptr, nullptr, nullptr, nullptr);
  k_colstats<<<dim3(288), dim3(256), 0, stream>>>(Zb, encM, encI);
  k_attn_av<<<dim3(7200), dim3(256), 0, stream>>>(Zb, QKV, encM, encI, S1, S3);  // o1 = LN(S1+attn)
  gemm(S3, ef1, enc_f1b, HID, 43200, 1024, 256, 1, 1024, 0);
  gemm(HID, ef2, enc_f2b, S5, 43200, 256, 1024, 0, 256, 0);
  k_add_ln<<<dim3(10800), dim3(256), 0, stream>>>(S3, S5, S1);  // enc_out

  // ---- decoder masked self-attention ----
  gemm(S2, MQKVw, nullptr, QKV, 43200, 768, 256, 0, 768, 0);
  k_attn_z<1><<<dim3(7200), dim3(256), 0, stream>>>(QKV, dm_rel, Zb, L1p, L2p, dm_l1b, dm_l2b);
  k_colstats<<<dim3(288), dim3(256), 0, stream>>>(Zb, dmM, dmI);
  k_attn_av<<<dim3(7200), dim3(256), 0, stream>>>(Zb, QKV, dmM, dmI, S2, S4);  // h1 = LN(S2+attn)

  // ---- cross attention (q + kv merged into one dual-GEMM launch) ----
  k_gemm128<<<dim3(338, 6), dim3(256), 0, stream>>>(
      S4, S1, cqw, CKVw, 256, nullptr, QKV, 43200, 768, 256, 0, 768, 0);
  k_attn_z<0><<<dim3(7200), dim3(256), 0, stream>>>(QKV, dc_rel, Zb, nullptr, nullptr, nullptr, nullptr);
  k_colstats<<<dim3(288), dim3(256), 0, stream>>>(Zb, crM, crI);
  k_attn_av<<<dim3(7200), dim3(256), 0, stream>>>(Zb, QKV, crM, crI, S4, S3);  // h2 = LN(h1+attn)

  // ---- decoder FFN + head (h3 fused away: Y = dot(LN(h2 + FFN2), out_w) + out_b) ----
  gemm(S3, df1, d_f1b, HID, 43200, 1024, 256, 1, 1024, 0);
  gemm(HID, df2, d_f2b, S5, 43200, 256, 1024, 0, 256, 0);
  k_add_ln_ydot<<<dim3(10800), dim3(256), 0, stream>>>(S3, S5, out_w, out_b, Y);
  k_softmax48<<<dim3(4), dim3(256), 0, stream>>>(Y, OUT);
}